// Round 2
// baseline (359.250 us; speedup 1.0000x reference)
//
#include <hip/hip_runtime.h>
#include <hip/hip_bf16.h>
#include <stdint.h>

typedef __attribute__((ext_vector_type(8))) short bf16x8;
typedef __attribute__((ext_vector_type(4))) float f32x4;
typedef __attribute__((ext_vector_type(4))) unsigned short u16x4;

#define B_  4
#define T_  2048
#define D_  1024
#define BM  128
#define BN  128
#define BK  32

__device__ __forceinline__ float bf2f(ushort u) {
  union { unsigned int i; float f; } v; v.i = ((unsigned int)u) << 16; return v.f;
}
__device__ __forceinline__ ushort f2bf(float f) {
  return (ushort)(__bfloat16_as_ushort(__float2bfloat16(f)));
}
__device__ __forceinline__ void async16(const void* g, void* l) {
  __builtin_amdgcn_global_load_lds(
      (const __attribute__((address_space(1))) void*)g,
      (__attribute__((address_space(3))) void*)l, 16, 0, 0);
}
__device__ __forceinline__ int swz4(int r) { return (r ^ (r >> 2)) & 3; }

// ---------------- fused prep: all converts + transposed weight cvts + bias combine ----
__global__ __launch_bounds__(256)
void prep(const float* __restrict__ lat, const float* __restrict__ inp,
          const float* __restrict__ Wl, const float* __restrict__ bl,
          const float* __restrict__ Wu, const float* __restrict__ bu,
          const float* __restrict__ WA, const float* __restrict__ bA,
          const float* __restrict__ WV, const float* __restrict__ bV,
          const float* __restrict__ Wo, const float* __restrict__ bo,
          ushort* __restrict__ xBf, ushort* __restrict__ xBf2,
          ushort* __restrict__ w1, ushort* __restrict__ w2,
          ushort* __restrict__ wCatWo, float* __restrict__ bc, float* __restrict__ bc2)
{
  __shared__ alignas(16) ushort t[64 * 65];
  const long NW = (long)D_ * D_;
  const int bx = blockIdx.x;
  const int tid = threadIdx.x;
  if (bx < 16384) {                     // big tensor cvts
    const float* in = bx < 8192 ? lat : inp;
    ushort* out = bx < 8192 ? xBf : xBf2;
    const long i = (long)(bx & 8191) * 256 + tid;
    const float4 v = *(const float4*)(in + i * 4);
    u16x4 o;
    o[0] = f2bf(v.x); o[1] = f2bf(v.y); o[2] = f2bf(v.z); o[3] = f2bf(v.w);
    *(u16x4*)(out + i * 4) = o;
  } else if (bx < 19456) {              // weight cvts
    const int seg = (bx - 16384) >> 10;
    const float* in  = seg == 0 ? Wu : (seg == 1 ? WV : Wo);
    ushort* out = seg == 0 ? w1 : (seg == 1 ? w1 + NW : wCatWo);
    const long i = (long)((bx - 16384) & 1023) * 256 + tid;
    const float4 v = *(const float4*)(in + i * 4);
    u16x4 o;
    o[0] = f2bf(v.x); o[1] = f2bf(v.y); o[2] = f2bf(v.z); o[3] = f2bf(v.w);
    *(u16x4*)(out + i * 4) = o;
  } else if (bx < 19968) {              // transposed weight cvts
    const int z = (bx - 19456) >> 8;
    const int w = (bx - 19456) & 255;
    const float* in = z ? WA : Wl;
    ushort* out = z ? w2 + NW : w2;
    const int c0 = (w & 15) * 64, r0 = (w >> 4) * 64;
    const int tx = tid & 15, ty = tid >> 4;
#pragma unroll
    for (int i = 0; i < 4; ++i) {
      const int r = ty + i * 16;
      const float4 v = *(const float4*)(in + (long)(r0 + r) * D_ + c0 + tx * 4);
      t[(tx * 4 + 0) * 65 + r] = f2bf(v.x);
      t[(tx * 4 + 1) * 65 + r] = f2bf(v.y);
      t[(tx * 4 + 2) * 65 + r] = f2bf(v.z);
      t[(tx * 4 + 3) * 65 + r] = f2bf(v.w);
    }
    __syncthreads();
#pragma unroll
    for (int i = 0; i < 4; ++i) {
      const int c = ty + i * 16;
      u16x4 v;
#pragma unroll
      for (int j = 0; j < 4; ++j) v[j] = t[c * 65 + tx * 4 + j];
      *(u16x4*)(out + (long)(c0 + c) * D_ + r0 + tx * 4) = v;
    }
  } else {                              // bias combine
    const int z = (bx - 19968) >> 8;
    const int w = (bx - 19968) & 255;
    const float* W    = z ? WV : Wu;
    const float* bin  = z ? bA : bl;
    const float* badd = z ? bV : bu;
    float* out        = z ? bc2 : bc;
    const int wv = tid >> 6, lane = tid & 63;
    const int e = w * 4 + wv;
    const float* row = W + (long)e * D_;
    float s = 0.f;
#pragma unroll
    for (int i = 0; i < 16; ++i) s += row[lane + i * 64] * bin[lane + i * 64];
#pragma unroll
    for (int off = 32; off; off >>= 1) s += __shfl_xor(s, off);
    if (lane == 0) out[e] = s + badd[e];
  }
}

// ---------------- small 128^2 GEMM (kept for the 1024^3 weight-compose) ----------
template<bool OUT_F32, bool HAS_BIAS, bool EXP_OUT>
__global__ __launch_bounds__(256, 2)
void gemm_nt(const ushort* __restrict__ A, const ushort* __restrict__ B,
             const float* __restrict__ bias, void* __restrict__ C,
             int N, int K, long sA, long sB, long sC)
{
  __shared__ alignas(16) ushort As[BM * BK];
  __shared__ alignas(16) ushort Bs[BN * BK];
  const int tid  = threadIdx.x;
  const int wave = tid >> 6;
  const int lane = tid & 63;
  const int wm   = wave >> 1;
  const int wn   = wave & 1;
  const int bz   = blockIdx.z;
  const int tileN = blockIdx.x * BN;
  const int tileM = blockIdx.y * BM;
  A += (long)bz * sA;
  B += (long)bz * sB;

  const int lrow   = lane >> 2;
  const int lchunk = (lane & 3) ^ swz4(lrow);

  f32x4 acc[4][4];
#pragma unroll
  for (int i = 0; i < 4; ++i)
#pragma unroll
    for (int j = 0; j < 4; ++j) acc[i][j] = (f32x4){0.f, 0.f, 0.f, 0.f};

  const int frow = lane & 15;
  const int kg   = lane >> 4;
  const int coff = ((kg ^ swz4(frow)) << 3);

  for (int kt = 0; kt < K; kt += BK) {
    __syncthreads();
#pragma unroll
    for (int i = 0; i < 2; ++i) {
      const int rg  = wave * 2 + i;
      const int row = rg * 16 + lrow;
      async16(A + (long)(tileM + row) * K + kt + lchunk * 8, (void*)(As + rg * 16 * BK));
      async16(B + (long)(tileN + row) * K + kt + lchunk * 8, (void*)(Bs + rg * 16 * BK));
    }
    __syncthreads();
    bf16x8 af[4], bfr[4];
#pragma unroll
    for (int mi = 0; mi < 4; ++mi)
      af[mi] = *(const bf16x8*)(As + (wm * 64 + mi * 16 + frow) * BK + coff);
#pragma unroll
    for (int ni = 0; ni < 4; ++ni)
      bfr[ni] = *(const bf16x8*)(Bs + (wn * 64 + ni * 16 + frow) * BK + coff);
#pragma unroll
    for (int mi = 0; mi < 4; ++mi)
#pragma unroll
      for (int ni = 0; ni < 4; ++ni)
        acc[mi][ni] = __builtin_amdgcn_mfma_f32_16x16x32_bf16(af[mi], bfr[ni], acc[mi][ni], 0, 0, 0);
  }

  const int rowbase = tileM + wm * 64 + ((lane >> 4) << 2);
  const int colbase = tileN + wn * 64 + (lane & 15);
#pragma unroll
  for (int ni = 0; ni < 4; ++ni) {
    const int col = colbase + ni * 16;
    float bv = 0.f;
    if constexpr (HAS_BIAS) bv = bias[col];
#pragma unroll
    for (int mi = 0; mi < 4; ++mi) {
#pragma unroll
      for (int r = 0; r < 4; ++r) {
        const int row = rowbase + mi * 16 + r;
        float v = acc[mi][ni][r] + bv;
        if constexpr (EXP_OUT) v = __expf(v);
        const long idx = (long)bz * sC + (long)row * N + col;
        if constexpr (OUT_F32) ((float*)C)[idx] = v;
        else ((ushort*)C)[idx] = f2bf(v);
      }
    }
  }
}

// ================= 256x128 deep-pipelined GEMM core (reg-prefetch) =================
// C[m,n] = sum_k A[m,k]*B[n,k].  K = 1024 fixed (32 K-tiles of 32).
// 512 threads / 8 waves (4M x 2N), BM=256, BN=128.  4-deep LDS ring (96 KB),
// ONE raw barrier + ONE counted vmcnt per K-tile; fragments for tile t+1 are
// ds_read while MFMAs for tile t run on registers loaded last iteration
// (compiler emits counted lgkmcnt(8)).  XOR-swizzled LDS via pre-swizzled
// global source addresses (linear global_load_lds dest).  setprio around the
// MFMA cluster; bijective XCD-chunked block remap (all grids % 8 == 0).
// MODE: 0 = dual bf16 out (tileN<1024 -> C1/bias1 else C2/bias2)
//       1 = bf16 out, bias + exp
//       2 = bf16 out, split-K partial layout  C1 + ((z&1)*B_ + z>>1)*NW
//       3 = f32 out, z-batched by sCz
template<int MODE>
__global__ __launch_bounds__(512, 2)
void gemm8(const ushort* __restrict__ A, const ushort* __restrict__ Bm,
           const float* __restrict__ bias1, const float* __restrict__ bias2,
           void* __restrict__ C1, void* __restrict__ C2,
           int ldA, int ldB, long sAz, long sBz, long sCz)
{
  __shared__ alignas(16) ushort Ab[4][256 * 32];
  __shared__ alignas(16) ushort Bb[4][128 * 32];

  // bijective XCD-chunked remap (nwg % 8 == 0 for all launch shapes)
  const int gx = gridDim.x, gy = gridDim.y;
  const int nwg = gx * gy * gridDim.z;
  int fid = (blockIdx.z * gy + blockIdx.y) * gx + blockIdx.x;
  fid = (fid & 7) * (nwg >> 3) + (fid >> 3);
  const int bx = fid % gx;
  const int by = (fid / gx) % gy;
  const int bz = fid / (gx * gy);

  const int tileM = by * 256, tileN = bx * 128;

  const ushort* Ap = A;
  const ushort* Bp = Bm;
  if constexpr (MODE == 2) {
    Ap += (long)(bz >> 1) * sAz + (long)(bz & 1) * 1024;
    Bp += (long)(bz >> 1) * sBz + (long)(bz & 1) * 1024;
  } else {
    Ap += (long)bz * sAz;
    Bp += (long)bz * sBz;
  }

  const int tid  = threadIdx.x;
  const int wid  = tid >> 6;
  const int lane = tid & 63;
  const int wm   = wid >> 1;          // 4 waves along M
  const int wn   = wid & 1;           // 2 waves along N

  // staging: thread tid fills LDS elems [inst*4096 + tid*8, +8)
  //   row r = (tid>>2) (+128 for 2nd A inst); swizzled col chunk = (tid&3)^((r>>1)&3)
  const int srow = tid >> 2;
  const int scol = (((tid & 3) ^ ((tid >> 3) & 3)) << 3);
  const ushort* gA0 = Ap + (long)(tileM + srow) * ldA + scol;
  const ushort* gA1 = Ap + (long)(tileM + 128 + srow) * ldA + scol;
  const ushort* gB0 = Bp + (long)(tileN + srow) * ldB + scol;
  const int wofs = wid << 9;          // wave LDS base (elems)

  // fragment reads: row fr = base + frow, col chunk = kg ^ ((fr>>1)&3)
  const int frow  = lane & 15;
  const int cofs  = (((lane >> 4) ^ ((lane >> 1) & 3)) << 3);
  const int abase = wm * 64 + frow;
  const int bbase = wn * 64 + frow;

  f32x4 acc[4][4];
#pragma unroll
  for (int i = 0; i < 4; ++i)
#pragma unroll
    for (int j = 0; j < 4; ++j) acc[i][j] = (f32x4){0.f, 0.f, 0.f, 0.f};

  // prologue: stage K-tiles 0,1,2 into ring slots 0,1,2 (9 VMEM insts)
#pragma unroll
  for (int p = 0; p < 3; ++p) {
    const int kt = p * 32;
    async16(gA0 + kt, Ab[p] + wofs);
    async16(gA1 + kt, Ab[p] + 4096 + wofs);
    async16(gB0 + kt, Bb[p] + wofs);
  }
  asm volatile("s_waitcnt vmcnt(6)" ::: "memory");   // tile 0 resident
  __builtin_amdgcn_s_barrier();

  bf16x8 f0a[4], f0b[4], f1a[4], f1b[4];
#pragma unroll
  for (int ni = 0; ni < 4; ++ni)
    f0b[ni] = *(const bf16x8*)(Bb[0] + (bbase + ni * 16) * 32 + cofs);
#pragma unroll
  for (int mi = 0; mi < 4; ++mi)
    f0a[mi] = *(const bf16x8*)(Ab[0] + (abase + mi * 16) * 32 + cofs);

  // per K-tile: vmcnt(3) [t+1 resident] -> barrier [cross-wave visibility +
  // slot t-1 free] -> stage t+3 -> ds_read frags(t+1) -> pin -> 16 MFMA on t.
#define KSTEP(FC, FN, TC)                                                     \
  {                                                                           \
    if ((TC) == 30) { asm volatile("s_waitcnt vmcnt(0)" ::: "memory"); }      \
    else            { asm volatile("s_waitcnt vmcnt(3)" ::: "memory"); }      \
    __builtin_amdgcn_s_barrier();                                             \
    if ((TC) + 3 < 32) {                                                      \
      const int kt = ((TC) + 3) * 32; const int sl = ((TC) + 3) & 3;          \
      async16(gA0 + kt, Ab[sl] + wofs);                                       \
      async16(gA1 + kt, Ab[sl] + 4096 + wofs);                                \
      async16(gB0 + kt, Bb[sl] + wofs);                                       \
    }                                                                         \
    if ((TC) + 1 < 32) {                                                      \
      const int sl = ((TC) + 1) & 3;                                          \
      _Pragma("unroll")                                                       \
      for (int ni = 0; ni < 4; ++ni)                                          \
        FN##b[ni] = *(const bf16x8*)(Bb[sl] + (bbase + ni * 16) * 32 + cofs); \
      _Pragma("unroll")                                                       \
      for (int mi = 0; mi < 4; ++mi)                                          \
        FN##a[mi] = *(const bf16x8*)(Ab[sl] + (abase + mi * 16) * 32 + cofs); \
    }                                                                         \
    __builtin_amdgcn_sched_barrier(0);                                        \
    __builtin_amdgcn_s_setprio(1);                                            \
    _Pragma("unroll")                                                         \
    for (int mi = 0; mi < 4; ++mi)                                            \
      _Pragma("unroll")                                                       \
      for (int ni = 0; ni < 4; ++ni)                                          \
        acc[mi][ni] = __builtin_amdgcn_mfma_f32_16x16x32_bf16(                \
            FC##a[mi], FC##b[ni], acc[mi][ni], 0, 0, 0);                      \
    __builtin_amdgcn_s_setprio(0);                                            \
  }

#pragma unroll 1
  for (int t = 0; t < 32; t += 2) {
    KSTEP(f0, f1, t);
    KSTEP(f1, f0, t + 1);
  }
#undef KSTEP

  // ---- epilogue
  const int rowbase  = tileM + wm * 64 + ((lane >> 4) << 2);
  const int colbase0 = wn * 64 + (lane & 15);

  if constexpr (MODE == 0) {
    const bool second = tileN >= 1024;
    ushort* Cp = (ushort*)(second ? C2 : C1);
    const float* bb = second ? bias2 : bias1;
    const int cb = tileN - (second ? 1024 : 0) + colbase0;
#pragma unroll
    for (int ni = 0; ni < 4; ++ni) {
      const int col = cb + ni * 16;
      const float bv = bb[col];
#pragma unroll
      for (int mi = 0; mi < 4; ++mi)
#pragma unroll
        for (int r = 0; r < 4; ++r)
          Cp[(long)(rowbase + mi * 16 + r) * 1024 + col] = f2bf(acc[mi][ni][r] + bv);
    }
  } else if constexpr (MODE == 1) {
    ushort* Cp = (ushort*)C1;
    const int cb = tileN + colbase0;
#pragma unroll
    for (int ni = 0; ni < 4; ++ni) {
      const int col = cb + ni * 16;
      const float bv = bias1[col];
#pragma unroll
      for (int mi = 0; mi < 4; ++mi)
#pragma unroll
        for (int r = 0; r < 4; ++r)
          Cp[(long)(rowbase + mi * 16 + r) * 1024 + col] = f2bf(__expf(acc[mi][ni][r] + bv));
    }
  } else if constexpr (MODE == 2) {
    ushort* Cp = (ushort*)C1 + ((long)(bz & 1) * B_ + (bz >> 1)) * ((long)D_ * D_);
    const int cb = tileN + colbase0;
#pragma unroll
    for (int ni = 0; ni < 4; ++ni) {
      const int col = cb + ni * 16;
#pragma unroll
      for (int mi = 0; mi < 4; ++mi)
#pragma unroll
        for (int r = 0; r < 4; ++r)
          Cp[(long)(rowbase + mi * 16 + r) * 1024 + col] = f2bf(acc[mi][ni][r]);
    }
  } else {
    float* Cp = (float*)C1 + (long)bz * sCz;
    const int cb = tileN + colbase0;
#pragma unroll
    for (int ni = 0; ni < 4; ++ni) {
      const int col = cb + ni * 16;
#pragma unroll
      for (int mi = 0; mi < 4; ++mi)
#pragma unroll
        for (int r = 0; r < 4; ++r)
          Cp[(long)(rowbase + mi * 16 + r) * 1024 + col] = acc[mi][ni][r];
    }
  }
}

// MT2[b][d][e] = (p0+p1) * cinv[b][e] ; 8 elems/thread over B_*NW.
__global__ __launch_bounds__(256)
void reduce2_scale(const ushort* __restrict__ P, const float* __restrict__ cinv,
                   ushort* __restrict__ MT)
{
  const long stride = (long)B_ * D_ * D_;
  const long base = ((long)blockIdx.x * 256 + threadIdx.x) * 8;
  const int b = (int)(base >> 20);            // NW = 2^20
  const int e0 = (int)(base & (D_ - 1));
  bf16x8 p0 = *(const bf16x8*)(P + base);
  bf16x8 p1 = *(const bf16x8*)(P + stride + base);
  const float4 c0 = *(const float4*)(cinv + (long)b * D_ + e0);
  const float4 c1 = *(const float4*)(cinv + (long)b * D_ + e0 + 4);
  const float cc[8] = {c0.x, c0.y, c0.z, c0.w, c1.x, c1.y, c1.z, c1.w};
  bf16x8 o;
#pragma unroll
  for (int j = 0; j < 8; ++j)
    o[j] = (short)f2bf((bf2f((ushort)p0[j]) + bf2f((ushort)p1[j])) * cc[j]);
  *(bf16x8*)(MT + base) = o;
}

// row softmax, no max subtraction (|logits| bounded ~3). bf16 in/out in place.
__global__ __launch_bounds__(256)
void softmax_row(ushort* __restrict__ S)
{
  const long base = (long)blockIdx.x * D_;
  const int tid = threadIdx.x;
  float e[4], s = 0.f;
#pragma unroll
  for (int i = 0; i < 4; ++i) { e[i] = __expf(bf2f(S[base + i * 256 + tid])); s += e[i]; }
#pragma unroll
  for (int off = 32; off; off >>= 1) s += __shfl_xor(s, off);
  __shared__ float reds[4];
  if ((tid & 63) == 0) reds[tid >> 6] = s;
  __syncthreads();
  s = reds[0] + reds[1] + reds[2] + reds[3];
  const float inv = 1.f / s;
#pragma unroll
  for (int i = 0; i < 4; ++i)
    S[base + i * 256 + tid] = f2bf(e[i] * inv);
}

// merged transpose of l and ov: z in [0,B_): bufB->xBf ; [B_,2B_): bufA->scr. [T][D]->[D][T]
__global__ __launch_bounds__(256)
void transpose2(const ushort* __restrict__ l, ushort* __restrict__ lT,
                const ushort* __restrict__ ov, ushort* __restrict__ ovT)
{
  __shared__ alignas(16) ushort t[64 * 65];
  const int z = blockIdx.z;
  const int b = z & (B_ - 1);
  const ushort* in = (z < B_ ? l : ov) + (long)b * T_ * D_;
  ushort* out      = (z < B_ ? lT : ovT) + (long)b * (long)D_ * T_;
  const int c0 = blockIdx.x * 64, r0 = blockIdx.y * 64;
  const int tx = threadIdx.x & 15, ty = threadIdx.x >> 4;
#pragma unroll
  for (int i = 0; i < 4; ++i) {
    const int r = ty + i * 16;
    u16x4 v = *(const u16x4*)(in + (long)(r0 + r) * D_ + c0 + tx * 4);
#pragma unroll
    for (int c = 0; c < 4; ++c) t[(tx * 4 + c) * 65 + r] = v[c];
  }
  __syncthreads();
#pragma unroll
  for (int i = 0; i < 4; ++i) {
    const int c = ty + i * 16;
    u16x4 v;
#pragma unroll
    for (int j = 0; j < 4; ++j) v[j] = t[c * 65 + tx * 4 + j];
    *(u16x4*)(out + (long)(c0 + c) * T_ + r0 + tx * 4) = v;
  }
}

// column sums of E over T_ rows, chunked. grid (D_/256, 16, B_).
__global__ __launch_bounds__(256)
void colsum_part(const ushort* __restrict__ E, float* __restrict__ psum)
{
  const int d = blockIdx.x * 256 + threadIdx.x;
  const int c = blockIdx.y;
  const int b = blockIdx.z;
  const ushort* p = E + ((long)b * T_ + (long)c * 128) * D_ + d;
  float s = 0.f;
#pragma unroll 4
  for (int r = 0; r < 128; ++r) s += bf2f(p[(long)r * D_]);
  psum[((long)b * 16 + c) * D_ + d] = s;
}

// cinv = 1/sum over chunks. grid (D_/256, B_).
__global__ __launch_bounds__(256)
void colsum_comb(const float* __restrict__ psum, float* __restrict__ cinv)
{
  const int d = blockIdx.x * 256 + threadIdx.x;
  const int b = blockIdx.y;
  float s = 0.f;
#pragma unroll
  for (int c = 0; c < 16; ++c) s += psum[((long)b * 16 + c) * D_ + d];
  cinv[(long)b * D_ + d] = 1.f / s;
}

extern "C" void kernel_launch(void* const* d_in, const int* in_sizes, int n_in,
                              void* d_out, int out_size, void* d_ws, size_t ws_size,
                              hipStream_t stream)
{
  (void)in_sizes; (void)n_in; (void)out_size; (void)ws_size;
  const float* lat = (const float*)d_in[0];
  const float* inp = (const float*)d_in[1];
  const float* Wl  = (const float*)d_in[2];
  const float* bl  = (const float*)d_in[3];
  const float* Wu  = (const float*)d_in[4];
  const float* bu  = (const float*)d_in[5];
  const float* WA  = (const float*)d_in[6];
  const float* bA  = (const float*)d_in[7];
  const float* WV  = (const float*)d_in[8];
  const float* bV  = (const float*)d_in[9];
  const float* Wo  = (const float*)d_in[10];
  const float* bo  = (const float*)d_in[11];

  char* w = (char*)d_ws;
  auto carve = [&](size_t bytes) { char* p = w; w += (bytes + 255) & ~(size_t)255; return p; };
  const long NT = (long)B_ * T_ * D_;
  const long NW = (long)D_ * D_;
  ushort* xBf   = (ushort*)carve(NT * 2);
  ushort* xBf2  = (ushort*)carve(NT * 2);
  ushort* bufA  = (ushort*)carve(NT * 2);
  ushort* bufB  = (ushort*)carve(NT * 2);
  ushort* scr   = (ushort*)carve(NT * 2);
  ushort* MT    = (ushort*)carve((long)B_ * NW * 2);
  ushort* wCat  = (ushort*)carve(3 * NW * 2);
  float*  bc    = (float*)carve(D_ * 4);
  float*  bc2   = (float*)carve(D_ * 4);
  float*  psum  = (float*)carve(64 * 1024 * 4);
  float*  cinv  = (float*)carve(8 * 1024 * 4);
  ushort* w1 = scr;            // [Wu_bf ; WV_bf]
  ushort* w2 = scr + 2 * NW;   // [WlT ; WAT]
  ushort* ovT = scr;           // after weight-compose, scr is dead -> ovT
  ushort* part = bufB;         // after l transposed out, bufB is dead -> splitk partials

  const dim3 blk(256, 1, 1);
  const dim3 blk5(512, 1, 1);

  // 1. fused prep
  prep<<<dim3(20480), blk, 0, stream>>>(lat, inp, Wl, bl, Wu, bu, WA, bA, WV, bV, Wo, bo,
                                        xBf, xBf2, w1, w2, wCat + NW, bc, bc2);
  // 2. weight compose: z0: Wc=Wu·Wl -> wCat[0]; z1: Wc2=WV·WA -> wCat[2NW]
  gemm_nt<false, false, false><<<dim3(8, 8, 2), blk, 0, stream>>>(
      w1, w2, nullptr, wCat, D_, D_, NW, NW, 2 * NW);
  // 3. S1 (bufB) + ov (bufA) in one N=2048 GEMM over [Wc ; Wo]
  gemm8<0><<<dim3(16, 32, 1), blk5, 0, stream>>>(
      xBf, wCat, bc, bo, bufB, bufA, D_, D_, 0, 0, 0);
  // 4. l = row-softmax(S1), in place
  softmax_row<<<dim3(B_ * T_), blk, 0, stream>>>(bufB);
  // 5. lT (bufB->xBf) + ovT (bufA->scr), one launch
  transpose2<<<dim3(16, 32, 2 * B_), blk, 0, stream>>>(bufB, xBf, bufA, ovT);
  // 6. MT partials: MT[d,e] = sum_q ovT[d,q]·lT[e,q], split-K=2 -> bufB
  gemm8<2><<<dim3(8, 4, 8), blk5, 0, stream>>>(
      ovT, xBf, nullptr, nullptr, part, nullptr, T_, T_, (long)D_ * T_, (long)D_ * T_, 0);
  // 7. E = exp(inp @ Wc2^T + bc2) -> bufA
  gemm8<1><<<dim3(8, 32, 1), blk5, 0, stream>>>(
      xBf2, wCat + 2 * NW, bc2, nullptr, bufA, nullptr, D_, D_, 0, 0, 0);
  // 8-9. column sums of E -> cinv
  colsum_part<<<dim3(4, 16, B_), blk, 0, stream>>>(bufA, psum);
  colsum_comb<<<dim3(4, B_, 1), blk, 0, stream>>>(psum, cinv);
  // 10. MT2 = (partial sum) * cinv[e]
  reduce2_scale<<<dim3(2048), blk, 0, stream>>>(part, cinv, MT);
  // 11. o = E @ MT2^T -> d_out (fp32)
  gemm8<3><<<dim3(8, 8, 4), blk5, 0, stream>>>(
      bufA, MT, nullptr, nullptr, d_out, nullptr, D_, D_,
      (long)T_ * D_, NW, (long)T_ * D_);
}

// Round 3
// 323.289 us; speedup vs baseline: 1.1112x; 1.1112x over previous
//
#include <hip/hip_runtime.h>
#include <hip/hip_bf16.h>
#include <stdint.h>

typedef __attribute__((ext_vector_type(8))) short bf16x8;
typedef __attribute__((ext_vector_type(4))) float f32x4;
typedef __attribute__((ext_vector_type(4))) unsigned short u16x4;

#define B_  4
#define T_  2048
#define D_  1024
#define BM  128
#define BN  128
#define BK  32

__device__ __forceinline__ float bf2f(ushort u) {
  union { unsigned int i; float f; } v; v.i = ((unsigned int)u) << 16; return v.f;
}
__device__ __forceinline__ ushort f2bf(float f) {
  return (ushort)(__bfloat16_as_ushort(__float2bfloat16(f)));
}
__device__ __forceinline__ void async16(const void* g, void* l) {
  __builtin_amdgcn_global_load_lds(
      (const __attribute__((address_space(1))) void*)g,
      (__attribute__((address_space(3))) void*)l, 16, 0, 0);
}
__device__ __forceinline__ int swz4(int r) { return (r ^ (r >> 2)) & 3; }

// ---------------- fused prep ----------------
__global__ __launch_bounds__(256)
void prep(const float* __restrict__ lat, const float* __restrict__ inp,
          const float* __restrict__ Wl, const float* __restrict__ bl,
          const float* __restrict__ Wu, const float* __restrict__ bu,
          const float* __restrict__ WA, const float* __restrict__ bA,
          const float* __restrict__ WV, const float* __restrict__ bV,
          const float* __restrict__ Wo, const float* __restrict__ bo,
          ushort* __restrict__ xBf, ushort* __restrict__ xBf2,
          ushort* __restrict__ w1, ushort* __restrict__ w2,
          ushort* __restrict__ wCatWo, float* __restrict__ bc, float* __restrict__ bc2)
{
  __shared__ alignas(16) ushort t[64 * 65];
  const long NW = (long)D_ * D_;
  const int bx = blockIdx.x;
  const int tid = threadIdx.x;
  if (bx < 16384) {
    const float* in = bx < 8192 ? lat : inp;
    ushort* out = bx < 8192 ? xBf : xBf2;
    const long i = (long)(bx & 8191) * 256 + tid;
    const float4 v = *(const float4*)(in + i * 4);
    u16x4 o;
    o[0] = f2bf(v.x); o[1] = f2bf(v.y); o[2] = f2bf(v.z); o[3] = f2bf(v.w);
    *(u16x4*)(out + i * 4) = o;
  } else if (bx < 19456) {
    const int seg = (bx - 16384) >> 10;
    const float* in  = seg == 0 ? Wu : (seg == 1 ? WV : Wo);
    ushort* out = seg == 0 ? w1 : (seg == 1 ? w1 + NW : wCatWo);
    const long i = (long)((bx - 16384) & 1023) * 256 + tid;
    const float4 v = *(const float4*)(in + i * 4);
    u16x4 o;
    o[0] = f2bf(v.x); o[1] = f2bf(v.y); o[2] = f2bf(v.z); o[3] = f2bf(v.w);
    *(u16x4*)(out + i * 4) = o;
  } else if (bx < 19968) {
    const int z = (bx - 19456) >> 8;
    const int w = (bx - 19456) & 255;
    const float* in = z ? WA : Wl;
    ushort* out = z ? w2 + NW : w2;
    const int c0 = (w & 15) * 64, r0 = (w >> 4) * 64;
    const int tx = tid & 15, ty = tid >> 4;
#pragma unroll
    for (int i = 0; i < 4; ++i) {
      const int r = ty + i * 16;
      const float4 v = *(const float4*)(in + (long)(r0 + r) * D_ + c0 + tx * 4);
      t[(tx * 4 + 0) * 65 + r] = f2bf(v.x);
      t[(tx * 4 + 1) * 65 + r] = f2bf(v.y);
      t[(tx * 4 + 2) * 65 + r] = f2bf(v.z);
      t[(tx * 4 + 3) * 65 + r] = f2bf(v.w);
    }
    __syncthreads();
#pragma unroll
    for (int i = 0; i < 4; ++i) {
      const int c = ty + i * 16;
      u16x4 v;
#pragma unroll
      for (int j = 0; j < 4; ++j) v[j] = t[c * 65 + tx * 4 + j];
      *(u16x4*)(out + (long)(c0 + c) * D_ + r0 + tx * 4) = v;
    }
  } else {
    const int z = (bx - 19968) >> 8;
    const int w = (bx - 19968) & 255;
    const float* W    = z ? WV : Wu;
    const float* bin  = z ? bA : bl;
    const float* badd = z ? bV : bu;
    float* out        = z ? bc2 : bc;
    const int wv = tid >> 6, lane = tid & 63;
    const int e = w * 4 + wv;
    const float* row = W + (long)e * D_;
    float s = 0.f;
#pragma unroll
    for (int i = 0; i < 16; ++i) s += row[lane + i * 64] * bin[lane + i * 64];
#pragma unroll
    for (int off = 32; off; off >>= 1) s += __shfl_xor(s, off);
    if (lane == 0) out[e] = s + badd[e];
  }
}

// ---------------- small 128^2 GEMM (weight-compose only) ----------
template<bool OUT_F32, bool HAS_BIAS, bool EXP_OUT>
__global__ __launch_bounds__(256, 2)
void gemm_nt(const ushort* __restrict__ A, const ushort* __restrict__ B,
             const float* __restrict__ bias, void* __restrict__ C,
             int N, int K, long sA, long sB, long sC)
{
  __shared__ alignas(16) ushort As[BM * BK];
  __shared__ alignas(16) ushort Bs[BN * BK];
  const int tid  = threadIdx.x;
  const int wave = tid >> 6;
  const int lane = tid & 63;
  const int wm   = wave >> 1;
  const int wn   = wave & 1;
  const int bz   = blockIdx.z;
  const int tileN = blockIdx.x * BN;
  const int tileM = blockIdx.y * BM;
  A += (long)bz * sA;
  B += (long)bz * sB;

  const int lrow   = lane >> 2;
  const int lchunk = (lane & 3) ^ swz4(lrow);

  f32x4 acc[4][4];
#pragma unroll
  for (int i = 0; i < 4; ++i)
#pragma unroll
    for (int j = 0; j < 4; ++j) acc[i][j] = (f32x4){0.f, 0.f, 0.f, 0.f};

  const int frow = lane & 15;
  const int kg   = lane >> 4;
  const int coff = ((kg ^ swz4(frow)) << 3);

  for (int kt = 0; kt < K; kt += BK) {
    __syncthreads();
#pragma unroll
    for (int i = 0; i < 2; ++i) {
      const int rg  = wave * 2 + i;
      const int row = rg * 16 + lrow;
      async16(A + (long)(tileM + row) * K + kt + lchunk * 8, (void*)(As + rg * 16 * BK));
      async16(B + (long)(tileN + row) * K + kt + lchunk * 8, (void*)(Bs + rg * 16 * BK));
    }
    __syncthreads();
    bf16x8 af[4], bfr[4];
#pragma unroll
    for (int mi = 0; mi < 4; ++mi)
      af[mi] = *(const bf16x8*)(As + (wm * 64 + mi * 16 + frow) * BK + coff);
#pragma unroll
    for (int ni = 0; ni < 4; ++ni)
      bfr[ni] = *(const bf16x8*)(Bs + (wn * 64 + ni * 16 + frow) * BK + coff);
#pragma unroll
    for (int mi = 0; mi < 4; ++mi)
#pragma unroll
      for (int ni = 0; ni < 4; ++ni)
        acc[mi][ni] = __builtin_amdgcn_mfma_f32_16x16x32_bf16(af[mi], bfr[ni], acc[mi][ni], 0, 0, 0);
  }

  const int rowbase = tileM + wm * 64 + ((lane >> 4) << 2);
  const int colbase = tileN + wn * 64 + (lane & 15);
#pragma unroll
  for (int ni = 0; ni < 4; ++ni) {
    const int col = colbase + ni * 16;
    float bv = 0.f;
    if constexpr (HAS_BIAS) bv = bias[col];
#pragma unroll
    for (int mi = 0; mi < 4; ++mi) {
#pragma unroll
      for (int r = 0; r < 4; ++r) {
        const int row = rowbase + mi * 16 + r;
        float v = acc[mi][ni][r] + bv;
        if constexpr (EXP_OUT) v = __expf(v);
        const long idx = (long)bz * sC + (long)row * N + col;
        if constexpr (OUT_F32) ((float*)C)[idx] = v;
        else ((ushort*)C)[idx] = f2bf(v);
      }
    }
  }
}

// =============== 256x256 BK=64 pipelined GEMM (dual output) ===============
// C = A·B^T, K=1024 (16 K-tiles of 64). 512 thr / 8 waves (2M x 4N),
// wave output 128x64 with M interleaved at 64-granularity (A-halves free
// after 2 of 4 phases). LDS: 2-buf x (A 32KB + B 32KB) = 128KB.
// Per K-tile: 4 phases (qM x k-half), 2 barriers, counted vmcnt(6)/vmcnt(2),
// stages issued AFTER the barrier (overwrite-safe by barrier ordering),
// 4-phase issue->wait distance (~2500cyc). Swizzled via pre-swizzled source.
__global__ __launch_bounds__(512, 2)
void gemm256(const ushort* __restrict__ A, const ushort* __restrict__ Bm,
             const float* __restrict__ bias1, const float* __restrict__ bias2,
             ushort* __restrict__ C1, ushort* __restrict__ C2,
             int ldA, int ldB)
{
  __shared__ alignas(16) ushort AbS[2 * 16384];
  __shared__ alignas(16) ushort BbS[2 * 16384];

  const int gx = gridDim.x, gy = gridDim.y;
  const int nwg = gx * gy;
  int fid = blockIdx.y * gx + blockIdx.x;
  fid = (fid & 7) * (nwg >> 3) + (fid >> 3);
  const int bx = fid % gx;
  const int by = fid / gx;
  const int tileM = by * 256, tileN = bx * 256;

  const int tid  = threadIdx.x;
  const int wid  = tid >> 6;
  const int lane = tid & 63;
  const int wm   = wid >> 2;          // 2 waves along M
  const int wn   = wid & 3;           // 4 waves along N

  // staging addresses (source pre-swizzled, LDS dest linear)
  const int srow = tid >> 2;
  const int sc   = (((tid & 3) ^ ((tid >> 3) & 3)) << 3);
  const ushort* gA[2] = { A  + (long)(tileM + srow) * ldA + sc,
                          A  + (long)(tileM + 128 + srow) * ldA + sc };
  const ushort* gB[2] = { Bm + (long)(tileN + srow) * ldB + sc,
                          Bm + (long)(tileN + 128 + srow) * ldB + sc };
  const int dofs = tid << 3;          // LDS elems

  // fragment read offsets. region: half*8192 + kh*4096 + r*32 + chunk*8
  const int frow = lane & 15;
  const int cofs = (((lane >> 4) ^ ((lane >> 1) & 3)) << 3);
  int aoff[8], boff[4];
#pragma unroll
  for (int f = 0; f < 8; ++f) {
    const int r = wm * 64 + (f & 3) * 16 + frow;        // in [0,128)
    aoff[f] = ((f >> 2) << 13) + (r << 5) + cofs;
  }
#pragma unroll
  for (int n = 0; n < 4; ++n) {
    const int row = wn * 64 + n * 16 + frow;            // in [0,256)
    boff[n] = ((row >> 7) << 13) + ((row & 127) << 5) + cofs;
  }

#define STA256(b, h, kh, kt) async16(gA[h] + (long)(kt) * 64 + (kh) * 32, \
    AbS + (b) * 16384 + (h) * 8192 + (kh) * 4096 + dofs)
#define STB256(b, h, kh, kt) async16(gB[h] + (long)(kt) * 64 + (kh) * 32, \
    BbS + (b) * 16384 + (h) * 8192 + (kh) * 4096 + dofs)

  f32x4 acc[8][4];
#pragma unroll
  for (int i = 0; i < 8; ++i)
#pragma unroll
    for (int j = 0; j < 4; ++j) acc[i][j] = (f32x4){0.f, 0.f, 0.f, 0.f};

  // prologue: tiles 0,1 fully staged, full drain once
#pragma unroll
  for (int p = 0; p < 2; ++p) {
    STA256(p, 0, 0, p); STA256(p, 0, 1, p); STA256(p, 1, 0, p); STA256(p, 1, 1, p);
    STB256(p, 0, 0, p); STB256(p, 0, 1, p); STB256(p, 1, 0, p); STB256(p, 1, 1, p);
  }
  asm volatile("s_waitcnt vmcnt(0)" ::: "memory");
  __builtin_amdgcn_s_barrier();

#pragma unroll 1
  for (int t = 0; t < 16; ++t) {
    const int buf = t & 1;
    const ushort* Ac = AbS + buf * 16384;
    const ushort* Bc = BbS + buf * 16384;
    bf16x8 fa[4], fb[4];

    // ---- ph0: A-lo k0 + B k0 ; vmcnt(6) ; barrier ; stage A-hi(t+1)
#pragma unroll
    for (int n = 0; n < 4; ++n) fb[n] = *(const bf16x8*)(Bc + boff[n]);
#pragma unroll
    for (int f = 0; f < 4; ++f) fa[f] = *(const bf16x8*)(Ac + aoff[f]);
    if (t == 15) asm volatile("s_waitcnt vmcnt(0)" ::: "memory");
    else         asm volatile("s_waitcnt vmcnt(6)" ::: "memory");
    __builtin_amdgcn_s_barrier();
    __builtin_amdgcn_sched_barrier(0);
    if (t >= 1 && t <= 14) { STA256(buf ^ 1, 1, 0, t + 1); STA256(buf ^ 1, 1, 1, t + 1); }
    __builtin_amdgcn_s_setprio(1);
#pragma unroll
    for (int f = 0; f < 4; ++f)
#pragma unroll
      for (int n = 0; n < 4; ++n)
        acc[f][n] = __builtin_amdgcn_mfma_f32_16x16x32_bf16(fa[f], fb[n], acc[f][n], 0, 0, 0);
    __builtin_amdgcn_s_setprio(0);

    // ---- ph1: A-hi k0 (B k0 reused)
    bf16x8 ga[4];
#pragma unroll
    for (int f = 0; f < 4; ++f) ga[f] = *(const bf16x8*)(Ac + aoff[4 + f]);
    __builtin_amdgcn_s_setprio(1);
#pragma unroll
    for (int f = 0; f < 4; ++f)
#pragma unroll
      for (int n = 0; n < 4; ++n)
        acc[4 + f][n] = __builtin_amdgcn_mfma_f32_16x16x32_bf16(ga[f], fb[n], acc[4 + f][n], 0, 0, 0);
    __builtin_amdgcn_s_setprio(0);

    // ---- ph2: A-lo k1 + B k1
#pragma unroll
    for (int n = 0; n < 4; ++n) fb[n] = *(const bf16x8*)(Bc + boff[n] + 4096);
#pragma unroll
    for (int f = 0; f < 4; ++f) fa[f] = *(const bf16x8*)(Ac + aoff[f] + 4096);
    __builtin_amdgcn_s_setprio(1);
#pragma unroll
    for (int f = 0; f < 4; ++f)
#pragma unroll
      for (int n = 0; n < 4; ++n)
        acc[f][n] = __builtin_amdgcn_mfma_f32_16x16x32_bf16(fa[f], fb[n], acc[f][n], 0, 0, 0);
    __builtin_amdgcn_s_setprio(0);

    // ---- ph3: A-hi k1 ; vmcnt(2) ; barrier ; stage A-lo/B-lo/B-hi(t+2)
#pragma unroll
    for (int f = 0; f < 4; ++f) ga[f] = *(const bf16x8*)(Ac + aoff[4 + f] + 4096);
    if (t >= 1 && t <= 14) asm volatile("s_waitcnt vmcnt(2)" ::: "memory");
    __builtin_amdgcn_s_barrier();
    __builtin_amdgcn_sched_barrier(0);
    if (t <= 13) {
      STA256(buf, 0, 0, t + 2); STA256(buf, 0, 1, t + 2);
      STB256(buf, 0, 0, t + 2); STB256(buf, 0, 1, t + 2);
      STB256(buf, 1, 0, t + 2); STB256(buf, 1, 1, t + 2);
    }
    __builtin_amdgcn_s_setprio(1);
#pragma unroll
    for (int f = 0; f < 4; ++f)
#pragma unroll
      for (int n = 0; n < 4; ++n)
        acc[4 + f][n] = __builtin_amdgcn_mfma_f32_16x16x32_bf16(ga[f], fb[n], acc[4 + f][n], 0, 0, 0);
    __builtin_amdgcn_s_setprio(0);
  }
#undef STA256
#undef STB256

  // ---- epilogue (dual bf16 out)
  const bool second = tileN >= 1024;
  ushort* Cp = second ? C2 : C1;
  const float* bb = second ? bias2 : bias1;
  const int cb = tileN - (second ? 1024 : 0) + wn * 64 + (lane & 15);
#pragma unroll
  for (int mi = 0; mi < 8; ++mi) {
    const int mrow = tileM + wm * 64 + ((mi & 3) << 4) + ((mi >> 2) << 7) + ((lane >> 4) << 2);
#pragma unroll
    for (int ni = 0; ni < 4; ++ni) {
      const int col = cb + ni * 16;
      const float bv = bb[col];
#pragma unroll
      for (int r = 0; r < 4; ++r)
        Cp[(long)(mrow + r) * 1024 + col] = f2bf(acc[mi][ni][r] + bv);
    }
  }
}

// =============== 256x128 BK=64 pipelined GEMM, 3-deep ring ===============
// 512 thr / 8 waves (4M x 2N), wave output 64x64. LDS ring 3 x (A 32KB +
// B 16KB) = 144KB. 2 phases per K-tile (k-halves), 2 barriers, vmcnt(6)@ph1,
// stage tile t+2 at ph0 (3-phase issue->wait distance).
// MODE: 1 = bf16 out, bias+exp ; 2 = bf16 splitK partial ; 3 = f32 out batched
template<int MODE>
__global__ __launch_bounds__(512, 2)
void gemm128(const ushort* __restrict__ A, const ushort* __restrict__ Bm,
             const float* __restrict__ bias1, void* __restrict__ C1,
             int ldA, int ldB, long sAz, long sBz, long sCz)
{
  __shared__ alignas(16) ushort AbS[3 * 16384];
  __shared__ alignas(16) ushort BbS[3 * 8192];

  const int gx = gridDim.x, gy = gridDim.y;
  const int nwg = gx * gy * gridDim.z;
  int fid = (blockIdx.z * gy + blockIdx.y) * gx + blockIdx.x;
  fid = (fid & 7) * (nwg >> 3) + (fid >> 3);
  const int bx = fid % gx;
  const int by = (fid / gx) % gy;
  const int bz = fid / (gx * gy);
  const int tileM = by * 256, tileN = bx * 128;

  const ushort* Ap = A;
  const ushort* Bp = Bm;
  if constexpr (MODE == 2) {
    Ap += (long)(bz >> 1) * sAz + (long)(bz & 1) * 1024;
    Bp += (long)(bz >> 1) * sBz + (long)(bz & 1) * 1024;
  } else {
    Ap += (long)bz * sAz;
    Bp += (long)bz * sBz;
  }

  const int tid  = threadIdx.x;
  const int wid  = tid >> 6;
  const int lane = tid & 63;
  const int wm   = wid >> 1;          // 4 waves along M
  const int wn   = wid & 1;           // 2 waves along N

  const int srow = tid >> 2;
  const int sc   = (((tid & 3) ^ ((tid >> 3) & 3)) << 3);
  const ushort* gA[2] = { Ap + (long)(tileM + srow) * ldA + sc,
                          Ap + (long)(tileM + 128 + srow) * ldA + sc };
  const ushort* gB    =   Bp + (long)(tileN + srow) * ldB + sc;
  const int dofs = tid << 3;

  const int frow = lane & 15;
  const int cofs = (((lane >> 4) ^ ((lane >> 1) & 3)) << 3);
  int aoff[4], boff[4];
#pragma unroll
  for (int f = 0; f < 4; ++f) {
    const int row = wm * 64 + f * 16 + frow;            // [0,256)
    aoff[f] = ((row >> 7) << 13) + ((row & 127) << 5) + cofs;
  }
#pragma unroll
  for (int n = 0; n < 4; ++n) {
    const int row = wn * 64 + n * 16 + frow;            // [0,128)
    boff[n] = (row << 5) + cofs;
  }

#define STA128(b, h, kh, kt) async16(gA[h] + (long)(kt) * 64 + (kh) * 32, \
    AbS + (b) * 16384 + (h) * 8192 + (kh) * 4096 + dofs)
#define STB128(b, kh, kt) async16(gB + (long)(kt) * 64 + (kh) * 32, \
    BbS + (b) * 8192 + (kh) * 4096 + dofs)
#define STAGE_TILE(b, kt) { STA128(b, 0, 0, kt); STA128(b, 0, 1, kt); \
    STA128(b, 1, 0, kt); STA128(b, 1, 1, kt); STB128(b, 0, kt); STB128(b, 1, kt); }

  f32x4 acc[4][4];
#pragma unroll
  for (int i = 0; i < 4; ++i)
#pragma unroll
    for (int j = 0; j < 4; ++j) acc[i][j] = (f32x4){0.f, 0.f, 0.f, 0.f};

  // prologue
  STAGE_TILE(0, 0);
  STAGE_TILE(1, 1);
  asm volatile("s_waitcnt vmcnt(0)" ::: "memory");
  __builtin_amdgcn_s_barrier();

#pragma unroll 1
  for (int t = 0; t < 16; ++t) {
    const int buf = t - (t / 3) * 3;                    // t % 3
    const int nb  = (t + 2) - ((t + 2) / 3) * 3;        // (t+2) % 3
    const ushort* Ac = AbS + buf * 16384;
    const ushort* Bc = BbS + buf * 8192;
    bf16x8 fa[4], fb[4];

    // ---- ph0: k0 ; barrier ; stage tile t+2
#pragma unroll
    for (int n = 0; n < 4; ++n) fb[n] = *(const bf16x8*)(Bc + boff[n]);
#pragma unroll
    for (int f = 0; f < 4; ++f) fa[f] = *(const bf16x8*)(Ac + aoff[f]);
    __builtin_amdgcn_s_barrier();
    __builtin_amdgcn_sched_barrier(0);
    if (t <= 13) STAGE_TILE(nb, t + 2);
    __builtin_amdgcn_s_setprio(1);
#pragma unroll
    for (int f = 0; f < 4; ++f)
#pragma unroll
      for (int n = 0; n < 4; ++n)
        acc[f][n] = __builtin_amdgcn_mfma_f32_16x16x32_bf16(fa[f], fb[n], acc[f][n], 0, 0, 0);
    __builtin_amdgcn_s_setprio(0);

    // ---- ph1: k1 ; vmcnt ; barrier
#pragma unroll
    for (int n = 0; n < 4; ++n) fb[n] = *(const bf16x8*)(Bc + boff[n] + 4096);
#pragma unroll
    for (int f = 0; f < 4; ++f) fa[f] = *(const bf16x8*)(Ac + aoff[f] + 4096);
    if (t <= 13)      asm volatile("s_waitcnt vmcnt(6)" ::: "memory");
    else if (t == 14) asm volatile("s_waitcnt vmcnt(0)" ::: "memory");
    __builtin_amdgcn_s_barrier();
    __builtin_amdgcn_sched_barrier(0);
    __builtin_amdgcn_s_setprio(1);
#pragma unroll
    for (int f = 0; f < 4; ++f)
#pragma unroll
      for (int n = 0; n < 4; ++n)
        acc[f][n] = __builtin_amdgcn_mfma_f32_16x16x32_bf16(fa[f], fb[n], acc[f][n], 0, 0, 0);
    __builtin_amdgcn_s_setprio(0);
  }
#undef STA128
#undef STB128
#undef STAGE_TILE

  // ---- epilogue
  const int cb = tileN + wn * 64 + (lane & 15);
  const int rb = tileM + wm * 64 + ((lane >> 4) << 2);

  if constexpr (MODE == 1) {
    ushort* Cp = (ushort*)C1;
#pragma unroll
    for (int ni = 0; ni < 4; ++ni) {
      const int col = cb + ni * 16;
      const float bv = bias1[col];
#pragma unroll
      for (int mi = 0; mi < 4; ++mi)
#pragma unroll
        for (int r = 0; r < 4; ++r)
          Cp[(long)(rb + mi * 16 + r) * 1024 + col] = f2bf(__expf(acc[mi][ni][r] + bv));
    }
  } else if constexpr (MODE == 2) {
    ushort* Cp = (ushort*)C1 + ((long)(bz & 1) * B_ + (bz >> 1)) * ((long)D_ * D_);
#pragma unroll
    for (int ni = 0; ni < 4; ++ni) {
      const int col = cb + ni * 16;
#pragma unroll
      for (int mi = 0; mi < 4; ++mi)
#pragma unroll
        for (int r = 0; r < 4; ++r)
          Cp[(long)(rb + mi * 16 + r) * 1024 + col] = f2bf(acc[mi][ni][r]);
    }
  } else {
    float* Cp = (float*)C1 + (long)bz * sCz;
#pragma unroll
    for (int ni = 0; ni < 4; ++ni) {
      const int col = cb + ni * 16;
#pragma unroll
      for (int mi = 0; mi < 4; ++mi)
#pragma unroll
        for (int r = 0; r < 4; ++r)
          Cp[(long)(rb + mi * 16 + r) * 1024 + col] = acc[mi][ni][r];
    }
  }
}

// MT2[b][d][e] = (p0+p1) * cinv[b][e]
__global__ __launch_bounds__(256)
void reduce2_scale(const ushort* __restrict__ P, const float* __restrict__ cinv,
                   ushort* __restrict__ MT)
{
  const long stride = (long)B_ * D_ * D_;
  const long base = ((long)blockIdx.x * 256 + threadIdx.x) * 8;
  const int b = (int)(base >> 20);
  const int e0 = (int)(base & (D_ - 1));
  bf16x8 p0 = *(const bf16x8*)(P + base);
  bf16x8 p1 = *(const bf16x8*)(P + stride + base);
  const float4 c0 = *(const float4*)(cinv + (long)b * D_ + e0);
  const float4 c1 = *(const float4*)(cinv + (long)b * D_ + e0 + 4);
  const float cc[8] = {c0.x, c0.y, c0.z, c0.w, c1.x, c1.y, c1.z, c1.w};
  bf16x8 o;
#pragma unroll
  for (int j = 0; j < 8; ++j)
    o[j] = (short)f2bf((bf2f((ushort)p0[j]) + bf2f((ushort)p1[j])) * cc[j]);
  *(bf16x8*)(MT + base) = o;
}

// row softmax
__global__ __launch_bounds__(256)
void softmax_row(ushort* __restrict__ S)
{
  const long base = (long)blockIdx.x * D_;
  const int tid = threadIdx.x;
  float e[4], s = 0.f;
#pragma unroll
  for (int i = 0; i < 4; ++i) { e[i] = __expf(bf2f(S[base + i * 256 + tid])); s += e[i]; }
#pragma unroll
  for (int off = 32; off; off >>= 1) s += __shfl_xor(s, off);
  __shared__ float reds[4];
  if ((tid & 63) == 0) reds[tid >> 6] = s;
  __syncthreads();
  s = reds[0] + reds[1] + reds[2] + reds[3];
  const float inv = 1.f / s;
#pragma unroll
  for (int i = 0; i < 4; ++i)
    S[base + i * 256 + tid] = f2bf(e[i] * inv);
}

// merged transpose of l and ov
__global__ __launch_bounds__(256)
void transpose2(const ushort* __restrict__ l, ushort* __restrict__ lT,
                const ushort* __restrict__ ov, ushort* __restrict__ ovT)
{
  __shared__ alignas(16) ushort t[64 * 65];
  const int z = blockIdx.z;
  const int b = z & (B_ - 1);
  const ushort* in = (z < B_ ? l : ov) + (long)b * T_ * D_;
  ushort* out      = (z < B_ ? lT : ovT) + (long)b * (long)D_ * T_;
  const int c0 = blockIdx.x * 64, r0 = blockIdx.y * 64;
  const int tx = threadIdx.x & 15, ty = threadIdx.x >> 4;
#pragma unroll
  for (int i = 0; i < 4; ++i) {
    const int r = ty + i * 16;
    u16x4 v = *(const u16x4*)(in + (long)(r0 + r) * D_ + c0 + tx * 4);
#pragma unroll
    for (int c = 0; c < 4; ++c) t[(tx * 4 + c) * 65 + r] = v[c];
  }
  __syncthreads();
#pragma unroll
  for (int i = 0; i < 4; ++i) {
    const int c = ty + i * 16;
    u16x4 v;
#pragma unroll
    for (int j = 0; j < 4; ++j) v[j] = t[c * 65 + tx * 4 + j];
    *(u16x4*)(out + (long)(c0 + c) * T_ + r0 + tx * 4) = v;
  }
}

// column sums of E
__global__ __launch_bounds__(256)
void colsum_part(const ushort* __restrict__ E, float* __restrict__ psum)
{
  const int d = blockIdx.x * 256 + threadIdx.x;
  const int c = blockIdx.y;
  const int b = blockIdx.z;
  const ushort* p = E + ((long)b * T_ + (long)c * 128) * D_ + d;
  float s = 0.f;
#pragma unroll 4
  for (int r = 0; r < 128; ++r) s += bf2f(p[(long)r * D_]);
  psum[((long)b * 16 + c) * D_ + d] = s;
}

__global__ __launch_bounds__(256)
void colsum_comb(const float* __restrict__ psum, float* __restrict__ cinv)
{
  const int d = blockIdx.x * 256 + threadIdx.x;
  const int b = blockIdx.y;
  float s = 0.f;
#pragma unroll
  for (int c = 0; c < 16; ++c) s += psum[((long)b * 16 + c) * D_ + d];
  cinv[(long)b * D_ + d] = 1.f / s;
}

extern "C" void kernel_launch(void* const* d_in, const int* in_sizes, int n_in,
                              void* d_out, int out_size, void* d_ws, size_t ws_size,
                              hipStream_t stream)
{
  (void)in_sizes; (void)n_in; (void)out_size; (void)ws_size;
  const float* lat = (const float*)d_in[0];
  const float* inp = (const float*)d_in[1];
  const float* Wl  = (const float*)d_in[2];
  const float* bl  = (const float*)d_in[3];
  const float* Wu  = (const float*)d_in[4];
  const float* bu  = (const float*)d_in[5];
  const float* WA  = (const float*)d_in[6];
  const float* bA  = (const float*)d_in[7];
  const float* WV  = (const float*)d_in[8];
  const float* bV  = (const float*)d_in[9];
  const float* Wo  = (const float*)d_in[10];
  const float* bo  = (const float*)d_in[11];

  char* w = (char*)d_ws;
  auto carve = [&](size_t bytes) { char* p = w; w += (bytes + 255) & ~(size_t)255; return p; };
  const long NT = (long)B_ * T_ * D_;
  const long NW = (long)D_ * D_;
  ushort* xBf   = (ushort*)carve(NT * 2);
  ushort* xBf2  = (ushort*)carve(NT * 2);
  ushort* bufA  = (ushort*)carve(NT * 2);
  ushort* bufB  = (ushort*)carve(NT * 2);
  ushort* scr   = (ushort*)carve(NT * 2);
  ushort* MT    = (ushort*)carve((long)B_ * NW * 2);
  ushort* wCat  = (ushort*)carve(3 * NW * 2);
  float*  bc    = (float*)carve(D_ * 4);
  float*  bc2   = (float*)carve(D_ * 4);
  float*  psum  = (float*)carve(64 * 1024 * 4);
  float*  cinv  = (float*)carve(8 * 1024 * 4);
  ushort* w1 = scr;
  ushort* w2 = scr + 2 * NW;
  ushort* ovT = scr;
  ushort* part = bufB;

  const dim3 blk(256, 1, 1);
  const dim3 blk5(512, 1, 1);

  // 1. fused prep
  prep<<<dim3(20480), blk, 0, stream>>>(lat, inp, Wl, bl, Wu, bu, WA, bA, WV, bV, Wo, bo,
                                        xBf, xBf2, w1, w2, wCat + NW, bc, bc2);
  // 2. weight compose
  gemm_nt<false, false, false><<<dim3(8, 8, 2), blk, 0, stream>>>(
      w1, w2, nullptr, wCat, D_, D_, NW, NW, 2 * NW);
  // 3. S1 (bufB) + ov (bufA), 256x256 core, grid 8x32 = 256 blocks
  gemm256<<<dim3(8, 32, 1), blk5, 0, stream>>>(
      xBf, wCat, bc, bo, bufB, bufA, D_, D_);
  // 4. softmax
  softmax_row<<<dim3(B_ * T_), blk, 0, stream>>>(bufB);
  // 5. transposes
  transpose2<<<dim3(16, 32, 2 * B_), blk, 0, stream>>>(bufB, xBf, bufA, ovT);
  // 6. MT partials, 256 blocks
  gemm128<2><<<dim3(8, 4, 8), blk5, 0, stream>>>(
      ovT, xBf, nullptr, part, T_, T_, (long)D_ * T_, (long)D_ * T_, 0);
  // 7. E = exp(...), 256 blocks
  gemm128<1><<<dim3(8, 32, 1), blk5, 0, stream>>>(
      xBf2, wCat + 2 * NW, bc2, bufA, D_, D_, 0, 0, 0);
  // 8-9. column sums
  colsum_part<<<dim3(4, 16, B_), blk, 0, stream>>>(bufA, psum);
  colsum_comb<<<dim3(4, B_, 1), blk, 0, stream>>>(psum, cinv);
  // 10. combine + scale
  reduce2_scale<<<dim3(2048), blk, 0, stream>>>(part, cinv, MT);
  // 11. final, 256 blocks
  gemm128<3><<<dim3(8, 8, 4), blk5, 0, stream>>>(
      bufA, MT, nullptr, d_out, D_, D_,
      (long)T_ * D_, NW, (long)T_ * D_);
}

// Round 4
// 321.166 us; speedup vs baseline: 1.1186x; 1.0066x over previous
//
#include <hip/hip_runtime.h>
#include <hip/hip_bf16.h>
#include <stdint.h>

typedef __attribute__((ext_vector_type(8))) short bf16x8;
typedef __attribute__((ext_vector_type(4))) float f32x4;
typedef __attribute__((ext_vector_type(4))) unsigned short u16x4;

#define B_  4
#define T_  2048
#define D_  1024
#define BM  128
#define BN  128
#define BK  32

__device__ __forceinline__ float bf2f(ushort u) {
  union { unsigned int i; float f; } v; v.i = ((unsigned int)u) << 16; return v.f;
}
__device__ __forceinline__ ushort f2bf(float f) {
  return (ushort)(__bfloat16_as_ushort(__float2bfloat16(f)));
}
__device__ __forceinline__ void async16(const void* g, void* l) {
  __builtin_amdgcn_global_load_lds(
      (const __attribute__((address_space(1))) void*)g,
      (__attribute__((address_space(3))) void*)l, 16, 0, 0);
}
__device__ __forceinline__ int swz4(int r) { return (r ^ (r >> 2)) & 3; }

// ---------------- fused prep ----------------
__global__ __launch_bounds__(256)
void prep(const float* __restrict__ lat, const float* __restrict__ inp,
          const float* __restrict__ Wl, const float* __restrict__ bl,
          const float* __restrict__ Wu, const float* __restrict__ bu,
          const float* __restrict__ WA, const float* __restrict__ bA,
          const float* __restrict__ WV, const float* __restrict__ bV,
          const float* __restrict__ Wo, const float* __restrict__ bo,
          ushort* __restrict__ xBf, ushort* __restrict__ xBf2,
          ushort* __restrict__ w1, ushort* __restrict__ w2,
          ushort* __restrict__ wCatWo, float* __restrict__ bc, float* __restrict__ bc2)
{
  __shared__ alignas(16) ushort t[64 * 65];
  const long NW = (long)D_ * D_;
  const int bx = blockIdx.x;
  const int tid = threadIdx.x;
  if (bx < 16384) {
    const float* in = bx < 8192 ? lat : inp;
    ushort* out = bx < 8192 ? xBf : xBf2;
    const long i = (long)(bx & 8191) * 256 + tid;
    const float4 v = *(const float4*)(in + i * 4);
    u16x4 o;
    o[0] = f2bf(v.x); o[1] = f2bf(v.y); o[2] = f2bf(v.z); o[3] = f2bf(v.w);
    *(u16x4*)(out + i * 4) = o;
  } else if (bx < 19456) {
    const int seg = (bx - 16384) >> 10;
    const float* in  = seg == 0 ? Wu : (seg == 1 ? WV : Wo);
    ushort* out = seg == 0 ? w1 : (seg == 1 ? w1 + NW : wCatWo);
    const long i = (long)((bx - 16384) & 1023) * 256 + tid;
    const float4 v = *(const float4*)(in + i * 4);
    u16x4 o;
    o[0] = f2bf(v.x); o[1] = f2bf(v.y); o[2] = f2bf(v.z); o[3] = f2bf(v.w);
    *(u16x4*)(out + i * 4) = o;
  } else if (bx < 19968) {
    const int z = (bx - 19456) >> 8;
    const int w = (bx - 19456) & 255;
    const float* in = z ? WA : Wl;
    ushort* out = z ? w2 + NW : w2;
    const int c0 = (w & 15) * 64, r0 = (w >> 4) * 64;
    const int tx = tid & 15, ty = tid >> 4;
#pragma unroll
    for (int i = 0; i < 4; ++i) {
      const int r = ty + i * 16;
      const float4 v = *(const float4*)(in + (long)(r0 + r) * D_ + c0 + tx * 4);
      t[(tx * 4 + 0) * 65 + r] = f2bf(v.x);
      t[(tx * 4 + 1) * 65 + r] = f2bf(v.y);
      t[(tx * 4 + 2) * 65 + r] = f2bf(v.z);
      t[(tx * 4 + 3) * 65 + r] = f2bf(v.w);
    }
    __syncthreads();
#pragma unroll
    for (int i = 0; i < 4; ++i) {
      const int c = ty + i * 16;
      u16x4 v;
#pragma unroll
      for (int j = 0; j < 4; ++j) v[j] = t[c * 65 + tx * 4 + j];
      *(u16x4*)(out + (long)(c0 + c) * D_ + r0 + tx * 4) = v;
    }
  } else {
    const int z = (bx - 19968) >> 8;
    const int w = (bx - 19968) & 255;
    const float* W    = z ? WV : Wu;
    const float* bin  = z ? bA : bl;
    const float* badd = z ? bV : bu;
    float* out        = z ? bc2 : bc;
    const int wv = tid >> 6, lane = tid & 63;
    const int e = w * 4 + wv;
    const float* row = W + (long)e * D_;
    float s = 0.f;
#pragma unroll
    for (int i = 0; i < 16; ++i) s += row[lane + i * 64] * bin[lane + i * 64];
#pragma unroll
    for (int off = 32; off; off >>= 1) s += __shfl_xor(s, off);
    if (lane == 0) out[e] = s + badd[e];
  }
}

// ---------------- small 128^2 GEMM (weight-compose only) ----------
template<bool OUT_F32, bool HAS_BIAS, bool EXP_OUT>
__global__ __launch_bounds__(256, 2)
void gemm_nt(const ushort* __restrict__ A, const ushort* __restrict__ B,
             const float* __restrict__ bias, void* __restrict__ C,
             int N, int K, long sA, long sB, long sC)
{
  __shared__ alignas(16) ushort As[BM * BK];
  __shared__ alignas(16) ushort Bs[BN * BK];
  const int tid  = threadIdx.x;
  const int wave = tid >> 6;
  const int lane = tid & 63;
  const int wm   = wave >> 1;
  const int wn   = wave & 1;
  const int bz   = blockIdx.z;
  const int tileN = blockIdx.x * BN;
  const int tileM = blockIdx.y * BM;
  A += (long)bz * sA;
  B += (long)bz * sB;

  const int lrow   = lane >> 2;
  const int lchunk = (lane & 3) ^ swz4(lrow);

  f32x4 acc[4][4];
#pragma unroll
  for (int i = 0; i < 4; ++i)
#pragma unroll
    for (int j = 0; j < 4; ++j) acc[i][j] = (f32x4){0.f, 0.f, 0.f, 0.f};

  const int frow = lane & 15;
  const int kg   = lane >> 4;
  const int coff = ((kg ^ swz4(frow)) << 3);

  for (int kt = 0; kt < K; kt += BK) {
    __syncthreads();
#pragma unroll
    for (int i = 0; i < 2; ++i) {
      const int rg  = wave * 2 + i;
      const int row = rg * 16 + lrow;
      async16(A + (long)(tileM + row) * K + kt + lchunk * 8, (void*)(As + rg * 16 * BK));
      async16(B + (long)(tileN + row) * K + kt + lchunk * 8, (void*)(Bs + rg * 16 * BK));
    }
    __syncthreads();
    bf16x8 af[4], bfr[4];
#pragma unroll
    for (int mi = 0; mi < 4; ++mi)
      af[mi] = *(const bf16x8*)(As + (wm * 64 + mi * 16 + frow) * BK + coff);
#pragma unroll
    for (int ni = 0; ni < 4; ++ni)
      bfr[ni] = *(const bf16x8*)(Bs + (wn * 64 + ni * 16 + frow) * BK + coff);
#pragma unroll
    for (int mi = 0; mi < 4; ++mi)
#pragma unroll
      for (int ni = 0; ni < 4; ++ni)
        acc[mi][ni] = __builtin_amdgcn_mfma_f32_16x16x32_bf16(af[mi], bfr[ni], acc[mi][ni], 0, 0, 0);
  }

  const int rowbase = tileM + wm * 64 + ((lane >> 4) << 2);
  const int colbase = tileN + wn * 64 + (lane & 15);
#pragma unroll
  for (int ni = 0; ni < 4; ++ni) {
    const int col = colbase + ni * 16;
    float bv = 0.f;
    if constexpr (HAS_BIAS) bv = bias[col];
#pragma unroll
    for (int mi = 0; mi < 4; ++mi) {
#pragma unroll
      for (int r = 0; r < 4; ++r) {
        const int row = rowbase + mi * 16 + r;
        float v = acc[mi][ni][r] + bv;
        if constexpr (EXP_OUT) v = __expf(v);
        const long idx = (long)bz * sC + (long)row * N + col;
        if constexpr (OUT_F32) ((float*)C)[idx] = v;
        else ((ushort*)C)[idx] = f2bf(v);
      }
    }
  }
}

// Phase skeleton shared by gemm256/gemm128 (m201 template, plain HIP):
//   [8 ds_read_b128] [stage k-half] [counted vmcnt] s_barrier ;
//   lgkmcnt(0) ; sched_barrier(0) ; setprio(1) ; 16 MFMA ; setprio(0) ; s_barrier
#define PH_SYNC_IN()                                               \
  __builtin_amdgcn_s_barrier();                                    \
  asm volatile("s_waitcnt lgkmcnt(0)" ::: "memory");               \
  __builtin_amdgcn_sched_barrier(0);                               \
  __builtin_amdgcn_s_setprio(1)
#define PH_SYNC_OUT()                                              \
  __builtin_amdgcn_s_setprio(0);                                   \
  __builtin_amdgcn_s_barrier()

// =============== 256x256 BK=64, 4 phases/K-tile, 2-dbuf k-half staging =======
// 512 thr / 8 waves (2M x 4N), wave tile 128x64, acc[8][4]. LDS 128 KB.
// Per K-tile t (buf=t&1): ph0 {k0,m-lo; stage k1(t+1)->buf^1}, ph1 {k0,m-hi;
// vmcnt(8)}, ph2 {k1,m-lo; stage k0(t+2)->buf}, ph3 {k1,m-hi; vmcnt(8)}.
// 12 loads in flight, 6-phase issue->wait distance. WAR-safe: each k-half
// region's last read completes (lgkmcnt(0)) before the barrier preceding the
// overwriting stage.
__global__ __launch_bounds__(512, 2)
void gemm256(const ushort* __restrict__ A, const ushort* __restrict__ Bm,
             const float* __restrict__ bias1, const float* __restrict__ bias2,
             ushort* __restrict__ C1, ushort* __restrict__ C2,
             int ldA, int ldB)
{
  __shared__ alignas(16) ushort AbS[2 * 16384];
  __shared__ alignas(16) ushort BbS[2 * 16384];

  const int gx = gridDim.x;
  const int nwg = gx * gridDim.y;
  int fid = blockIdx.y * gx + blockIdx.x;
  fid = (fid & 7) * (nwg >> 3) + (fid >> 3);
  const int bx = fid % gx;
  const int by = fid / gx;
  const int tileM = by * 256, tileN = bx * 256;

  const int tid  = threadIdx.x;
  const int wid  = tid >> 6;
  const int lane = tid & 63;
  const int wm   = wid >> 2;          // 2 waves along M
  const int wn   = wid & 3;           // 4 waves along N

  // staging (source pre-swizzled, LDS dest linear per wave)
  const int srow = tid >> 2;
  const int sc   = (((tid & 3) ^ ((tid >> 3) & 3)) << 3);
  const ushort* gA0 = A  + (long)(tileM + srow) * ldA + sc;
  const ushort* gA1 = A  + (long)(tileM + 128 + srow) * ldA + sc;
  const ushort* gB0 = Bm + (long)(tileN + srow) * ldB + sc;
  const ushort* gB1 = Bm + (long)(tileN + 128 + srow) * ldB + sc;
  const int dofs = tid << 3;

  // layout per buf: kh*8192 + half*4096 + r*32 + c   (elems)
#define STA(b, kh, t) { \
    async16(gA0 + (long)(t) * 64 + (kh) * 32, AbS + (b) * 16384 + (kh) * 8192 + dofs); \
    async16(gA1 + (long)(t) * 64 + (kh) * 32, AbS + (b) * 16384 + (kh) * 8192 + 4096 + dofs); }
#define STB(b, kh, t) { \
    async16(gB0 + (long)(t) * 64 + (kh) * 32, BbS + (b) * 16384 + (kh) * 8192 + dofs); \
    async16(gB1 + (long)(t) * 64 + (kh) * 32, BbS + (b) * 16384 + (kh) * 8192 + 4096 + dofs); }

  const int frow = lane & 15;
  const int cofs = (((lane >> 4) ^ ((frow >> 1) & 3)) << 3);
  int aoff[8], boff[4];
#pragma unroll
  for (int mi = 0; mi < 8; ++mi)
    aoff[mi] = wm * 4096 + (mi * 16 + frow) * 32 + cofs;
#pragma unroll
  for (int n = 0; n < 4; ++n) {
    const int Brow = wn * 64 + n * 16 + frow;
    boff[n] = (Brow >> 7) * 4096 + (Brow & 127) * 32 + cofs;
  }

  f32x4 acc[8][4];
#pragma unroll
  for (int i = 0; i < 8; ++i)
#pragma unroll
    for (int j = 0; j < 4; ++j) acc[i][j] = (f32x4){0.f, 0.f, 0.f, 0.f};

  // prologue: k0(0), k1(0), k0(1); drain k0(0)
  STA(0, 0, 0); STB(0, 0, 0);
  STA(0, 1, 0); STB(0, 1, 0);
  STA(1, 0, 1); STB(1, 0, 1);
  asm volatile("s_waitcnt vmcnt(8)" ::: "memory");
  __builtin_amdgcn_s_barrier();

#pragma unroll 1
  for (int t = 0; t < 16; ++t) {
    const int buf = t & 1;
    const ushort* Ac = AbS + buf * 16384;
    const ushort* Bc = BbS + buf * 16384;
    bf16x8 fa[4], fb[4], ga[4];

    // ---- ph0: k0, m-lo ; stage k1(t+1) -> buf^1
#pragma unroll
    for (int n = 0; n < 4; ++n) fb[n] = *(const bf16x8*)(Bc + boff[n]);
#pragma unroll
    for (int m = 0; m < 4; ++m) fa[m] = *(const bf16x8*)(Ac + aoff[m]);
    if (t <= 14) { STA(buf ^ 1, 1, t + 1); STB(buf ^ 1, 1, t + 1); }
    PH_SYNC_IN();
#pragma unroll
    for (int m = 0; m < 4; ++m)
#pragma unroll
      for (int n = 0; n < 4; ++n)
        acc[m][n] = __builtin_amdgcn_mfma_f32_16x16x32_bf16(fa[m], fb[n], acc[m][n], 0, 0, 0);
    PH_SYNC_OUT();

    // ---- ph1: k0, m-hi ; vmcnt drains k1(t)
#pragma unroll
    for (int m = 0; m < 4; ++m) ga[m] = *(const bf16x8*)(Ac + aoff[4 + m]);
    if (t <= 14) asm volatile("s_waitcnt vmcnt(8)" ::: "memory");
    else         asm volatile("s_waitcnt vmcnt(0)" ::: "memory");
    PH_SYNC_IN();
#pragma unroll
    for (int m = 0; m < 4; ++m)
#pragma unroll
      for (int n = 0; n < 4; ++n)
        acc[4 + m][n] = __builtin_amdgcn_mfma_f32_16x16x32_bf16(ga[m], fb[n], acc[4 + m][n], 0, 0, 0);
    PH_SYNC_OUT();

    // ---- ph2: k1, m-lo ; stage k0(t+2) -> buf
#pragma unroll
    for (int n = 0; n < 4; ++n) fb[n] = *(const bf16x8*)(Bc + boff[n] + 8192);
#pragma unroll
    for (int m = 0; m < 4; ++m) fa[m] = *(const bf16x8*)(Ac + aoff[m] + 8192);
    if (t <= 13) { STA(buf, 0, t + 2); STB(buf, 0, t + 2); }
    PH_SYNC_IN();
#pragma unroll
    for (int m = 0; m < 4; ++m)
#pragma unroll
      for (int n = 0; n < 4; ++n)
        acc[m][n] = __builtin_amdgcn_mfma_f32_16x16x32_bf16(fa[m], fb[n], acc[m][n], 0, 0, 0);
    PH_SYNC_OUT();

    // ---- ph3: k1, m-hi ; vmcnt drains k0(t+1)
#pragma unroll
    for (int m = 0; m < 4; ++m) ga[m] = *(const bf16x8*)(Ac + aoff[4 + m] + 8192);
    if (t <= 13)      asm volatile("s_waitcnt vmcnt(8)" ::: "memory");
    else if (t == 14) asm volatile("s_waitcnt vmcnt(4)" ::: "memory");
    PH_SYNC_IN();
#pragma unroll
    for (int m = 0; m < 4; ++m)
#pragma unroll
      for (int n = 0; n < 4; ++n)
        acc[4 + m][n] = __builtin_amdgcn_mfma_f32_16x16x32_bf16(ga[m], fb[n], acc[4 + m][n], 0, 0, 0);
    PH_SYNC_OUT();
  }
#undef STA
#undef STB

  // ---- epilogue (dual bf16 out)
  const bool second = tileN >= 1024;
  ushort* Cp = second ? C2 : C1;
  const float* bb = second ? bias2 : bias1;
  const int cb = tileN - (second ? 1024 : 0) + wn * 64 + (lane & 15);
  const int rb = tileM + wm * 128 + ((lane >> 4) << 2);
#pragma unroll
  for (int mi = 0; mi < 8; ++mi) {
    const int mrow = rb + mi * 16;
#pragma unroll
    for (int ni = 0; ni < 4; ++ni) {
      const int col = cb + ni * 16;
      const float bv = bb[col];
#pragma unroll
      for (int r = 0; r < 4; ++r)
        Cp[(long)(mrow + r) * 1024 + col] = f2bf(acc[mi][ni][r] + bv);
    }
  }
}

// =============== 256x128 BK=64, 2 phases/K-tile, 2-dbuf k-half staging =======
// 512 thr / 8 waves (4M x 2N), wave tile 64x64, acc[4][4]. LDS 96 KB.
// ph0(t) {k0; stage k1(t+1)->buf^1; vmcnt(6)}, ph1(t) {k1; stage k0(t+2)->buf;
// vmcnt(6)}. 9 loads in flight, 3-phase issue->wait distance.
// MODE: 1 = bf16 out bias+exp ; 2 = bf16 splitK partial ; 3 = f32 out batched
template<int MODE>
__global__ __launch_bounds__(512, 2)
void gemm128(const ushort* __restrict__ A, const ushort* __restrict__ Bm,
             const float* __restrict__ bias1, void* __restrict__ C1,
             int ldA, int ldB, long sAz, long sBz, long sCz)
{
  __shared__ alignas(16) ushort AbS[2 * 16384];
  __shared__ alignas(16) ushort BbS[2 * 8192];

  const int gx = gridDim.x, gy = gridDim.y;
  const int nwg = gx * gy * gridDim.z;
  int fid = (blockIdx.z * gy + blockIdx.y) * gx + blockIdx.x;
  fid = (fid & 7) * (nwg >> 3) + (fid >> 3);
  const int bx = fid % gx;
  const int by = (fid / gx) % gy;
  const int bz = fid / (gx * gy);
  const int tileM = by * 256, tileN = bx * 128;

  const ushort* Ap = A;
  const ushort* Bp = Bm;
  if constexpr (MODE == 2) {
    Ap += (long)(bz >> 1) * sAz + (long)(bz & 1) * 1024;
    Bp += (long)(bz >> 1) * sBz + (long)(bz & 1) * 1024;
  } else {
    Ap += (long)bz * sAz;
    Bp += (long)bz * sBz;
  }

  const int tid  = threadIdx.x;
  const int wid  = tid >> 6;
  const int lane = tid & 63;
  const int wm   = wid >> 1;          // 4 waves along M
  const int wn   = wid & 1;           // 2 waves along N

  const int srow = tid >> 2;
  const int sc   = (((tid & 3) ^ ((tid >> 3) & 3)) << 3);
  const ushort* gA0 = Ap + (long)(tileM + srow) * ldA + sc;
  const ushort* gA1 = Ap + (long)(tileM + 128 + srow) * ldA + sc;
  const ushort* gB0 = Bp + (long)(tileN + srow) * ldB + sc;
  const int dofs = tid << 3;

  // A layout per buf: kh*8192 + half*4096 + r*32 ; B: kh*4096 + r*32
#define STA(b, kh, t) { \
    async16(gA0 + (long)(t) * 64 + (kh) * 32, AbS + (b) * 16384 + (kh) * 8192 + dofs); \
    async16(gA1 + (long)(t) * 64 + (kh) * 32, AbS + (b) * 16384 + (kh) * 8192 + 4096 + dofs); }
#define STB(b, kh, t) \
    async16(gB0 + (long)(t) * 64 + (kh) * 32, BbS + (b) * 8192 + (kh) * 4096 + dofs);

  const int frow = lane & 15;
  const int cofs = (((lane >> 4) ^ ((frow >> 1) & 3)) << 3);
  int aoff[4], boff[4];
#pragma unroll
  for (int mi = 0; mi < 4; ++mi) {
    const int R = wm * 64 + mi * 16 + frow;   // [0,256)
    aoff[mi] = (R >> 7) * 4096 + (R & 127) * 32 + cofs;
  }
#pragma unroll
  for (int n = 0; n < 4; ++n)
    boff[n] = (wn * 64 + n * 16 + frow) * 32 + cofs;

  f32x4 acc[4][4];
#pragma unroll
  for (int i = 0; i < 4; ++i)
#pragma unroll
    for (int j = 0; j < 4; ++j) acc[i][j] = (f32x4){0.f, 0.f, 0.f, 0.f};

  // prologue: k0(0), k1(0), k0(1); drain k0(0)
  STA(0, 0, 0); STB(0, 0, 0);
  STA(0, 1, 0); STB(0, 1, 0);
  STA(1, 0, 1); STB(1, 0, 1);
  asm volatile("s_waitcnt vmcnt(6)" ::: "memory");
  __builtin_amdgcn_s_barrier();

#pragma unroll 1
  for (int t = 0; t < 16; ++t) {
    const int buf = t & 1;
    const ushort* Ac = AbS + buf * 16384;
    const ushort* Bc = BbS + buf * 8192;
    bf16x8 fa[4], fb[4];

    // ---- ph0: k0 ; stage k1(t+1) -> buf^1 ; vmcnt drains k1(t)
#pragma unroll
    for (int n = 0; n < 4; ++n) fb[n] = *(const bf16x8*)(Bc + boff[n]);
#pragma unroll
    for (int m = 0; m < 4; ++m) fa[m] = *(const bf16x8*)(Ac + aoff[m]);
    if (t <= 14) { STA(buf ^ 1, 1, t + 1); STB(buf ^ 1, 1, t + 1); }
    if (t <= 14) asm volatile("s_waitcnt vmcnt(6)" ::: "memory");
    else         asm volatile("s_waitcnt vmcnt(0)" ::: "memory");
    PH_SYNC_IN();
#pragma unroll
    for (int m = 0; m < 4; ++m)
#pragma unroll
      for (int n = 0; n < 4; ++n)
        acc[m][n] = __builtin_amdgcn_mfma_f32_16x16x32_bf16(fa[m], fb[n], acc[m][n], 0, 0, 0);
    PH_SYNC_OUT();

    // ---- ph1: k1 ; stage k0(t+2) -> buf ; vmcnt drains k0(t+1)
#pragma unroll
    for (int n = 0; n < 4; ++n) fb[n] = *(const bf16x8*)(Bc + boff[n] + 4096);
#pragma unroll
    for (int m = 0; m < 4; ++m) fa[m] = *(const bf16x8*)(Ac + aoff[m] + 8192);
    if (t <= 13) { STA(buf, 0, t + 2); STB(buf, 0, t + 2); }
    if (t <= 13)      asm volatile("s_waitcnt vmcnt(6)" ::: "memory");
    else if (t == 14) asm volatile("s_waitcnt vmcnt(3)" ::: "memory");
    PH_SYNC_IN();
#pragma unroll
    for (int m = 0; m < 4; ++m)
#pragma unroll
      for (int n = 0; n < 4; ++n)
        acc[m][n] = __builtin_amdgcn_mfma_f32_16x16x32_bf16(fa[m], fb[n], acc[m][n], 0, 0, 0);
    PH_SYNC_OUT();
  }
#undef STA
#undef STB

  // ---- epilogue
  const int cb = tileN + wn * 64 + (lane & 15);
  const int rb = tileM + wm * 64 + ((lane >> 4) << 2);

  if constexpr (MODE == 1) {
    ushort* Cp = (ushort*)C1;
#pragma unroll
    for (int ni = 0; ni < 4; ++ni) {
      const int col = cb + ni * 16;
      const float bv = bias1[col];
#pragma unroll
      for (int mi = 0; mi < 4; ++mi)
#pragma unroll
        for (int r = 0; r < 4; ++r)
          Cp[(long)(rb + mi * 16 + r) * 1024 + col] = f2bf(__expf(acc[mi][ni][r] + bv));
    }
  } else if constexpr (MODE == 2) {
    ushort* Cp = (ushort*)C1 + ((long)(bz & 1) * B_ + (bz >> 1)) * ((long)D_ * D_);
#pragma unroll
    for (int ni = 0; ni < 4; ++ni) {
      const int col = cb + ni * 16;
#pragma unroll
      for (int mi = 0; mi < 4; ++mi)
#pragma unroll
        for (int r = 0; r < 4; ++r)
          Cp[(long)(rb + mi * 16 + r) * 1024 + col] = f2bf(acc[mi][ni][r]);
    }
  } else {
    float* Cp = (float*)C1 + (long)bz * sCz;
#pragma unroll
    for (int ni = 0; ni < 4; ++ni) {
      const int col = cb + ni * 16;
#pragma unroll
      for (int mi = 0; mi < 4; ++mi)
#pragma unroll
        for (int r = 0; r < 4; ++r)
          Cp[(long)(rb + mi * 16 + r) * 1024 + col] = acc[mi][ni][r];
    }
  }
}

// MT2[b][d][e] = (p0+p1) * cinv[b][e]
__global__ __launch_bounds__(256)
void reduce2_scale(const ushort* __restrict__ P, const float* __restrict__ cinv,
                   ushort* __restrict__ MT)
{
  const long stride = (long)B_ * D_ * D_;
  const long base = ((long)blockIdx.x * 256 + threadIdx.x) * 8;
  const int b = (int)(base >> 20);
  const int e0 = (int)(base & (D_ - 1));
  bf16x8 p0 = *(const bf16x8*)(P + base);
  bf16x8 p1 = *(const bf16x8*)(P + stride + base);
  const float4 c0 = *(const float4*)(cinv + (long)b * D_ + e0);
  const float4 c1 = *(const float4*)(cinv + (long)b * D_ + e0 + 4);
  const float cc[8] = {c0.x, c0.y, c0.z, c0.w, c1.x, c1.y, c1.z, c1.w};
  bf16x8 o;
#pragma unroll
  for (int j = 0; j < 8; ++j)
    o[j] = (short)f2bf((bf2f((ushort)p0[j]) + bf2f((ushort)p1[j])) * cc[j]);
  *(bf16x8*)(MT + base) = o;
}

// row softmax
__global__ __launch_bounds__(256)
void softmax_row(ushort* __restrict__ S)
{
  const long base = (long)blockIdx.x * D_;
  const int tid = threadIdx.x;
  float e[4], s = 0.f;
#pragma unroll
  for (int i = 0; i < 4; ++i) { e[i] = __expf(bf2f(S[base + i * 256 + tid])); s += e[i]; }
#pragma unroll
  for (int off = 32; off; off >>= 1) s += __shfl_xor(s, off);
  __shared__ float reds[4];
  if ((tid & 63) == 0) reds[tid >> 6] = s;
  __syncthreads();
  s = reds[0] + reds[1] + reds[2] + reds[3];
  const float inv = 1.f / s;
#pragma unroll
  for (int i = 0; i < 4; ++i)
    S[base + i * 256 + tid] = f2bf(e[i] * inv);
}

// merged transpose of l and ov
__global__ __launch_bounds__(256)
void transpose2(const ushort* __restrict__ l, ushort* __restrict__ lT,
                const ushort* __restrict__ ov, ushort* __restrict__ ovT)
{
  __shared__ alignas(16) ushort t[64 * 65];
  const int z = blockIdx.z;
  const int b = z & (B_ - 1);
  const ushort* in = (z < B_ ? l : ov) + (long)b * T_ * D_;
  ushort* out      = (z < B_ ? lT : ovT) + (long)b * (long)D_ * T_;
  const int c0 = blockIdx.x * 64, r0 = blockIdx.y * 64;
  const int tx = threadIdx.x & 15, ty = threadIdx.x >> 4;
#pragma unroll
  for (int i = 0; i < 4; ++i) {
    const int r = ty + i * 16;
    u16x4 v = *(const u16x4*)(in + (long)(r0 + r) * D_ + c0 + tx * 4);
#pragma unroll
    for (int c = 0; c < 4; ++c) t[(tx * 4 + c) * 65 + r] = v[c];
  }
  __syncthreads();
#pragma unroll
  for (int i = 0; i < 4; ++i) {
    const int c = ty + i * 16;
    u16x4 v;
#pragma unroll
    for (int j = 0; j < 4; ++j) v[j] = t[c * 65 + tx * 4 + j];
    *(u16x4*)(out + (long)(c0 + c) * T_ + r0 + tx * 4) = v;
  }
}

// column sums of E
__global__ __launch_bounds__(256)
void colsum_part(const ushort* __restrict__ E, float* __restrict__ psum)
{
  const int d = blockIdx.x * 256 + threadIdx.x;
  const int c = blockIdx.y;
  const int b = blockIdx.z;
  const ushort* p = E + ((long)b * T_ + (long)c * 128) * D_ + d;
  float s = 0.f;
#pragma unroll 4
  for (int r = 0; r < 128; ++r) s += bf2f(p[(long)r * D_]);
  psum[((long)b * 16 + c) * D_ + d] = s;
}

__global__ __launch_bounds__(256)
void colsum_comb(const float* __restrict__ psum, float* __restrict__ cinv)
{
  const int d = blockIdx.x * 256 + threadIdx.x;
  const int b = blockIdx.y;
  float s = 0.f;
#pragma unroll
  for (int c = 0; c < 16; ++c) s += psum[((long)b * 16 + c) * D_ + d];
  cinv[(long)b * D_ + d] = 1.f / s;
}

extern "C" void kernel_launch(void* const* d_in, const int* in_sizes, int n_in,
                              void* d_out, int out_size, void* d_ws, size_t ws_size,
                              hipStream_t stream)
{
  (void)in_sizes; (void)n_in; (void)out_size; (void)ws_size;
  const float* lat = (const float*)d_in[0];
  const float* inp = (const float*)d_in[1];
  const float* Wl  = (const float*)d_in[2];
  const float* bl  = (const float*)d_in[3];
  const float* Wu  = (const float*)d_in[4];
  const float* bu  = (const float*)d_in[5];
  const float* WA  = (const float*)d_in[6];
  const float* bA  = (const float*)d_in[7];
  const float* WV  = (const float*)d_in[8];
  const float* bV  = (const float*)d_in[9];
  const float* Wo  = (const float*)d_in[10];
  const float* bo  = (const float*)d_in[11];

  char* w = (char*)d_ws;
  auto carve = [&](size_t bytes) { char* p = w; w += (bytes + 255) & ~(size_t)255; return p; };
  const long NT = (long)B_ * T_ * D_;
  const long NW = (long)D_ * D_;
  ushort* xBf   = (ushort*)carve(NT * 2);
  ushort* xBf2  = (ushort*)carve(NT * 2);
  ushort* bufA  = (ushort*)carve(NT * 2);
  ushort* bufB  = (ushort*)carve(NT * 2);
  ushort* scr   = (ushort*)carve(NT * 2);
  ushort* MT    = (ushort*)carve((long)B_ * NW * 2);
  ushort* wCat  = (ushort*)carve(3 * NW * 2);
  float*  bc    = (float*)carve(D_ * 4);
  float*  bc2   = (float*)carve(D_ * 4);
  float*  psum  = (float*)carve(64 * 1024 * 4);
  float*  cinv  = (float*)carve(8 * 1024 * 4);
  ushort* w1 = scr;
  ushort* w2 = scr + 2 * NW;
  ushort* ovT = scr;
  ushort* part = bufB;

  const dim3 blk(256, 1, 1);
  const dim3 blk5(512, 1, 1);

  // 1. fused prep
  prep<<<dim3(20480), blk, 0, stream>>>(lat, inp, Wl, bl, Wu, bu, WA, bA, WV, bV, Wo, bo,
                                        xBf, xBf2, w1, w2, wCat + NW, bc, bc2);
  // 2. weight compose
  gemm_nt<false, false, false><<<dim3(8, 8, 2), blk, 0, stream>>>(
      w1, w2, nullptr, wCat, D_, D_, NW, NW, 2 * NW);
  // 3. S1 (bufB) + ov (bufA), 256x256 core, grid 8x32 = 256 blocks
  gemm256<<<dim3(8, 32, 1), blk5, 0, stream>>>(
      xBf, wCat, bc, bo, bufB, bufA, D_, D_);
  // 4. softmax
  softmax_row<<<dim3(B_ * T_), blk, 0, stream>>>(bufB);
  // 5. transposes
  transpose2<<<dim3(16, 32, 2 * B_), blk, 0, stream>>>(bufB, xBf, bufA, ovT);
  // 6. MT partials, 256 blocks
  gemm128<2><<<dim3(8, 4, 8), blk5, 0, stream>>>(
      ovT, xBf, nullptr, part, T_, T_, (long)D_ * T_, (long)D_ * T_, 0);
  // 7. E = exp(...), 256 blocks
  gemm128<1><<<dim3(8, 32, 1), blk5, 0, stream>>>(
      xBf2, wCat + 2 * NW, bc2, bufA, D_, D_, 0, 0, 0);
  // 8-9. column sums
  colsum_part<<<dim3(4, 16, B_), blk, 0, stream>>>(bufA, psum);
  colsum_comb<<<dim3(4, B_, 1), blk, 0, stream>>>(psum, cinv);
  // 10. combine + scale
  reduce2_scale<<<dim3(2048), blk, 0, stream>>>(part, cinv, MT);
  // 11. final, 256 blocks
  gemm128<3><<<dim3(8, 8, 4), blk5, 0, stream>>>(
      bufA, MT, nullptr, d_out, D_, D_,
      (long)T_ * D_, NW, (long)T_ * D_);
}

// Round 5
// 309.571 us; speedup vs baseline: 1.1605x; 1.0375x over previous
//
#include <hip/hip_runtime.h>
#include <hip/hip_bf16.h>
#include <stdint.h>

typedef __attribute__((ext_vector_type(8))) short bf16x8;
typedef __attribute__((ext_vector_type(4))) float f32x4;
typedef __attribute__((ext_vector_type(4))) unsigned short u16x4;

#define B_  4
#define T_  2048
#define D_  1024

__device__ __forceinline__ float bf2f(ushort u) {
  union { unsigned int i; float f; } v; v.i = ((unsigned int)u) << 16; return v.f;
}
__device__ __forceinline__ ushort f2bf(float f) {
  return (ushort)(__bfloat16_as_ushort(__float2bfloat16(f)));
}
__device__ __forceinline__ void async16(const void* g, void* l) {
  __builtin_amdgcn_global_load_lds(
      (const __attribute__((address_space(1))) void*)g,
      (__attribute__((address_space(3))) void*)l, 16, 0, 0);
}

// ---------------- fused prep ----------------
__global__ __launch_bounds__(256)
void prep(const float* __restrict__ lat, const float* __restrict__ inp,
          const float* __restrict__ Wl, const float* __restrict__ bl,
          const float* __restrict__ Wu, const float* __restrict__ bu,
          const float* __restrict__ WA, const float* __restrict__ bA,
          const float* __restrict__ WV, const float* __restrict__ bV,
          const float* __restrict__ Wo, const float* __restrict__ bo,
          ushort* __restrict__ xBf, ushort* __restrict__ xBf2,
          ushort* __restrict__ w1, ushort* __restrict__ w2,
          ushort* __restrict__ wCatWo, float* __restrict__ bc, float* __restrict__ bc2)
{
  __shared__ alignas(16) ushort t[64 * 65];
  const long NW = (long)D_ * D_;
  const int bx = blockIdx.x;
  const int tid = threadIdx.x;
  if (bx < 16384) {
    const float* in = bx < 8192 ? lat : inp;
    ushort* out = bx < 8192 ? xBf : xBf2;
    const long i = (long)(bx & 8191) * 256 + tid;
    const float4 v = *(const float4*)(in + i * 4);
    u16x4 o;
    o[0] = f2bf(v.x); o[1] = f2bf(v.y); o[2] = f2bf(v.z); o[3] = f2bf(v.w);
    *(u16x4*)(out + i * 4) = o;
  } else if (bx < 19456) {
    const int seg = (bx - 16384) >> 10;
    const float* in  = seg == 0 ? Wu : (seg == 1 ? WV : Wo);
    ushort* out = seg == 0 ? w1 : (seg == 1 ? w1 + NW : wCatWo);
    const long i = (long)((bx - 16384) & 1023) * 256 + tid;
    const float4 v = *(const float4*)(in + i * 4);
    u16x4 o;
    o[0] = f2bf(v.x); o[1] = f2bf(v.y); o[2] = f2bf(v.z); o[3] = f2bf(v.w);
    *(u16x4*)(out + i * 4) = o;
  } else if (bx < 19968) {
    const int z = (bx - 19456) >> 8;
    const int w = (bx - 19456) & 255;
    const float* in = z ? WA : Wl;
    ushort* out = z ? w2 + NW : w2;
    const int c0 = (w & 15) * 64, r0 = (w >> 4) * 64;
    const int tx = tid & 15, ty = tid >> 4;
#pragma unroll
    for (int i = 0; i < 4; ++i) {
      const int r = ty + i * 16;
      const float4 v = *(const float4*)(in + (long)(r0 + r) * D_ + c0 + tx * 4);
      t[(tx * 4 + 0) * 65 + r] = f2bf(v.x);
      t[(tx * 4 + 1) * 65 + r] = f2bf(v.y);
      t[(tx * 4 + 2) * 65 + r] = f2bf(v.z);
      t[(tx * 4 + 3) * 65 + r] = f2bf(v.w);
    }
    __syncthreads();
#pragma unroll
    for (int i = 0; i < 4; ++i) {
      const int c = ty + i * 16;
      u16x4 v;
#pragma unroll
      for (int j = 0; j < 4; ++j) v[j] = t[c * 65 + tx * 4 + j];
      *(u16x4*)(out + (long)(c0 + c) * D_ + r0 + tx * 4) = v;
    }
  } else {
    const int z = (bx - 19968) >> 8;
    const int w = (bx - 19968) & 255;
    const float* W    = z ? WV : Wu;
    const float* bin  = z ? bA : bl;
    const float* badd = z ? bV : bu;
    float* out        = z ? bc2 : bc;
    const int wv = tid >> 6, lane = tid & 63;
    const int e = w * 4 + wv;
    const float* row = W + (long)e * D_;
    float s = 0.f;
#pragma unroll
    for (int i = 0; i < 16; ++i) s += row[lane + i * 64] * bin[lane + i * 64];
#pragma unroll
    for (int off = 32; off; off >>= 1) s += __shfl_xor(s, off);
    if (lane == 0) out[e] = s + badd[e];
  }
}

// Phase skeleton (m201 template):
//   [ds_reads] [stage insts] [counted vmcnt] s_barrier ; lgkmcnt(0) ;
//   sched_barrier(0) ; setprio(1) ; 16 MFMA ; setprio(0) ; s_barrier
#define PH_SYNC_IN()                                               \
  __builtin_amdgcn_s_barrier();                                    \
  asm volatile("s_waitcnt lgkmcnt(0)" ::: "memory");               \
  __builtin_amdgcn_sched_barrier(0);                               \
  __builtin_amdgcn_s_setprio(1)
#define PH_SYNC_OUT()                                              \
  __builtin_amdgcn_s_setprio(0);                                   \
  __builtin_amdgcn_s_barrier()

// Full-line staging (both GEMMs): one instruction = 64 rows x 64 K-cols;
// thread tid reads row (tid>>3), 16B chunk ((tid&7) ^ (row&7)) -> each row's
// 8 lanes cover one whole 128-B line (XOR-permuted order, still 1 txn).
// LDS dest linear (tid*16B); ds_read applies the same XOR:
//   elem = row*64 + ((kh*4+kg) ^ (row&7))*8  -> conflict-free b128 (G4).

// =============== 256x256 BK=64, A 2-buf + B 3-buf, 4 phases/K-tile ===========
// 512 thr / 8 waves (2M x 4N), wave tile 128x64, acc[8][4]. LDS 160 KB exact.
// Stages: ph0 A01(t+1), ph1 A23(t+1)+B01(t+2), ph2 B23(t+2), ph3 vmcnt(4).
// All hazards barrier-ordered; min issue->wait age = 2 phases (~1300 cyc).
__global__ __launch_bounds__(512, 2)
void gemm256(const ushort* __restrict__ A, const ushort* __restrict__ Bm,
             const float* __restrict__ bias1, const float* __restrict__ bias2,
             ushort* __restrict__ C1, ushort* __restrict__ C2,
             int ldA, int ldB)
{
  __shared__ alignas(16) ushort AbS[2 * 16384];   // 64 KB
  __shared__ alignas(16) ushort BbS[3 * 16384];   // 96 KB

  const int gx = gridDim.x;
  const int nwg = gx * gridDim.y;
  int fid = blockIdx.y * gx + blockIdx.x;
  fid = (fid & 7) * (nwg >> 3) + (fid >> 3);
  const int bx = fid % gx;
  const int by = fid / gx;
  const int tileM = by * 256, tileN = bx * 256;

  const int tid  = threadIdx.x;
  const int wid  = tid >> 6;
  const int lane = tid & 63;
  const int wm   = wid >> 2;          // 2 waves along M (128 rows each)
  const int wn   = wid & 3;           // 4 waves along N (64 cols each)

  const int srow8 = tid >> 3;                         // [0,64)
  const int scol8 = ((tid & 7) ^ (srow8 & 7)) << 3;   // swizzled source chunk
  const ushort* gAs = A  + (long)(tileM + srow8) * ldA + scol8;
  const ushort* gBs = Bm + (long)(tileN + srow8) * ldB + scol8;
  const int sdst = tid << 3;

#define STA(b, i, t) async16(gAs + (long)((i) * 64) * ldA + (t) * 64, \
                             AbS + (b) * 16384 + (i) * 4096 + sdst)
#define STB(b, i, t) async16(gBs + (long)((i) * 64) * ldB + (t) * 64, \
                             BbS + (b) * 16384 + (i) * 4096 + sdst)

  const int frow = lane & 15;
  const int kg   = lane >> 4;
  const int ck0 = ((kg       ^ (frow & 7)) << 3);
  const int ck1 = (((4 + kg) ^ (frow & 7)) << 3);
  int aoffr[8], boffr[4];
#pragma unroll
  for (int mi = 0; mi < 8; ++mi) aoffr[mi] = (wm * 128 + mi * 16 + frow) * 64;
#pragma unroll
  for (int n = 0; n < 4; ++n)    boffr[n]  = (wn * 64 + n * 16 + frow) * 64;

  f32x4 acc[8][4];
#pragma unroll
  for (int i = 0; i < 8; ++i)
#pragma unroll
    for (int j = 0; j < 4; ++j) acc[i][j] = (f32x4){0.f, 0.f, 0.f, 0.f};

  // prologue: A(0),B(0),A(1),B(1); drain tile 0 (oldest 8 of 16)
#pragma unroll
  for (int i = 0; i < 4; ++i) STA(0, i, 0);
#pragma unroll
  for (int i = 0; i < 4; ++i) STB(0, i, 0);
#pragma unroll
  for (int i = 0; i < 4; ++i) STA(1, i, 1);
#pragma unroll
  for (int i = 0; i < 4; ++i) STB(1, i, 1);
  asm volatile("s_waitcnt vmcnt(8)" ::: "memory");
  __builtin_amdgcn_s_barrier();

#pragma unroll 1
  for (int t = 0; t < 16; ++t) {
    const int buf = t & 1;
    const int bB  = t - (t / 3) * 3;            // t % 3
    const int nA  = (t + 1) & 1;
    const int nB  = (t + 2) - ((t + 2) / 3) * 3;
    const ushort* Ac = AbS + buf * 16384;
    const ushort* Bc = BbS + bB * 16384;
    bf16x8 fa[4], fb[4], ga[4];

    // ---- ph0: k0, m-lo ; stage A01(t+1)
#pragma unroll
    for (int n = 0; n < 4; ++n) fb[n] = *(const bf16x8*)(Bc + boffr[n] + ck0);
#pragma unroll
    for (int m = 0; m < 4; ++m) fa[m] = *(const bf16x8*)(Ac + aoffr[m] + ck0);
    if (t >= 1 && t <= 14) { STA(nA, 0, t + 1); STA(nA, 1, t + 1); }
    PH_SYNC_IN();
#pragma unroll
    for (int m = 0; m < 4; ++m)
#pragma unroll
      for (int n = 0; n < 4; ++n)
        acc[m][n] = __builtin_amdgcn_mfma_f32_16x16x32_bf16(fa[m], fb[n], acc[m][n], 0, 0, 0);
    PH_SYNC_OUT();

    // ---- ph1: k0, m-hi ; stage A23(t+1) + B01(t+2)
#pragma unroll
    for (int m = 0; m < 4; ++m) ga[m] = *(const bf16x8*)(Ac + aoffr[4 + m] + ck0);
    if (t >= 1 && t <= 14) { STA(nA, 2, t + 1); STA(nA, 3, t + 1); }
    if (t <= 13)           { STB(nB, 0, t + 2); STB(nB, 1, t + 2); }
    PH_SYNC_IN();
#pragma unroll
    for (int m = 0; m < 4; ++m)
#pragma unroll
      for (int n = 0; n < 4; ++n)
        acc[4 + m][n] = __builtin_amdgcn_mfma_f32_16x16x32_bf16(ga[m], fb[n], acc[4 + m][n], 0, 0, 0);
    PH_SYNC_OUT();

    // ---- ph2: k1, m-lo ; stage B23(t+2)
#pragma unroll
    for (int n = 0; n < 4; ++n) fb[n] = *(const bf16x8*)(Bc + boffr[n] + ck1);
#pragma unroll
    for (int m = 0; m < 4; ++m) fa[m] = *(const bf16x8*)(Ac + aoffr[m] + ck1);
    if (t <= 13) { STB(nB, 2, t + 2); STB(nB, 3, t + 2); }
    PH_SYNC_IN();
#pragma unroll
    for (int m = 0; m < 4; ++m)
#pragma unroll
      for (int n = 0; n < 4; ++n)
        acc[m][n] = __builtin_amdgcn_mfma_f32_16x16x32_bf16(fa[m], fb[n], acc[m][n], 0, 0, 0);
    PH_SYNC_OUT();

    // ---- ph3: k1, m-hi ; counted drain (tile t+1 resident after barrier)
#pragma unroll
    for (int m = 0; m < 4; ++m) ga[m] = *(const bf16x8*)(Ac + aoffr[4 + m] + ck1);
    if (t <= 13)      { asm volatile("s_waitcnt vmcnt(4)" ::: "memory"); }
    else if (t == 14) { asm volatile("s_waitcnt vmcnt(0)" ::: "memory"); }
    PH_SYNC_IN();
#pragma unroll
    for (int m = 0; m < 4; ++m)
#pragma unroll
      for (int n = 0; n < 4; ++n)
        acc[4 + m][n] = __builtin_amdgcn_mfma_f32_16x16x32_bf16(ga[m], fb[n], acc[4 + m][n], 0, 0, 0);
    PH_SYNC_OUT();
  }
#undef STA
#undef STB

  // ---- epilogue (dual bf16 out)
  const bool second = tileN >= 1024;
  ushort* Cp = second ? C2 : C1;
  const float* bb = second ? bias2 : bias1;
  const int cb = tileN - (second ? 1024 : 0) + wn * 64 + (lane & 15);
  const int rb = tileM + wm * 128 + ((lane >> 4) << 2);
#pragma unroll
  for (int mi = 0; mi < 8; ++mi) {
    const int mrow = rb + mi * 16;
#pragma unroll
    for (int ni = 0; ni < 4; ++ni) {
      const int col = cb + ni * 16;
      const float bv = bb[col];
#pragma unroll
      for (int r = 0; r < 4; ++r)
        Cp[(long)(mrow + r) * 1024 + col] = f2bf(acc[mi][ni][r] + bv);
    }
  }
}

// =============== 256x128 BK=64, 3-deep full-tile ring, 2 phases/K-tile =======
// 512 thr / 8 waves (4M x 2N), wave tile 64x64, acc[4][4]. LDS 144 KB.
// ph0: stage A(t+2)x4 ; ph1: stage B(t+2)x2 + vmcnt(6). 12 loads in flight.
// MODE: 0 = bf16 out z-batched ; 1 = bf16 bias+exp ; 2 = bf16 splitK partial ;
//       3 = f32 out z-batched
template<int MODE>
__global__ __launch_bounds__(512, 2)
void gemm128(const ushort* __restrict__ A, const ushort* __restrict__ Bm,
             const float* __restrict__ bias1, void* __restrict__ C1,
             int ldA, int ldB, long sAz, long sBz, long sCz)
{
  __shared__ alignas(16) ushort AbS[3 * 16384];   // 96 KB
  __shared__ alignas(16) ushort BbS[3 * 8192];    // 48 KB

  const int gx = gridDim.x, gy = gridDim.y;
  const int nwg = gx * gy * gridDim.z;
  int fid = (blockIdx.z * gy + blockIdx.y) * gx + blockIdx.x;
  fid = (fid & 7) * (nwg >> 3) + (fid >> 3);
  const int bx = fid % gx;
  const int by = (fid / gx) % gy;
  const int bz = fid / (gx * gy);
  const int tileM = by * 256, tileN = bx * 128;

  const ushort* Ap = A;
  const ushort* Bp = Bm;
  if constexpr (MODE == 2) {
    Ap += (long)(bz >> 1) * sAz + (long)(bz & 1) * 1024;
    Bp += (long)(bz >> 1) * sBz + (long)(bz & 1) * 1024;
  } else {
    Ap += (long)bz * sAz;
    Bp += (long)bz * sBz;
  }

  const int tid  = threadIdx.x;
  const int wid  = tid >> 6;
  const int lane = tid & 63;
  const int wm   = wid >> 1;          // 4 waves along M
  const int wn   = wid & 1;           // 2 waves along N

  const int srow8 = tid >> 3;
  const int scol8 = ((tid & 7) ^ (srow8 & 7)) << 3;
  const ushort* gAs = Ap + (long)(tileM + srow8) * ldA + scol8;
  const ushort* gBs = Bp + (long)(tileN + srow8) * ldB + scol8;
  const int sdst = tid << 3;

#define STA(b, i, t) async16(gAs + (long)((i) * 64) * ldA + (t) * 64, \
                             AbS + (b) * 16384 + (i) * 4096 + sdst)
#define STB(b, i, t) async16(gBs + (long)((i) * 64) * ldB + (t) * 64, \
                             BbS + (b) * 8192 + (i) * 4096 + sdst)

  const int frow = lane & 15;
  const int kg   = lane >> 4;
  const int ck0 = ((kg       ^ (frow & 7)) << 3);
  const int ck1 = (((4 + kg) ^ (frow & 7)) << 3);
  int aoffr[4], boffr[4];
#pragma unroll
  for (int mi = 0; mi < 4; ++mi) aoffr[mi] = (wm * 64 + mi * 16 + frow) * 64;
#pragma unroll
  for (int n = 0; n < 4; ++n)    boffr[n]  = (wn * 64 + n * 16 + frow) * 64;

  f32x4 acc[4][4];
#pragma unroll
  for (int i = 0; i < 4; ++i)
#pragma unroll
    for (int j = 0; j < 4; ++j) acc[i][j] = (f32x4){0.f, 0.f, 0.f, 0.f};

  // prologue: A(0),B(0),A(1),B(1); drain tile 0 (oldest 6 of 12)
#pragma unroll
  for (int i = 0; i < 4; ++i) STA(0, i, 0);
  STB(0, 0, 0); STB(0, 1, 0);
#pragma unroll
  for (int i = 0; i < 4; ++i) STA(1, i, 1);
  STB(1, 0, 1); STB(1, 1, 1);
  asm volatile("s_waitcnt vmcnt(6)" ::: "memory");
  __builtin_amdgcn_s_barrier();

#pragma unroll 1
  for (int t = 0; t < 16; ++t) {
    const int bufT = t - (t / 3) * 3;            // t % 3
    const int nb   = (t + 2) - ((t + 2) / 3) * 3;
    const ushort* Ac = AbS + bufT * 16384;
    const ushort* Bc = BbS + bufT * 8192;
    bf16x8 fa[4], fb[4];

    // ---- ph0: k0 ; stage A(t+2)
#pragma unroll
    for (int n = 0; n < 4; ++n) fb[n] = *(const bf16x8*)(Bc + boffr[n] + ck0);
#pragma unroll
    for (int m = 0; m < 4; ++m) fa[m] = *(const bf16x8*)(Ac + aoffr[m] + ck0);
    if (t <= 13) { STA(nb, 0, t + 2); STA(nb, 1, t + 2); STA(nb, 2, t + 2); STA(nb, 3, t + 2); }
    PH_SYNC_IN();
#pragma unroll
    for (int m = 0; m < 4; ++m)
#pragma unroll
      for (int n = 0; n < 4; ++n)
        acc[m][n] = __builtin_amdgcn_mfma_f32_16x16x32_bf16(fa[m], fb[n], acc[m][n], 0, 0, 0);
    PH_SYNC_OUT();

    // ---- ph1: k1 ; stage B(t+2) ; counted drain
#pragma unroll
    for (int n = 0; n < 4; ++n) fb[n] = *(const bf16x8*)(Bc + boffr[n] + ck1);
#pragma unroll
    for (int m = 0; m < 4; ++m) fa[m] = *(const bf16x8*)(Ac + aoffr[m] + ck1);
    if (t <= 13) { STB(nb, 0, t + 2); STB(nb, 1, t + 2); }
    if (t <= 13)      { asm volatile("s_waitcnt vmcnt(6)" ::: "memory"); }
    else if (t == 14) { asm volatile("s_waitcnt vmcnt(0)" ::: "memory"); }
    PH_SYNC_IN();
#pragma unroll
    for (int m = 0; m < 4; ++m)
#pragma unroll
      for (int n = 0; n < 4; ++n)
        acc[m][n] = __builtin_amdgcn_mfma_f32_16x16x32_bf16(fa[m], fb[n], acc[m][n], 0, 0, 0);
    PH_SYNC_OUT();
  }
#undef STA
#undef STB

  // ---- epilogue
  const int cb = tileN + wn * 64 + (lane & 15);
  const int rb = tileM + wm * 64 + ((lane >> 4) << 2);

  if constexpr (MODE == 0) {
    ushort* Cp = (ushort*)C1 + (long)bz * sCz;
#pragma unroll
    for (int ni = 0; ni < 4; ++ni) {
      const int col = cb + ni * 16;
#pragma unroll
      for (int mi = 0; mi < 4; ++mi)
#pragma unroll
        for (int r = 0; r < 4; ++r)
          Cp[(long)(rb + mi * 16 + r) * 1024 + col] = f2bf(acc[mi][ni][r]);
    }
  } else if constexpr (MODE == 1) {
    ushort* Cp = (ushort*)C1;
#pragma unroll
    for (int ni = 0; ni < 4; ++ni) {
      const int col = cb + ni * 16;
      const float bv = bias1[col];
#pragma unroll
      for (int mi = 0; mi < 4; ++mi)
#pragma unroll
        for (int r = 0; r < 4; ++r)
          Cp[(long)(rb + mi * 16 + r) * 1024 + col] = f2bf(__expf(acc[mi][ni][r] + bv));
    }
  } else if constexpr (MODE == 2) {
    ushort* Cp = (ushort*)C1 + ((long)(bz & 1) * B_ + (bz >> 1)) * ((long)D_ * D_);
#pragma unroll
    for (int ni = 0; ni < 4; ++ni) {
      const int col = cb + ni * 16;
#pragma unroll
      for (int mi = 0; mi < 4; ++mi)
#pragma unroll
        for (int r = 0; r < 4; ++r)
          Cp[(long)(rb + mi * 16 + r) * 1024 + col] = f2bf(acc[mi][ni][r]);
    }
  } else {
    float* Cp = (float*)C1 + (long)bz * sCz;
#pragma unroll
    for (int ni = 0; ni < 4; ++ni) {
      const int col = cb + ni * 16;
#pragma unroll
      for (int mi = 0; mi < 4; ++mi)
#pragma unroll
        for (int r = 0; r < 4; ++r)
          Cp[(long)(rb + mi * 16 + r) * 1024 + col] = acc[mi][ni][r];
    }
  }
}

// MT2[b][d][e] = (p0+p1) * cinv[b][e]
__global__ __launch_bounds__(256)
void reduce2_scale(const ushort* __restrict__ P, const float* __restrict__ cinv,
                   ushort* __restrict__ MT)
{
  const long stride = (long)B_ * D_ * D_;
  const long base = ((long)blockIdx.x * 256 + threadIdx.x) * 8;
  const int b = (int)(base >> 20);
  const int e0 = (int)(base & (D_ - 1));
  bf16x8 p0 = *(const bf16x8*)(P + base);
  bf16x8 p1 = *(const bf16x8*)(P + stride + base);
  const float4 c0 = *(const float4*)(cinv + (long)b * D_ + e0);
  const float4 c1 = *(const float4*)(cinv + (long)b * D_ + e0 + 4);
  const float cc[8] = {c0.x, c0.y, c0.z, c0.w, c1.x, c1.y, c1.z, c1.w};
  bf16x8 o;
#pragma unroll
  for (int j = 0; j < 8; ++j)
    o[j] = (short)f2bf((bf2f((ushort)p0[j]) + bf2f((ushort)p1[j])) * cc[j]);
  *(bf16x8*)(MT + base) = o;
}

// row softmax
__global__ __launch_bounds__(256)
void softmax_row(ushort* __restrict__ S)
{
  const long base = (long)blockIdx.x * D_;
  const int tid = threadIdx.x;
  float e[4], s = 0.f;
#pragma unroll
  for (int i = 0; i < 4; ++i) { e[i] = __expf(bf2f(S[base + i * 256 + tid])); s += e[i]; }
#pragma unroll
  for (int off = 32; off; off >>= 1) s += __shfl_xor(s, off);
  __shared__ float reds[4];
  if ((tid & 63) == 0) reds[tid >> 6] = s;
  __syncthreads();
  s = reds[0] + reds[1] + reds[2] + reds[3];
  const float inv = 1.f / s;
#pragma unroll
  for (int i = 0; i < 4; ++i)
    S[base + i * 256 + tid] = f2bf(e[i] * inv);
}

// merged transpose of l and ov
__global__ __launch_bounds__(256)
void transpose2(const ushort* __restrict__ l, ushort* __restrict__ lT,
                const ushort* __restrict__ ov, ushort* __restrict__ ovT)
{
  __shared__ alignas(16) ushort t[64 * 65];
  const int z = blockIdx.z;
  const int b = z & (B_ - 1);
  const ushort* in = (z < B_ ? l : ov) + (long)b * T_ * D_;
  ushort* out      = (z < B_ ? lT : ovT) + (long)b * (long)D_ * T_;
  const int c0 = blockIdx.x * 64, r0 = blockIdx.y * 64;
  const int tx = threadIdx.x & 15, ty = threadIdx.x >> 4;
#pragma unroll
  for (int i = 0; i < 4; ++i) {
    const int r = ty + i * 16;
    u16x4 v = *(const u16x4*)(in + (long)(r0 + r) * D_ + c0 + tx * 4);
#pragma unroll
    for (int c = 0; c < 4; ++c) t[(tx * 4 + c) * 65 + r] = v[c];
  }
  __syncthreads();
#pragma unroll
  for (int i = 0; i < 4; ++i) {
    const int c = ty + i * 16;
    u16x4 v;
#pragma unroll
    for (int j = 0; j < 4; ++j) v[j] = t[c * 65 + tx * 4 + j];
    *(u16x4*)(out + (long)(c0 + c) * T_ + r0 + tx * 4) = v;
  }
}

// column sums of E
__global__ __launch_bounds__(256)
void colsum_part(const ushort* __restrict__ E, float* __restrict__ psum)
{
  const int d = blockIdx.x * 256 + threadIdx.x;
  const int c = blockIdx.y;
  const int b = blockIdx.z;
  const ushort* p = E + ((long)b * T_ + (long)c * 128) * D_ + d;
  float s = 0.f;
#pragma unroll 4
  for (int r = 0; r < 128; ++r) s += bf2f(p[(long)r * D_]);
  psum[((long)b * 16 + c) * D_ + d] = s;
}

__global__ __launch_bounds__(256)
void colsum_comb(const float* __restrict__ psum, float* __restrict__ cinv)
{
  const int d = blockIdx.x * 256 + threadIdx.x;
  const int b = blockIdx.y;
  float s = 0.f;
#pragma unroll
  for (int c = 0; c < 16; ++c) s += psum[((long)b * 16 + c) * D_ + d];
  cinv[(long)b * D_ + d] = 1.f / s;
}

extern "C" void kernel_launch(void* const* d_in, const int* in_sizes, int n_in,
                              void* d_out, int out_size, void* d_ws, size_t ws_size,
                              hipStream_t stream)
{
  (void)in_sizes; (void)n_in; (void)out_size; (void)ws_size;
  const float* lat = (const float*)d_in[0];
  const float* inp = (const float*)d_in[1];
  const float* Wl  = (const float*)d_in[2];
  const float* bl  = (const float*)d_in[3];
  const float* Wu  = (const float*)d_in[4];
  const float* bu  = (const float*)d_in[5];
  const float* WA  = (const float*)d_in[6];
  const float* bA  = (const float*)d_in[7];
  const float* WV  = (const float*)d_in[8];
  const float* bV  = (const float*)d_in[9];
  const float* Wo  = (const float*)d_in[10];
  const float* bo  = (const float*)d_in[11];

  char* w = (char*)d_ws;
  auto carve = [&](size_t bytes) { char* p = w; w += (bytes + 255) & ~(size_t)255; return p; };
  const long NT = (long)B_ * T_ * D_;
  const long NW = (long)D_ * D_;
  ushort* xBf   = (ushort*)carve(NT * 2);
  ushort* xBf2  = (ushort*)carve(NT * 2);
  ushort* bufA  = (ushort*)carve(NT * 2);
  ushort* bufB  = (ushort*)carve(NT * 2);
  ushort* scr   = (ushort*)carve(NT * 2);
  ushort* MT    = (ushort*)carve((long)B_ * NW * 2);
  ushort* wCat  = (ushort*)carve(3 * NW * 2);
  float*  bc    = (float*)carve(D_ * 4);
  float*  bc2   = (float*)carve(D_ * 4);
  float*  psum  = (float*)carve(64 * 1024 * 4);
  float*  cinv  = (float*)carve(8 * 1024 * 4);
  ushort* w1 = scr;
  ushort* w2 = scr + 2 * NW;
  ushort* ovT = scr;
  ushort* part = bufB;

  const dim3 blk(256, 1, 1);
  const dim3 blk5(512, 1, 1);

  // 1. fused prep
  prep<<<dim3(20480), blk, 0, stream>>>(lat, inp, Wl, bl, Wu, bu, WA, bA, WV, bV, Wo, bo,
                                        xBf, xBf2, w1, w2, wCat + NW, bc, bc2);
  // 2. weight compose: z0: Wc=Wu·Wl^T-form ; z1: Wc2=WV·WA (64 blocks)
  gemm128<0><<<dim3(8, 4, 2), blk5, 0, stream>>>(
      w1, w2, nullptr, wCat, D_, D_, NW, NW, 2 * NW);
  // 3. S1 (bufB) + ov (bufA), 256x256 core, 256 blocks
  gemm256<<<dim3(8, 32, 1), blk5, 0, stream>>>(
      xBf, wCat, bc, bo, bufB, bufA, D_, D_);
  // 4. softmax
  softmax_row<<<dim3(B_ * T_), blk, 0, stream>>>(bufB);
  // 5. transposes
  transpose2<<<dim3(16, 32, 2 * B_), blk, 0, stream>>>(bufB, xBf, bufA, ovT);
  // 6. MT partials, 256 blocks
  gemm128<2><<<dim3(8, 4, 8), blk5, 0, stream>>>(
      ovT, xBf, nullptr, part, T_, T_, (long)D_ * T_, (long)D_ * T_, 0);
  // 7. E = exp(...), 256 blocks
  gemm128<1><<<dim3(8, 32, 1), blk5, 0, stream>>>(
      xBf2, wCat + 2 * NW, bc2, bufA, D_, D_, 0, 0, 0);
  // 8-9. column sums
  colsum_part<<<dim3(4, 16, B_), blk, 0, stream>>>(bufA, psum);
  colsum_comb<<<dim3(4, B_, 1), blk, 0, stream>>>(psum, cinv);
  // 10. combine + scale
  reduce2_scale<<<dim3(2048), blk, 0, stream>>>(part, cinv, MT);
  // 11. final, 256 blocks
  gemm128<3><<<dim3(8, 8, 4), blk5, 0, stream>>>(
      bufA, MT, nullptr, d_out, D_, D_,
      (long)T_ * D_, NW, (long)T_ * D_);
}

// Round 9
// 292.030 us; speedup vs baseline: 1.2302x; 1.0601x over previous
//
#include <hip/hip_runtime.h>
#include <hip/hip_bf16.h>
#include <stdint.h>

typedef __attribute__((ext_vector_type(8))) short bf16x8;
typedef __attribute__((ext_vector_type(4))) float f32x4;
typedef __attribute__((ext_vector_type(4))) unsigned short u16x4;

#define B_  4
#define T_  2048
#define D_  1024

__device__ __forceinline__ float bf2f(ushort u) {
  union { unsigned int i; float f; } v; v.i = ((unsigned int)u) << 16; return v.f;
}
__device__ __forceinline__ ushort f2bf(float f) {
  return (ushort)(__bfloat16_as_ushort(__float2bfloat16(f)));
}
__device__ __forceinline__ void async16(const void* g, void* l) {
  __builtin_amdgcn_global_load_lds(
      (const __attribute__((address_space(1))) void*)g,
      (__attribute__((address_space(3))) void*)l, 16, 0, 0);
}

// ---------------- fused prep (+ psum zeroing, blocks 20480..20495) ----------------
__global__ __launch_bounds__(256)
void prep(const float* __restrict__ lat, const float* __restrict__ inp,
          const float* __restrict__ Wl, const float* __restrict__ bl,
          const float* __restrict__ Wu, const float* __restrict__ bu,
          const float* __restrict__ WA, const float* __restrict__ bA,
          const float* __restrict__ WV, const float* __restrict__ bV,
          const float* __restrict__ Wo, const float* __restrict__ bo,
          ushort* __restrict__ xBf, ushort* __restrict__ xBf2,
          ushort* __restrict__ w1, ushort* __restrict__ w2,
          ushort* __restrict__ wCatWo, float* __restrict__ bc, float* __restrict__ bc2,
          float* __restrict__ psum)
{
  __shared__ alignas(16) ushort t[64 * 65];
  const long NW = (long)D_ * D_;
  const int bx = blockIdx.x;
  const int tid = threadIdx.x;
  if (bx < 16384) {
    const float* in = bx < 8192 ? lat : inp;
    ushort* out = bx < 8192 ? xBf : xBf2;
    const long i = (long)(bx & 8191) * 256 + tid;
    const float4 v = *(const float4*)(in + i * 4);
    u16x4 o;
    o[0] = f2bf(v.x); o[1] = f2bf(v.y); o[2] = f2bf(v.z); o[3] = f2bf(v.w);
    *(u16x4*)(out + i * 4) = o;
  } else if (bx < 19456) {
    const int seg = (bx - 16384) >> 10;
    const float* in  = seg == 0 ? Wu : (seg == 1 ? WV : Wo);
    ushort* out = seg == 0 ? w1 : (seg == 1 ? w1 + NW : wCatWo);
    const long i = (long)((bx - 16384) & 1023) * 256 + tid;
    const float4 v = *(const float4*)(in + i * 4);
    u16x4 o;
    o[0] = f2bf(v.x); o[1] = f2bf(v.y); o[2] = f2bf(v.z); o[3] = f2bf(v.w);
    *(u16x4*)(out + i * 4) = o;
  } else if (bx < 19968) {
    const int z = (bx - 19456) >> 8;
    const int w = (bx - 19456) & 255;
    const float* in = z ? WA : Wl;
    ushort* out = z ? w2 + NW : w2;
    const int c0 = (w & 15) * 64, r0 = (w >> 4) * 64;
    const int tx = tid & 15, ty = tid >> 4;
#pragma unroll
    for (int i = 0; i < 4; ++i) {
      const int r = ty + i * 16;
      const float4 v = *(const float4*)(in + (long)(r0 + r) * D_ + c0 + tx * 4);
      t[(tx * 4 + 0) * 65 + r] = f2bf(v.x);
      t[(tx * 4 + 1) * 65 + r] = f2bf(v.y);
      t[(tx * 4 + 2) * 65 + r] = f2bf(v.z);
      t[(tx * 4 + 3) * 65 + r] = f2bf(v.w);
    }
    __syncthreads();
#pragma unroll
    for (int i = 0; i < 4; ++i) {
      const int c = ty + i * 16;
      u16x4 v;
#pragma unroll
      for (int j = 0; j < 4; ++j) v[j] = t[c * 65 + tx * 4 + j];
      *(u16x4*)(out + (long)(c0 + c) * D_ + r0 + tx * 4) = v;
    }
  } else if (bx < 20480) {
    const int z = (bx - 19968) >> 8;
    const int w = (bx - 19968) & 255;
    const float* W    = z ? WV : Wu;
    const float* bin  = z ? bA : bl;
    const float* badd = z ? bV : bu;
    float* out        = z ? bc2 : bc;
    const int wv = tid >> 6, lane = tid & 63;
    const int e = w * 4 + wv;
    const float* row = W + (long)e * D_;
    float s = 0.f;
#pragma unroll
    for (int i = 0; i < 16; ++i) s += row[lane + i * 64] * bin[lane + i * 64];
#pragma unroll
    for (int off = 32; off; off >>= 1) s += __shfl_xor(s, off);
    if (lane == 0) out[e] = s + badd[e];
  } else {
    // zero the E column-sum accumulator: 16 blocks x 256 thr = B_*D_ floats
    psum[(bx - 20480) * 256 + tid] = 0.f;
  }
}

// Phase skeleton (m201 template)
#define PH_SYNC_IN()                                               \
  __builtin_amdgcn_s_barrier();                                    \
  asm volatile("s_waitcnt lgkmcnt(0)" ::: "memory");               \
  __builtin_amdgcn_sched_barrier(0);                               \
  __builtin_amdgcn_s_setprio(1)
#define PH_SYNC_OUT()                                              \
  __builtin_amdgcn_s_setprio(0);                                   \
  __builtin_amdgcn_s_barrier()

// =============== 256x256 BK=64, A 2-buf + B 3-buf, 4 phases/K-tile ===========
// (unchanged from R5 — 42 us, 0 bank conflicts)
__global__ __launch_bounds__(512, 2)
void gemm256(const ushort* __restrict__ A, const ushort* __restrict__ Bm,
             const float* __restrict__ bias1, const float* __restrict__ bias2,
             ushort* __restrict__ C1, ushort* __restrict__ C2,
             int ldA, int ldB)
{
  __shared__ alignas(16) ushort AbS[2 * 16384];   // 64 KB
  __shared__ alignas(16) ushort BbS[3 * 16384];   // 96 KB

  const int gx = gridDim.x;
  const int nwg = gx * gridDim.y;
  int fid = blockIdx.y * gx + blockIdx.x;
  fid = (fid & 7) * (nwg >> 3) + (fid >> 3);
  const int bx = fid % gx;
  const int by = fid / gx;
  const int tileM = by * 256, tileN = bx * 256;

  const int tid  = threadIdx.x;
  const int wid  = tid >> 6;
  const int lane = tid & 63;
  const int wm   = wid >> 2;
  const int wn   = wid & 3;

  const int srow8 = tid >> 3;
  const int scol8 = ((tid & 7) ^ (srow8 & 7)) << 3;
  const ushort* gAs = A  + (long)(tileM + srow8) * ldA + scol8;
  const ushort* gBs = Bm + (long)(tileN + srow8) * ldB + scol8;
  const int sdst = tid << 3;

#define STA(b, i, t) async16(gAs + (long)((i) * 64) * ldA + (t) * 64, \
                             AbS + (b) * 16384 + (i) * 4096 + sdst)
#define STB(b, i, t) async16(gBs + (long)((i) * 64) * ldB + (t) * 64, \
                             BbS + (b) * 16384 + (i) * 4096 + sdst)

  const int frow = lane & 15;
  const int kg   = lane >> 4;
  const int ck0 = ((kg       ^ (frow & 7)) << 3);
  const int ck1 = (((4 + kg) ^ (frow & 7)) << 3);
  int aoffr[8], boffr[4];
#pragma unroll
  for (int mi = 0; mi < 8; ++mi) aoffr[mi] = (wm * 128 + mi * 16 + frow) * 64;
#pragma unroll
  for (int n = 0; n < 4; ++n)    boffr[n]  = (wn * 64 + n * 16 + frow) * 64;

  f32x4 acc[8][4];
#pragma unroll
  for (int i = 0; i < 8; ++i)
#pragma unroll
    for (int j = 0; j < 4; ++j) acc[i][j] = (f32x4){0.f, 0.f, 0.f, 0.f};

#pragma unroll
  for (int i = 0; i < 4; ++i) STA(0, i, 0);
#pragma unroll
  for (int i = 0; i < 4; ++i) STB(0, i, 0);
#pragma unroll
  for (int i = 0; i < 4; ++i) STA(1, i, 1);
#pragma unroll
  for (int i = 0; i < 4; ++i) STB(1, i, 1);
  asm volatile("s_waitcnt vmcnt(8)" ::: "memory");
  __builtin_amdgcn_s_barrier();

#pragma unroll 1
  for (int t = 0; t < 16; ++t) {
    const int buf = t & 1;
    const int bB  = t - (t / 3) * 3;
    const int nA  = (t + 1) & 1;
    const int nB  = (t + 2) - ((t + 2) / 3) * 3;
    const ushort* Ac = AbS + buf * 16384;
    const ushort* Bc = BbS + bB * 16384;
    bf16x8 fa[4], fb[4], ga[4];

#pragma unroll
    for (int n = 0; n < 4; ++n) fb[n] = *(const bf16x8*)(Bc + boffr[n] + ck0);
#pragma unroll
    for (int m = 0; m < 4; ++m) fa[m] = *(const bf16x8*)(Ac + aoffr[m] + ck0);
    if (t >= 1 && t <= 14) { STA(nA, 0, t + 1); STA(nA, 1, t + 1); }
    PH_SYNC_IN();
#pragma unroll
    for (int m = 0; m < 4; ++m)
#pragma unroll
      for (int n = 0; n < 4; ++n)
        acc[m][n] = __builtin_amdgcn_mfma_f32_16x16x32_bf16(fa[m], fb[n], acc[m][n], 0, 0, 0);
    PH_SYNC_OUT();

#pragma unroll
    for (int m = 0; m < 4; ++m) ga[m] = *(const bf16x8*)(Ac + aoffr[4 + m] + ck0);
    if (t >= 1 && t <= 14) { STA(nA, 2, t + 1); STA(nA, 3, t + 1); }
    if (t <= 13)           { STB(nB, 0, t + 2); STB(nB, 1, t + 2); }
    PH_SYNC_IN();
#pragma unroll
    for (int m = 0; m < 4; ++m)
#pragma unroll
      for (int n = 0; n < 4; ++n)
        acc[4 + m][n] = __builtin_amdgcn_mfma_f32_16x16x32_bf16(ga[m], fb[n], acc[4 + m][n], 0, 0, 0);
    PH_SYNC_OUT();

#pragma unroll
    for (int n = 0; n < 4; ++n) fb[n] = *(const bf16x8*)(Bc + boffr[n] + ck1);
#pragma unroll
    for (int m = 0; m < 4; ++m) fa[m] = *(const bf16x8*)(Ac + aoffr[m] + ck1);
    if (t <= 13) { STB(nB, 2, t + 2); STB(nB, 3, t + 2); }
    PH_SYNC_IN();
#pragma unroll
    for (int m = 0; m < 4; ++m)
#pragma unroll
      for (int n = 0; n < 4; ++n)
        acc[m][n] = __builtin_amdgcn_mfma_f32_16x16x32_bf16(fa[m], fb[n], acc[m][n], 0, 0, 0);
    PH_SYNC_OUT();

#pragma unroll
    for (int m = 0; m < 4; ++m) ga[m] = *(const bf16x8*)(Ac + aoffr[4 + m] + ck1);
    if (t <= 13)      { asm volatile("s_waitcnt vmcnt(4)" ::: "memory"); }
    else if (t == 14) { asm volatile("s_waitcnt vmcnt(0)" ::: "memory"); }
    PH_SYNC_IN();
#pragma unroll
    for (int m = 0; m < 4; ++m)
#pragma unroll
      for (int n = 0; n < 4; ++n)
        acc[4 + m][n] = __builtin_amdgcn_mfma_f32_16x16x32_bf16(ga[m], fb[n], acc[4 + m][n], 0, 0, 0);
    PH_SYNC_OUT();
  }
#undef STA
#undef STB

  const bool second = tileN >= 1024;
  ushort* Cp = second ? C2 : C1;
  const float* bb = second ? bias2 : bias1;
  const int cb = tileN - (second ? 1024 : 0) + wn * 64 + (lane & 15);
  const int rb = tileM + wm * 128 + ((lane >> 4) << 2);
#pragma unroll
  for (int mi = 0; mi < 8; ++mi) {
    const int mrow = rb + mi * 16;
#pragma unroll
    for (int ni = 0; ni < 4; ++ni) {
      const int col = cb + ni * 16;
      const float bv = bb[col];
#pragma unroll
      for (int r = 0; r < 4; ++r)
        Cp[(long)(mrow + r) * 1024 + col] = f2bf(acc[mi][ni][r] + bv);
    }
  }
}

// =============== 256x128 BK=64, 3-deep full-tile ring, 2 phases/K-tile =======
// NKT = K/64 (template). MODE: 1 = bf16 bias+exp + colsum atomics ;
// 2 = bf16 splitK partial ; 3 = f32 out batched ; 4 = compose splitK4 partial
template<int MODE, int NKT = 16>
__global__ __launch_bounds__(512, 2)
void gemm128(const ushort* __restrict__ A, const ushort* __restrict__ Bm,
             const float* __restrict__ bias1, void* __restrict__ C1,
             int ldA, int ldB, long sAz, long sBz, long sCz,
             float* __restrict__ psumG)
{
  __shared__ alignas(16) ushort AbS[3 * 16384];   // 96 KB
  __shared__ alignas(16) ushort BbS[3 * 8192];    // 48 KB

  const int gx = gridDim.x, gy = gridDim.y;
  const int nwg = gx * gy * gridDim.z;
  int fid = (blockIdx.z * gy + blockIdx.y) * gx + blockIdx.x;
  fid = (fid & 7) * (nwg >> 3) + (fid >> 3);
  const int bx = fid % gx;
  const int by = (fid / gx) % gy;
  const int bz = fid / (gx * gy);
  const int tileM = by * 256, tileN = bx * 128;

  const ushort* Ap = A;
  const ushort* Bp = Bm;
  if constexpr (MODE == 2) {
    Ap += (long)(bz >> 1) * sAz + (long)(bz & 1) * 1024;
    Bp += (long)(bz >> 1) * sBz + (long)(bz & 1) * 1024;
  } else if constexpr (MODE == 4) {
    Ap += (long)(bz >> 2) * sAz + (long)(bz & 3) * 256;
    Bp += (long)(bz >> 2) * sBz + (long)(bz & 3) * 256;
  } else {
    Ap += (long)bz * sAz;
    Bp += (long)bz * sBz;
  }

  const int tid  = threadIdx.x;
  const int wid  = tid >> 6;
  const int lane = tid & 63;
  const int wm   = wid >> 1;
  const int wn   = wid & 1;

  const int srow8 = tid >> 3;
  const int scol8 = ((tid & 7) ^ (srow8 & 7)) << 3;
  const ushort* gAs = Ap + (long)(tileM + srow8) * ldA + scol8;
  const ushort* gBs = Bp + (long)(tileN + srow8) * ldB + scol8;
  const int sdst = tid << 3;

#define STA(b, i, t) async16(gAs + (long)((i) * 64) * ldA + (t) * 64, \
                             AbS + (b) * 16384 + (i) * 4096 + sdst)
#define STB(b, i, t) async16(gBs + (long)((i) * 64) * ldB + (t) * 64, \
                             BbS + (b) * 8192 + (i) * 4096 + sdst)

  const int frow = lane & 15;
  const int kg   = lane >> 4;
  const int ck0 = ((kg       ^ (frow & 7)) << 3);
  const int ck1 = (((4 + kg) ^ (frow & 7)) << 3);
  int aoffr[4], boffr[4];
#pragma unroll
  for (int mi = 0; mi < 4; ++mi) aoffr[mi] = (wm * 64 + mi * 16 + frow) * 64;
#pragma unroll
  for (int n = 0; n < 4; ++n)    boffr[n]  = (wn * 64 + n * 16 + frow) * 64;

  f32x4 acc[4][4];
#pragma unroll
  for (int i = 0; i < 4; ++i)
#pragma unroll
    for (int j = 0; j < 4; ++j) acc[i][j] = (f32x4){0.f, 0.f, 0.f, 0.f};

#pragma unroll
  for (int i = 0; i < 4; ++i) STA(0, i, 0);
  STB(0, 0, 0); STB(0, 1, 0);
#pragma unroll
  for (int i = 0; i < 4; ++i) STA(1, i, 1);
  STB(1, 0, 1); STB(1, 1, 1);
  asm volatile("s_waitcnt vmcnt(6)" ::: "memory");
  __builtin_amdgcn_s_barrier();

#pragma unroll 1
  for (int t = 0; t < NKT; ++t) {
    const int bufT = t - (t / 3) * 3;
    const int nb   = (t + 2) - ((t + 2) / 3) * 3;
    const ushort* Ac = AbS + bufT * 16384;
    const ushort* Bc = BbS + bufT * 8192;
    bf16x8 fa[4], fb[4];

#pragma unroll
    for (int n = 0; n < 4; ++n) fb[n] = *(const bf16x8*)(Bc + boffr[n] + ck0);
#pragma unroll
    for (int m = 0; m < 4; ++m) fa[m] = *(const bf16x8*)(Ac + aoffr[m] + ck0);
    if (t <= NKT - 3) { STA(nb, 0, t + 2); STA(nb, 1, t + 2); STA(nb, 2, t + 2); STA(nb, 3, t + 2); }
    PH_SYNC_IN();
#pragma unroll
    for (int m = 0; m < 4; ++m)
#pragma unroll
      for (int n = 0; n < 4; ++n)
        acc[m][n] = __builtin_amdgcn_mfma_f32_16x16x32_bf16(fa[m], fb[n], acc[m][n], 0, 0, 0);
    PH_SYNC_OUT();

#pragma unroll
    for (int n = 0; n < 4; ++n) fb[n] = *(const bf16x8*)(Bc + boffr[n] + ck1);
#pragma unroll
    for (int m = 0; m < 4; ++m) fa[m] = *(const bf16x8*)(Ac + aoffr[m] + ck1);
    if (t <= NKT - 3) { STB(nb, 0, t + 2); STB(nb, 1, t + 2); }
    if (t <= NKT - 3)      { asm volatile("s_waitcnt vmcnt(6)" ::: "memory"); }
    else if (t == NKT - 2) { asm volatile("s_waitcnt vmcnt(0)" ::: "memory"); }
    PH_SYNC_IN();
#pragma unroll
    for (int m = 0; m < 4; ++m)
#pragma unroll
      for (int n = 0; n < 4; ++n)
        acc[m][n] = __builtin_amdgcn_mfma_f32_16x16x32_bf16(fa[m], fb[n], acc[m][n], 0, 0, 0);
    PH_SYNC_OUT();
  }
#undef STA
#undef STB

  const int cb = tileN + wn * 64 + (lane & 15);
  const int rb = tileM + wm * 64 + ((lane >> 4) << 2);

  if constexpr (MODE == 1) {
    // bf16 bias+exp out, plus per-block column-sum -> atomic psum[b][col]
    ushort* Cp = (ushort*)C1;
    const int bE = tileM >> 11;             // 2048 rows per batch
#pragma unroll
    for (int ni = 0; ni < 4; ++ni) {
      const int col = cb + ni * 16;
      const float bv = bias1[col];
      float cs = 0.f;
#pragma unroll
      for (int mi = 0; mi < 4; ++mi)
#pragma unroll
        for (int r = 0; r < 4; ++r) {
          const ushort ev = f2bf(__expf(acc[mi][ni][r] + bv));
          Cp[(long)(rb + mi * 16 + r) * 1024 + col] = ev;
          cs += bf2f(ev);                   // sum ROUNDED values (old colsum semantics)
        }
      cs += __shfl_xor(cs, 16);
      cs += __shfl_xor(cs, 32);
      if ((lane >> 4) == 0) atomicAdd(psumG + (long)bE * D_ + col, cs);
    }
  } else if constexpr (MODE == 2) {
    ushort* Cp = (ushort*)C1 + ((long)(bz & 1) * B_ + (bz >> 1)) * ((long)D_ * D_);
#pragma unroll
    for (int ni = 0; ni < 4; ++ni) {
      const int col = cb + ni * 16;
#pragma unroll
      for (int mi = 0; mi < 4; ++mi)
#pragma unroll
        for (int r = 0; r < 4; ++r)
          Cp[(long)(rb + mi * 16 + r) * 1024 + col] = f2bf(acc[mi][ni][r]);
    }
  } else if constexpr (MODE == 4) {
    // compose split-K partials: layout [sp][comp][NW]
    const int comp = bz >> 2, sp = bz & 3;
    ushort* Cp = (ushort*)C1 + ((long)sp * 2 + comp) * ((long)D_ * D_);
#pragma unroll
    for (int ni = 0; ni < 4; ++ni) {
      const int col = cb + ni * 16;
#pragma unroll
      for (int mi = 0; mi < 4; ++mi)
#pragma unroll
        for (int r = 0; r < 4; ++r)
          Cp[(long)(rb + mi * 16 + r) * 1024 + col] = f2bf(acc[mi][ni][r]);
    }
  } else {
    float* Cp = (float*)C1 + (long)bz * sCz;
#pragma unroll
    for (int ni = 0; ni < 4; ++ni) {
      const int col = cb + ni * 16;
#pragma unroll
      for (int mi = 0; mi < 4; ++mi)
#pragma unroll
        for (int r = 0; r < 4; ++r)
          Cp[(long)(rb + mi * 16 + r) * 1024 + col] = acc[mi][ni][r];
    }
  }
}

// reduce compose split-K partials: wCat[0..NW)=Σsp P[sp][0], wCat[2NW..3NW)=Σsp P[sp][1]
__global__ __launch_bounds__(256)
void reduce4(const ushort* __restrict__ P, ushort* __restrict__ wCat)
{
  const long NW = (long)D_ * D_;
  const long i = ((long)blockIdx.x * 256 + threadIdx.x) * 8;   // over [0, 2NW)
  float s[8] = {0.f, 0.f, 0.f, 0.f, 0.f, 0.f, 0.f, 0.f};
#pragma unroll
  for (int sp = 0; sp < 4; ++sp) {
    bf16x8 p = *(const bf16x8*)(P + (long)sp * 2 * NW + i);
#pragma unroll
    for (int j = 0; j < 8; ++j) s[j] += bf2f((ushort)p[j]);
  }
  const long comp = (i >= NW) ? 1 : 0;
  ushort* out = wCat + comp * 2 * NW + (i - comp * NW);
  bf16x8 o;
#pragma unroll
  for (int j = 0; j < 8; ++j) o[j] = (short)f2bf(s[j]);
  *(bf16x8*)out = o;
}

// rinv[row] = 1 / sum_e exp(S1[row][e])  (replaces softmax_row's write-back)
__global__ __launch_bounds__(256)
void rowexp_inv(const ushort* __restrict__ S, float* __restrict__ rinv)
{
  const long base = (long)blockIdx.x * D_;
  const int tid = threadIdx.x;
  float s = 0.f;
#pragma unroll
  for (int i = 0; i < 4; ++i) s += __expf(bf2f(S[base + i * 256 + tid]));
#pragma unroll
  for (int off = 32; off; off >>= 1) s += __shfl_xor(s, off);
  __shared__ float reds[4];
  if ((tid & 63) == 0) reds[tid >> 6] = s;
  __syncthreads();
  if (tid == 0) rinv[blockIdx.x] = 1.f / (reds[0] + reds[1] + reds[2] + reds[3]);
}

// merged transpose: z<B_: lT = (exp(S1)*rinv[row])^T (= old softmax, fused);
//                   z>=B_: ovT = ov^T (pass-through)
__global__ __launch_bounds__(256)
void transposeF(const ushort* __restrict__ l, ushort* __restrict__ lT,
                const ushort* __restrict__ ov, ushort* __restrict__ ovT,
                const float* __restrict__ rinv)
{
  __shared__ alignas(16) ushort t[64 * 65];
  const int z = blockIdx.z;
  const int b = z & (B_ - 1);
  const bool isL = z < B_;
  const ushort* in = (isL ? l : ov) + (long)b * T_ * D_;
  ushort* out      = (isL ? lT : ovT) + (long)b * (long)D_ * T_;
  const int c0 = blockIdx.x * 64, r0 = blockIdx.y * 64;
  const int tx = threadIdx.x & 15, ty = threadIdx.x >> 4;
#pragma unroll
  for (int i = 0; i < 4; ++i) {
    const int r = ty + i * 16;
    u16x4 v = *(const u16x4*)(in + (long)(r0 + r) * D_ + c0 + tx * 4);
    if (isL) {
      const float ri = rinv[(long)b * T_ + r0 + r];
#pragma unroll
      for (int c = 0; c < 4; ++c) t[(tx * 4 + c) * 65 + r] = f2bf(__expf(bf2f(v[c])) * ri);
    } else {
#pragma unroll
      for (int c = 0; c < 4; ++c) t[(tx * 4 + c) * 65 + r] = v[c];
    }
  }
  __syncthreads();
#pragma unroll
  for (int i = 0; i < 4; ++i) {
    const int c = ty + i * 16;
    u16x4 v;
#pragma unroll
    for (int j = 0; j < 4; ++j) v[j] = t[c * 65 + tx * 4 + j];
    *(u16x4*)(out + (long)(c0 + c) * T_ + r0 + tx * 4) = v;
  }
}

// MT2[b][d][e] = (p0+p1) / psum[b][e]
__global__ __launch_bounds__(256)
void reduce2_scale(const ushort* __restrict__ P, const float* __restrict__ psum,
                   ushort* __restrict__ MT)
{
  const long stride = (long)B_ * D_ * D_;
  const long base = ((long)blockIdx.x * 256 + threadIdx.x) * 8;
  const int b = (int)(base >> 20);
  const int e0 = (int)(base & (D_ - 1));
  bf16x8 p0 = *(const bf16x8*)(P + base);
  bf16x8 p1 = *(const bf16x8*)(P + stride + base);
  const float4 c0 = *(const float4*)(psum + (long)b * D_ + e0);
  const float4 c1 = *(const float4*)(psum + (long)b * D_ + e0 + 4);
  const float cc[8] = {1.f / c0.x, 1.f / c0.y, 1.f / c0.z, 1.f / c0.w,
                       1.f / c1.x, 1.f / c1.y, 1.f / c1.z, 1.f / c1.w};
  bf16x8 o;
#pragma unroll
  for (int j = 0; j < 8; ++j)
    o[j] = (short)f2bf((bf2f((ushort)p0[j]) + bf2f((ushort)p1[j])) * cc[j]);
  *(bf16x8*)(MT + base) = o;
}

extern "C" void kernel_launch(void* const* d_in, const int* in_sizes, int n_in,
                              void* d_out, int out_size, void* d_ws, size_t ws_size,
                              hipStream_t stream)
{
  (void)in_sizes; (void)n_in; (void)out_size; (void)ws_size;
  const float* lat = (const float*)d_in[0];
  const float* inp = (const float*)d_in[1];
  const float* Wl  = (const float*)d_in[2];
  const float* bl  = (const float*)d_in[3];
  const float* Wu  = (const float*)d_in[4];
  const float* bu  = (const float*)d_in[5];
  const float* WA  = (const float*)d_in[6];
  const float* bA  = (const float*)d_in[7];
  const float* WV  = (const float*)d_in[8];
  const float* bV  = (const float*)d_in[9];
  const float* Wo  = (const float*)d_in[10];
  const float* bo  = (const float*)d_in[11];

  char* w = (char*)d_ws;
  auto carve = [&](size_t bytes) { char* p = w; w += (bytes + 255) & ~(size_t)255; return p; };
  const long NT = (long)B_ * T_ * D_;
  const long NW = (long)D_ * D_;
  ushort* xBf   = (ushort*)carve(NT * 2);
  ushort* xBf2  = (ushort*)carve(NT * 2);
  ushort* bufA  = (ushort*)carve(NT * 2);
  ushort* bufB  = (ushort*)carve(NT * 2);
  ushort* scr   = (ushort*)carve(NT * 2);
  ushort* MT    = (ushort*)carve((long)B_ * NW * 2);
  ushort* wCat  = (ushort*)carve(3 * NW * 2);
  float*  bc    = (float*)carve(D_ * 4);
  float*  bc2   = (float*)carve(D_ * 4);
  float*  psum  = (float*)carve((long)B_ * D_ * 4);
  float*  rinv  = (float*)carve((long)B_ * T_ * 4);
  ushort* w1 = scr;              // [Wu_bf ; WV_bf]  (2NW)
  ushort* w2 = scr + 2 * NW;     // [WlT ; WAT]      (2NW)
  ushort* Pc = bufA;             // compose splitK partials (8NW == bufA size;
                                 //   bufA first written at step 3, Pc dead by then)
  ushort* ovT = scr;             // after compose, scr dead -> ovT
  ushort* part = bufB;           // after transposes, bufB dead -> splitk partials

  const dim3 blk(256, 1, 1);
  const dim3 blk5(512, 1, 1);

  // 1. fused prep (incl. psum zeroing — no host memset, graph-capture-safe)
  prep<<<dim3(20496), blk, 0, stream>>>(lat, inp, Wl, bl, Wu, bu, WA, bA, WV, bV, Wo, bo,
                                        xBf, xBf2, w1, w2, wCat + NW, bc, bc2, psum);
  // 2. weight compose, split-K=4 (256 blocks) + reduce
  gemm128<4, 4><<<dim3(8, 4, 8), blk5, 0, stream>>>(
      w1, w2, nullptr, Pc, D_, D_, NW, NW, 0, nullptr);
  reduce4<<<dim3(1024), blk, 0, stream>>>(Pc, wCat);
  // 3. S1 (bufB) + ov (bufA), 256x256 core, 256 blocks
  gemm256<<<dim3(8, 32, 1), blk5, 0, stream>>>(
      xBf, wCat, bc, bo, bufB, bufA, D_, D_);
  // 4. row exp-sums -> rinv (no write-back of softmax)
  rowexp_inv<<<dim3(B_ * T_), blk, 0, stream>>>(bufB, rinv);
  // 5. fused softmax-transpose (l) + transpose (ov)
  transposeF<<<dim3(16, 32, 2 * B_), blk, 0, stream>>>(bufB, xBf, bufA, ovT, rinv);
  // 6. MT partials, 256 blocks
  gemm128<2><<<dim3(8, 4, 8), blk5, 0, stream>>>(
      ovT, xBf, nullptr, part, T_, T_, (long)D_ * T_, (long)D_ * T_, 0, nullptr);
  // 7. E = exp(...) + fused column sums -> psum, 256 blocks
  gemm128<1><<<dim3(8, 32, 1), blk5, 0, stream>>>(
      xBf2, wCat + 2 * NW, bc2, bufA, D_, D_, 0, 0, 0, psum);
  // 8. combine splitK + scale by 1/psum
  reduce2_scale<<<dim3(2048), blk, 0, stream>>>(part, psum, MT);
  // 9. final, 256 blocks
  gemm128<3><<<dim3(8, 8, 4), blk5, 0, stream>>>(
      bufA, MT, nullptr, d_out, D_, D_,
      (long)T_ * D_, NW, (long)T_ * D_, nullptr);
}

// Round 10
// 287.983 us; speedup vs baseline: 1.2475x; 1.0141x over previous
//
#include <hip/hip_runtime.h>
#include <hip/hip_bf16.h>
#include <stdint.h>

typedef __attribute__((ext_vector_type(8))) short bf16x8;
typedef __attribute__((ext_vector_type(4))) float f32x4;
typedef __attribute__((ext_vector_type(4))) unsigned short u16x4;

#define B_  4
#define T_  2048
#define D_  1024

__device__ __forceinline__ float bf2f(ushort u) {
  union { unsigned int i; float f; } v; v.i = ((unsigned int)u) << 16; return v.f;
}
__device__ __forceinline__ ushort f2bf(float f) {
  return (ushort)(__bfloat16_as_ushort(__float2bfloat16(f)));
}
__device__ __forceinline__ void async16(const void* g, void* l) {
  __builtin_amdgcn_global_load_lds(
      (const __attribute__((address_space(1))) void*)g,
      (__attribute__((address_space(3))) void*)l, 16, 0, 0);
}

// ---------------- fused prep (+ psum zeroing, blocks 20480..20495) ----------------
__global__ __launch_bounds__(256)
void prep(const float* __restrict__ lat, const float* __restrict__ inp,
          const float* __restrict__ Wl, const float* __restrict__ bl,
          const float* __restrict__ Wu, const float* __restrict__ bu,
          const float* __restrict__ WA, const float* __restrict__ bA,
          const float* __restrict__ WV, const float* __restrict__ bV,
          const float* __restrict__ Wo, const float* __restrict__ bo,
          ushort* __restrict__ xBf, ushort* __restrict__ xBf2,
          ushort* __restrict__ w1, ushort* __restrict__ w2,
          ushort* __restrict__ wCatWo, float* __restrict__ bc, float* __restrict__ bc2,
          float* __restrict__ psum)
{
  __shared__ alignas(16) ushort t[64 * 65];
  const long NW = (long)D_ * D_;
  const int bx = blockIdx.x;
  const int tid = threadIdx.x;
  if (bx < 16384) {
    const float* in = bx < 8192 ? lat : inp;
    ushort* out = bx < 8192 ? xBf : xBf2;
    const long i = (long)(bx & 8191) * 256 + tid;
    const float4 v = *(const float4*)(in + i * 4);
    u16x4 o;
    o[0] = f2bf(v.x); o[1] = f2bf(v.y); o[2] = f2bf(v.z); o[3] = f2bf(v.w);
    *(u16x4*)(out + i * 4) = o;
  } else if (bx < 19456) {
    const int seg = (bx - 16384) >> 10;
    const float* in  = seg == 0 ? Wu : (seg == 1 ? WV : Wo);
    ushort* out = seg == 0 ? w1 : (seg == 1 ? w1 + NW : wCatWo);
    const long i = (long)((bx - 16384) & 1023) * 256 + tid;
    const float4 v = *(const float4*)(in + i * 4);
    u16x4 o;
    o[0] = f2bf(v.x); o[1] = f2bf(v.y); o[2] = f2bf(v.z); o[3] = f2bf(v.w);
    *(u16x4*)(out + i * 4) = o;
  } else if (bx < 19968) {
    const int z = (bx - 19456) >> 8;
    const int w = (bx - 19456) & 255;
    const float* in = z ? WA : Wl;
    ushort* out = z ? w2 + NW : w2;
    const int c0 = (w & 15) * 64, r0 = (w >> 4) * 64;
    const int tx = tid & 15, ty = tid >> 4;
#pragma unroll
    for (int i = 0; i < 4; ++i) {
      const int r = ty + i * 16;
      const float4 v = *(const float4*)(in + (long)(r0 + r) * D_ + c0 + tx * 4);
      t[(tx * 4 + 0) * 65 + r] = f2bf(v.x);
      t[(tx * 4 + 1) * 65 + r] = f2bf(v.y);
      t[(tx * 4 + 2) * 65 + r] = f2bf(v.z);
      t[(tx * 4 + 3) * 65 + r] = f2bf(v.w);
    }
    __syncthreads();
#pragma unroll
    for (int i = 0; i < 4; ++i) {
      const int c = ty + i * 16;
      u16x4 v;
#pragma unroll
      for (int j = 0; j < 4; ++j) v[j] = t[c * 65 + tx * 4 + j];
      *(u16x4*)(out + (long)(c0 + c) * D_ + r0 + tx * 4) = v;
    }
  } else if (bx < 20480) {
    const int z = (bx - 19968) >> 8;
    const int w = (bx - 19968) & 255;
    const float* W    = z ? WV : Wu;
    const float* bin  = z ? bA : bl;
    const float* badd = z ? bV : bu;
    float* out        = z ? bc2 : bc;
    const int wv = tid >> 6, lane = tid & 63;
    const int e = w * 4 + wv;
    const float* row = W + (long)e * D_;
    float s = 0.f;
#pragma unroll
    for (int i = 0; i < 16; ++i) s += row[lane + i * 64] * bin[lane + i * 64];
#pragma unroll
    for (int off = 32; off; off >>= 1) s += __shfl_xor(s, off);
    if (lane == 0) out[e] = s + badd[e];
  } else {
    psum[(bx - 20480) * 256 + tid] = 0.f;
  }
}

// Phase skeleton (m201 template)
#define PH_SYNC_IN()                                               \
  __builtin_amdgcn_s_barrier();                                    \
  asm volatile("s_waitcnt lgkmcnt(0)" ::: "memory");               \
  __builtin_amdgcn_sched_barrier(0);                               \
  __builtin_amdgcn_s_setprio(1)
#define PH_SYNC_OUT()                                              \
  __builtin_amdgcn_s_setprio(0);                                   \
  __builtin_amdgcn_s_barrier()

// =============== 256x256 BK=64, A 2-buf + B 3-buf, 4 phases/K-tile ===========
// + fused row exp-sum partials for S1 blocks: rsumP[tileN>>8][row] =
//   sum_col exp(bf16(S1+bc)), deterministic (unique writer per (bx,row)).
__global__ __launch_bounds__(512, 2)
void gemm256(const ushort* __restrict__ A, const ushort* __restrict__ Bm,
             const float* __restrict__ bias1, const float* __restrict__ bias2,
             ushort* __restrict__ C1, ushort* __restrict__ C2,
             int ldA, int ldB, float* __restrict__ rsumP)
{
  __shared__ alignas(16) ushort AbS[2 * 16384];   // 64 KB
  __shared__ alignas(16) ushort BbS[3 * 16384];   // 96 KB

  const int gx = gridDim.x;
  const int nwg = gx * gridDim.y;
  int fid = blockIdx.y * gx + blockIdx.x;
  fid = (fid & 7) * (nwg >> 3) + (fid >> 3);
  const int bx = fid % gx;
  const int by = fid / gx;
  const int tileM = by * 256, tileN = bx * 256;

  const int tid  = threadIdx.x;
  const int wid  = tid >> 6;
  const int lane = tid & 63;
  const int wm   = wid >> 2;
  const int wn   = wid & 3;

  const int srow8 = tid >> 3;
  const int scol8 = ((tid & 7) ^ (srow8 & 7)) << 3;
  const ushort* gAs = A  + (long)(tileM + srow8) * ldA + scol8;
  const ushort* gBs = Bm + (long)(tileN + srow8) * ldB + scol8;
  const int sdst = tid << 3;

#define STA(b, i, t) async16(gAs + (long)((i) * 64) * ldA + (t) * 64, \
                             AbS + (b) * 16384 + (i) * 4096 + sdst)
#define STB(b, i, t) async16(gBs + (long)((i) * 64) * ldB + (t) * 64, \
                             BbS + (b) * 16384 + (i) * 4096 + sdst)

  const int frow = lane & 15;
  const int kg   = lane >> 4;
  const int ck0 = ((kg       ^ (frow & 7)) << 3);
  const int ck1 = (((4 + kg) ^ (frow & 7)) << 3);
  int aoffr[8], boffr[4];
#pragma unroll
  for (int mi = 0; mi < 8; ++mi) aoffr[mi] = (wm * 128 + mi * 16 + frow) * 64;
#pragma unroll
  for (int n = 0; n < 4; ++n)    boffr[n]  = (wn * 64 + n * 16 + frow) * 64;

  f32x4 acc[8][4];
#pragma unroll
  for (int i = 0; i < 8; ++i)
#pragma unroll
    for (int j = 0; j < 4; ++j) acc[i][j] = (f32x4){0.f, 0.f, 0.f, 0.f};

#pragma unroll
  for (int i = 0; i < 4; ++i) STA(0, i, 0);
#pragma unroll
  for (int i = 0; i < 4; ++i) STB(0, i, 0);
#pragma unroll
  for (int i = 0; i < 4; ++i) STA(1, i, 1);
#pragma unroll
  for (int i = 0; i < 4; ++i) STB(1, i, 1);
  asm volatile("s_waitcnt vmcnt(8)" ::: "memory");
  __builtin_amdgcn_s_barrier();

#pragma unroll 1
  for (int t = 0; t < 16; ++t) {
    const int buf = t & 1;
    const int bB  = t - (t / 3) * 3;
    const int nA  = (t + 1) & 1;
    const int nB  = (t + 2) - ((t + 2) / 3) * 3;
    const ushort* Ac = AbS + buf * 16384;
    const ushort* Bc = BbS + bB * 16384;
    bf16x8 fa[4], fb[4], ga[4];

#pragma unroll
    for (int n = 0; n < 4; ++n) fb[n] = *(const bf16x8*)(Bc + boffr[n] + ck0);
#pragma unroll
    for (int m = 0; m < 4; ++m) fa[m] = *(const bf16x8*)(Ac + aoffr[m] + ck0);
    if (t >= 1 && t <= 14) { STA(nA, 0, t + 1); STA(nA, 1, t + 1); }
    PH_SYNC_IN();
#pragma unroll
    for (int m = 0; m < 4; ++m)
#pragma unroll
      for (int n = 0; n < 4; ++n)
        acc[m][n] = __builtin_amdgcn_mfma_f32_16x16x32_bf16(fa[m], fb[n], acc[m][n], 0, 0, 0);
    PH_SYNC_OUT();

#pragma unroll
    for (int m = 0; m < 4; ++m) ga[m] = *(const bf16x8*)(Ac + aoffr[4 + m] + ck0);
    if (t >= 1 && t <= 14) { STA(nA, 2, t + 1); STA(nA, 3, t + 1); }
    if (t <= 13)           { STB(nB, 0, t + 2); STB(nB, 1, t + 2); }
    PH_SYNC_IN();
#pragma unroll
    for (int m = 0; m < 4; ++m)
#pragma unroll
      for (int n = 0; n < 4; ++n)
        acc[4 + m][n] = __builtin_amdgcn_mfma_f32_16x16x32_bf16(ga[m], fb[n], acc[4 + m][n], 0, 0, 0);
    PH_SYNC_OUT();

#pragma unroll
    for (int n = 0; n < 4; ++n) fb[n] = *(const bf16x8*)(Bc + boffr[n] + ck1);
#pragma unroll
    for (int m = 0; m < 4; ++m) fa[m] = *(const bf16x8*)(Ac + aoffr[m] + ck1);
    if (t <= 13) { STB(nB, 2, t + 2); STB(nB, 3, t + 2); }
    PH_SYNC_IN();
#pragma unroll
    for (int m = 0; m < 4; ++m)
#pragma unroll
      for (int n = 0; n < 4; ++n)
        acc[m][n] = __builtin_amdgcn_mfma_f32_16x16x32_bf16(fa[m], fb[n], acc[m][n], 0, 0, 0);
    PH_SYNC_OUT();

#pragma unroll
    for (int m = 0; m < 4; ++m) ga[m] = *(const bf16x8*)(Ac + aoffr[4 + m] + ck1);
    if (t <= 13)      { asm volatile("s_waitcnt vmcnt(4)" ::: "memory"); }
    else if (t == 14) { asm volatile("s_waitcnt vmcnt(0)" ::: "memory"); }
    PH_SYNC_IN();
#pragma unroll
    for (int m = 0; m < 4; ++m)
#pragma unroll
      for (int n = 0; n < 4; ++n)
        acc[4 + m][n] = __builtin_amdgcn_mfma_f32_16x16x32_bf16(ga[m], fb[n], acc[4 + m][n], 0, 0, 0);
    PH_SYNC_OUT();
  }
#undef STA
#undef STB

  const bool second = tileN >= 1024;
  ushort* Cp = second ? C2 : C1;
  const float* bb = second ? bias2 : bias1;
  const int cb = tileN - (second ? 1024 : 0) + wn * 64 + (lane & 15);
  const int rb = tileM + wm * 128 + ((lane >> 4) << 2);

  if (!second) {
    // S1 blocks: store + row exp-sum partials (same rounding as old rowexp_inv)
    float bvv[4];
#pragma unroll
    for (int ni = 0; ni < 4; ++ni) bvv[ni] = bb[cb + ni * 16];
    float* rsh = (float*)AbS;   // [4][256] f32, reused post-loop (barrier passed)
#pragma unroll
    for (int mi = 0; mi < 8; ++mi) {
      const int mrow = rb + mi * 16;
#pragma unroll
      for (int r = 0; r < 4; ++r) {
        float s = 0.f;
#pragma unroll
        for (int ni = 0; ni < 4; ++ni) {
          const ushort ev = f2bf(acc[mi][ni][r] + bvv[ni]);
          Cp[(long)(mrow + r) * 1024 + cb + ni * 16] = ev;
          s += __expf(bf2f(ev));
        }
        s += __shfl_xor(s, 1); s += __shfl_xor(s, 2);
        s += __shfl_xor(s, 4); s += __shfl_xor(s, 8);
        if ((lane & 15) == 0)
          rsh[wn * 256 + (mrow + r - tileM)] = s;
      }
    }
    __syncthreads();
    if (tid < 256)
      rsumP[(long)(tileN >> 8) * 8192 + tileM + tid] =
          rsh[tid] + rsh[256 + tid] + rsh[512 + tid] + rsh[768 + tid];
  } else {
#pragma unroll
    for (int mi = 0; mi < 8; ++mi) {
      const int mrow = rb + mi * 16;
#pragma unroll
      for (int ni = 0; ni < 4; ++ni) {
        const int col = cb + ni * 16;
        const float bv = bb[col];
#pragma unroll
        for (int r = 0; r < 4; ++r)
          Cp[(long)(mrow + r) * 1024 + col] = f2bf(acc[mi][ni][r] + bv);
      }
    }
  }
}

// =============== 256x128 BK=64, 3-deep full-tile ring, 2 phases/K-tile =======
// MODE: 3 = f32 out batched ; 4 = compose splitK4 partial
template<int MODE, int NKT = 16>
__global__ __launch_bounds__(512, 2)
void gemm128(const ushort* __restrict__ A, const ushort* __restrict__ Bm,
             const float* __restrict__ bias1, void* __restrict__ C1,
             int ldA, int ldB, long sAz, long sBz, long sCz,
             float* __restrict__ psumG)
{
  __shared__ alignas(16) ushort AbS[3 * 16384];
  __shared__ alignas(16) ushort BbS[3 * 8192];

  const int gx = gridDim.x, gy = gridDim.y;
  const int nwg = gx * gy * gridDim.z;
  int fid = (blockIdx.z * gy + blockIdx.y) * gx + blockIdx.x;
  fid = (fid & 7) * (nwg >> 3) + (fid >> 3);
  const int bx = fid % gx;
  const int by = (fid / gx) % gy;
  const int bz = fid / (gx * gy);
  const int tileM = by * 256, tileN = bx * 128;

  const ushort* Ap = A;
  const ushort* Bp = Bm;
  if constexpr (MODE == 4) {
    Ap += (long)(bz >> 2) * sAz + (long)(bz & 3) * 256;
    Bp += (long)(bz >> 2) * sBz + (long)(bz & 3) * 256;
  } else {
    Ap += (long)bz * sAz;
    Bp += (long)bz * sBz;
  }

  const int tid  = threadIdx.x;
  const int wid  = tid >> 6;
  const int lane = tid & 63;
  const int wm   = wid >> 1;
  const int wn   = wid & 1;

  const int srow8 = tid >> 3;
  const int scol8 = ((tid & 7) ^ (srow8 & 7)) << 3;
  const ushort* gAs = Ap + (long)(tileM + srow8) * ldA + scol8;
  const ushort* gBs = Bp + (long)(tileN + srow8) * ldB + scol8;
  const int sdst = tid << 3;

#define STA(b, i, t) async16(gAs + (long)((i) * 64) * ldA + (t) * 64, \
                             AbS + (b) * 16384 + (i) * 4096 + sdst)
#define STB(b, i, t) async16(gBs + (long)((i) * 64) * ldB + (t) * 64, \
                             BbS + (b) * 8192 + (i) * 4096 + sdst)

  const int frow = lane & 15;
  const int kg   = lane >> 4;
  const int ck0 = ((kg       ^ (frow & 7)) << 3);
  const int ck1 = (((4 + kg) ^ (frow & 7)) << 3);
  int aoffr[4], boffr[4];
#pragma unroll
  for (int mi = 0; mi < 4; ++mi) aoffr[mi] = (wm * 64 + mi * 16 + frow) * 64;
#pragma unroll
  for (int n = 0; n < 4; ++n)    boffr[n]  = (wn * 64 + n * 16 + frow) * 64;

  f32x4 acc[4][4];
#pragma unroll
  for (int i = 0; i < 4; ++i)
#pragma unroll
    for (int j = 0; j < 4; ++j) acc[i][j] = (f32x4){0.f, 0.f, 0.f, 0.f};

#pragma unroll
  for (int i = 0; i < 4; ++i) STA(0, i, 0);
  STB(0, 0, 0); STB(0, 1, 0);
#pragma unroll
  for (int i = 0; i < 4; ++i) STA(1, i, 1);
  STB(1, 0, 1); STB(1, 1, 1);
  asm volatile("s_waitcnt vmcnt(6)" ::: "memory");
  __builtin_amdgcn_s_barrier();

#pragma unroll 1
  for (int t = 0; t < NKT; ++t) {
    const int bufT = t - (t / 3) * 3;
    const int nb   = (t + 2) - ((t + 2) / 3) * 3;
    const ushort* Ac = AbS + bufT * 16384;
    const ushort* Bc = BbS + bufT * 8192;
    bf16x8 fa[4], fb[4];

#pragma unroll
    for (int n = 0; n < 4; ++n) fb[n] = *(const bf16x8*)(Bc + boffr[n] + ck0);
#pragma unroll
    for (int m = 0; m < 4; ++m) fa[m] = *(const bf16x8*)(Ac + aoffr[m] + ck0);
    if (t <= NKT - 3) { STA(nb, 0, t + 2); STA(nb, 1, t + 2); STA(nb, 2, t + 2); STA(nb, 3, t + 2); }
    PH_SYNC_IN();
#pragma unroll
    for (int m = 0; m < 4; ++m)
#pragma unroll
      for (int n = 0; n < 4; ++n)
        acc[m][n] = __builtin_amdgcn_mfma_f32_16x16x32_bf16(fa[m], fb[n], acc[m][n], 0, 0, 0);
    PH_SYNC_OUT();

#pragma unroll
    for (int n = 0; n < 4; ++n) fb[n] = *(const bf16x8*)(Bc + boffr[n] + ck1);
#pragma unroll
    for (int m = 0; m < 4; ++m) fa[m] = *(const bf16x8*)(Ac + aoffr[m] + ck1);
    if (t <= NKT - 3) { STB(nb, 0, t + 2); STB(nb, 1, t + 2); }
    if (t <= NKT - 3)      { asm volatile("s_waitcnt vmcnt(6)" ::: "memory"); }
    else if (t == NKT - 2) { asm volatile("s_waitcnt vmcnt(0)" ::: "memory"); }
    PH_SYNC_IN();
#pragma unroll
    for (int m = 0; m < 4; ++m)
#pragma unroll
      for (int n = 0; n < 4; ++n)
        acc[m][n] = __builtin_amdgcn_mfma_f32_16x16x32_bf16(fa[m], fb[n], acc[m][n], 0, 0, 0);
    PH_SYNC_OUT();
  }
#undef STA
#undef STB

  const int cb = tileN + wn * 64 + (lane & 15);
  const int rb = tileM + wm * 64 + ((lane >> 4) << 2);

  if constexpr (MODE == 4) {
    const int comp = bz >> 2, sp = bz & 3;
    ushort* Cp = (ushort*)C1 + ((long)sp * 2 + comp) * ((long)D_ * D_);
#pragma unroll
    for (int ni = 0; ni < 4; ++ni) {
      const int col = cb + ni * 16;
#pragma unroll
      for (int mi = 0; mi < 4; ++mi)
#pragma unroll
        for (int r = 0; r < 4; ++r)
          Cp[(long)(rb + mi * 16 + r) * 1024 + col] = f2bf(acc[mi][ni][r]);
    }
  } else {
    float* Cp = (float*)C1 + (long)bz * sCz;
#pragma unroll
    for (int ni = 0; ni < 4; ++ni) {
      const int col = cb + ni * 16;
#pragma unroll
      for (int mi = 0; mi < 4; ++mi)
#pragma unroll
        for (int r = 0; r < 4; ++r)
          Cp[(long)(rb + mi * 16 + r) * 1024 + col] = acc[mi][ni][r];
    }
  }
}

// =============== merged MT-partials + E GEMM (512 blocks) =====================
// grid (8,4,16). bz<8: MT split-K partial (MODE2 semantics): A=ovT,B=lT,ld=2048.
// bz>=8: E = exp(xBf2@wc2^T + bc2) + colsum atomics: tileM=((bz-8)*4+by)*256.
__global__ __launch_bounds__(512, 2)
void gemm_me(const ushort* __restrict__ ovT, const ushort* __restrict__ lT,
             ushort* __restrict__ part,
             const ushort* __restrict__ xBf2, const ushort* __restrict__ wc2,
             const float* __restrict__ bias2, ushort* __restrict__ Eout,
             float* __restrict__ psumG)
{
  __shared__ alignas(16) ushort AbS[3 * 16384];
  __shared__ alignas(16) ushort BbS[3 * 8192];

  const int gx = gridDim.x, gy = gridDim.y;
  const int nwg = gx * gy * gridDim.z;
  int fid = (blockIdx.z * gy + blockIdx.y) * gx + blockIdx.x;
  fid = (fid & 7) * (nwg >> 3) + (fid >> 3);
  const int bx = fid % gx;
  const int by = (fid / gx) % gy;
  const int bz = fid / (gx * gy);

  const bool isE = bz >= 8;
  const int tileN = bx * 128;
  int tileM;
  const ushort* Ap; const ushort* Bp; long ld;
  if (isE) {
    tileM = ((bz - 8) * 4 + by) * 256;
    Ap = xBf2; Bp = wc2; ld = 1024;
  } else {
    tileM = by * 256;
    const long off = (long)(bz >> 1) * ((long)D_ * T_) + (long)(bz & 1) * 1024;
    Ap = ovT + off; Bp = lT + off; ld = 2048;
  }

  const int tid  = threadIdx.x;
  const int wid  = tid >> 6;
  const int lane = tid & 63;
  const int wm   = wid >> 1;
  const int wn   = wid & 1;

  const int srow8 = tid >> 3;
  const int scol8 = ((tid & 7) ^ (srow8 & 7)) << 3;
  const ushort* gAs = Ap + (long)(tileM + srow8) * ld + scol8;
  const ushort* gBs = Bp + (long)(tileN + srow8) * ld + scol8;
  const int sdst = tid << 3;

#define STA(b, i, t) async16(gAs + (long)((i) * 64) * ld + (t) * 64, \
                             AbS + (b) * 16384 + (i) * 4096 + sdst)
#define STB(b, i, t) async16(gBs + (long)((i) * 64) * ld + (t) * 64, \
                             BbS + (b) * 8192 + (i) * 4096 + sdst)

  const int frow = lane & 15;
  const int kg   = lane >> 4;
  const int ck0 = ((kg       ^ (frow & 7)) << 3);
  const int ck1 = (((4 + kg) ^ (frow & 7)) << 3);
  int aoffr[4], boffr[4];
#pragma unroll
  for (int mi = 0; mi < 4; ++mi) aoffr[mi] = (wm * 64 + mi * 16 + frow) * 64;
#pragma unroll
  for (int n = 0; n < 4; ++n)    boffr[n]  = (wn * 64 + n * 16 + frow) * 64;

  f32x4 acc[4][4];
#pragma unroll
  for (int i = 0; i < 4; ++i)
#pragma unroll
    for (int j = 0; j < 4; ++j) acc[i][j] = (f32x4){0.f, 0.f, 0.f, 0.f};

#pragma unroll
  for (int i = 0; i < 4; ++i) STA(0, i, 0);
  STB(0, 0, 0); STB(0, 1, 0);
#pragma unroll
  for (int i = 0; i < 4; ++i) STA(1, i, 1);
  STB(1, 0, 1); STB(1, 1, 1);
  asm volatile("s_waitcnt vmcnt(6)" ::: "memory");
  __builtin_amdgcn_s_barrier();

#pragma unroll 1
  for (int t = 0; t < 16; ++t) {
    const int bufT = t - (t / 3) * 3;
    const int nb   = (t + 2) - ((t + 2) / 3) * 3;
    const ushort* Ac = AbS + bufT * 16384;
    const ushort* Bc = BbS + bufT * 8192;
    bf16x8 fa[4], fb[4];

#pragma unroll
    for (int n = 0; n < 4; ++n) fb[n] = *(const bf16x8*)(Bc + boffr[n] + ck0);
#pragma unroll
    for (int m = 0; m < 4; ++m) fa[m] = *(const bf16x8*)(Ac + aoffr[m] + ck0);
    if (t <= 13) { STA(nb, 0, t + 2); STA(nb, 1, t + 2); STA(nb, 2, t + 2); STA(nb, 3, t + 2); }
    PH_SYNC_IN();
#pragma unroll
    for (int m = 0; m < 4; ++m)
#pragma unroll
      for (int n = 0; n < 4; ++n)
        acc[m][n] = __builtin_amdgcn_mfma_f32_16x16x32_bf16(fa[m], fb[n], acc[m][n], 0, 0, 0);
    PH_SYNC_OUT();

#pragma unroll
    for (int n = 0; n < 4; ++n) fb[n] = *(const bf16x8*)(Bc + boffr[n] + ck1);
#pragma unroll
    for (int m = 0; m < 4; ++m) fa[m] = *(const bf16x8*)(Ac + aoffr[m] + ck1);
    if (t <= 13) { STB(nb, 0, t + 2); STB(nb, 1, t + 2); }
    if (t <= 13)      { asm volatile("s_waitcnt vmcnt(6)" ::: "memory"); }
    else if (t == 14) { asm volatile("s_waitcnt vmcnt(0)" ::: "memory"); }
    PH_SYNC_IN();
#pragma unroll
    for (int m = 0; m < 4; ++m)
#pragma unroll
      for (int n = 0; n < 4; ++n)
        acc[m][n] = __builtin_amdgcn_mfma_f32_16x16x32_bf16(fa[m], fb[n], acc[m][n], 0, 0, 0);
    PH_SYNC_OUT();
  }
#undef STA
#undef STB

  const int cb = tileN + wn * 64 + (lane & 15);
  const int rb = tileM + wm * 64 + ((lane >> 4) << 2);

  if (isE) {
    const int bE = tileM >> 11;
#pragma unroll
    for (int ni = 0; ni < 4; ++ni) {
      const int col = cb + ni * 16;
      const float bv = bias2[col];
      float cs = 0.f;
#pragma unroll
      for (int mi = 0; mi < 4; ++mi)
#pragma unroll
        for (int r = 0; r < 4; ++r) {
          const ushort ev = f2bf(__expf(acc[mi][ni][r] + bv));
          Eout[(long)(rb + mi * 16 + r) * 1024 + col] = ev;
          cs += bf2f(ev);
        }
      cs += __shfl_xor(cs, 16);
      cs += __shfl_xor(cs, 32);
      if ((lane >> 4) == 0) atomicAdd(psumG + (long)bE * D_ + col, cs);
    }
  } else {
    ushort* Cp = part + ((long)(bz & 1) * B_ + (bz >> 1)) * ((long)D_ * D_);
#pragma unroll
    for (int ni = 0; ni < 4; ++ni) {
      const int col = cb + ni * 16;
#pragma unroll
      for (int mi = 0; mi < 4; ++mi)
#pragma unroll
        for (int r = 0; r < 4; ++r)
          Cp[(long)(rb + mi * 16 + r) * 1024 + col] = f2bf(acc[mi][ni][r]);
    }
  }
}

// reduce compose split-K partials
__global__ __launch_bounds__(256)
void reduce4(const ushort* __restrict__ P, ushort* __restrict__ wCat)
{
  const long NW = (long)D_ * D_;
  const long i = ((long)blockIdx.x * 256 + threadIdx.x) * 8;
  float s[8] = {0.f, 0.f, 0.f, 0.f, 0.f, 0.f, 0.f, 0.f};
#pragma unroll
  for (int sp = 0; sp < 4; ++sp) {
    bf16x8 p = *(const bf16x8*)(P + (long)sp * 2 * NW + i);
#pragma unroll
    for (int j = 0; j < 8; ++j) s[j] += bf2f((ushort)p[j]);
  }
  const long comp = (i >= NW) ? 1 : 0;
  ushort* out = wCat + comp * 2 * NW + (i - comp * NW);
  bf16x8 o;
#pragma unroll
  for (int j = 0; j < 8; ++j) o[j] = (short)f2bf(s[j]);
  *(bf16x8*)out = o;
}

// merged transpose: z<B_: lT = (exp(S1)/rowsum)^T ; z>=B_: ovT = ov^T
__global__ __launch_bounds__(256)
void transposeF(const ushort* __restrict__ l, ushort* __restrict__ lT,
                const ushort* __restrict__ ov, ushort* __restrict__ ovT,
                const float* __restrict__ rsumP)
{
  __shared__ alignas(16) ushort t[64 * 65];
  const int z = blockIdx.z;
  const int b = z & (B_ - 1);
  const bool isL = z < B_;
  const ushort* in = (isL ? l : ov) + (long)b * T_ * D_;
  ushort* out      = (isL ? lT : ovT) + (long)b * (long)D_ * T_;
  const int c0 = blockIdx.x * 64, r0 = blockIdx.y * 64;
  const int tx = threadIdx.x & 15, ty = threadIdx.x >> 4;
#pragma unroll
  for (int i = 0; i < 4; ++i) {
    const int r = ty + i * 16;
    u16x4 v = *(const u16x4*)(in + (long)(r0 + r) * D_ + c0 + tx * 4);
    if (isL) {
      const long gr = (long)b * T_ + r0 + r;
      const float ri = 1.f / (rsumP[gr] + rsumP[8192 + gr] +
                              rsumP[16384 + gr] + rsumP[24576 + gr]);
#pragma unroll
      for (int c = 0; c < 4; ++c) t[(tx * 4 + c) * 65 + r] = f2bf(__expf(bf2f(v[c])) * ri);
    } else {
#pragma unroll
      for (int c = 0; c < 4; ++c) t[(tx * 4 + c) * 65 + r] = v[c];
    }
  }
  __syncthreads();
#pragma unroll
  for (int i = 0; i < 4; ++i) {
    const int c = ty + i * 16;
    u16x4 v;
#pragma unroll
    for (int j = 0; j < 4; ++j) v[j] = t[c * 65 + tx * 4 + j];
    *(u16x4*)(out + (long)(c0 + c) * T_ + r0 + tx * 4) = v;
  }
}

// MT2[b][d][e] = (p0+p1) / psum[b][e]
__global__ __launch_bounds__(256)
void reduce2_scale(const ushort* __restrict__ P, const float* __restrict__ psum,
                   ushort* __restrict__ MT)
{
  const long stride = (long)B_ * D_ * D_;
  const long base = ((long)blockIdx.x * 256 + threadIdx.x) * 8;
  const int b = (int)(base >> 20);
  const int e0 = (int)(base & (D_ - 1));
  bf16x8 p0 = *(const bf16x8*)(P + base);
  bf16x8 p1 = *(const bf16x8*)(P + stride + base);
  const float4 c0 = *(const float4*)(psum + (long)b * D_ + e0);
  const float4 c1 = *(const float4*)(psum + (long)b * D_ + e0 + 4);
  const float cc[8] = {1.f / c0.x, 1.f / c0.y, 1.f / c0.z, 1.f / c0.w,
                       1.f / c1.x, 1.f / c1.y, 1.f / c1.z, 1.f / c1.w};
  bf16x8 o;
#pragma unroll
  for (int j = 0; j < 8; ++j)
    o[j] = (short)f2bf((bf2f((ushort)p0[j]) + bf2f((ushort)p1[j])) * cc[j]);
  *(bf16x8*)(MT + base) = o;
}

extern "C" void kernel_launch(void* const* d_in, const int* in_sizes, int n_in,
                              void* d_out, int out_size, void* d_ws, size_t ws_size,
                              hipStream_t stream)
{
  (void)in_sizes; (void)n_in; (void)out_size; (void)ws_size;
  const float* lat = (const float*)d_in[0];
  const float* inp = (const float*)d_in[1];
  const float* Wl  = (const float*)d_in[2];
  const float* bl  = (const float*)d_in[3];
  const float* Wu  = (const float*)d_in[4];
  const float* bu  = (const float*)d_in[5];
  const float* WA  = (const float*)d_in[6];
  const float* bA  = (const float*)d_in[7];
  const float* WV  = (const float*)d_in[8];
  const float* bV  = (const float*)d_in[9];
  const float* Wo  = (const float*)d_in[10];
  const float* bo  = (const float*)d_in[11];

  char* w = (char*)d_ws;
  auto carve = [&](size_t bytes) { char* p = w; w += (bytes + 255) & ~(size_t)255; return p; };
  const long NT = (long)B_ * T_ * D_;
  const long NW = (long)D_ * D_;
  ushort* xBf   = (ushort*)carve(NT * 2);
  ushort* xBf2  = (ushort*)carve(NT * 2);
  ushort* bufA  = (ushort*)carve(NT * 2);
  ushort* bufB  = (ushort*)carve(NT * 2);
  ushort* scr   = (ushort*)carve(NT * 2);
  ushort* MT    = (ushort*)carve((long)B_ * NW * 2);
  ushort* wCat  = (ushort*)carve(3 * NW * 2);
  float*  bc    = (float*)carve(D_ * 4);
  float*  bc2   = (float*)carve(D_ * 4);
  float*  psum  = (float*)carve((long)B_ * D_ * 4);
  float*  rsumP = (float*)carve(4L * B_ * T_ * 4);
  ushort* w1 = scr;              // [Wu_bf ; WV_bf]
  ushort* w2 = scr + 2 * NW;     // [WlT ; WAT]
  ushort* Pc = bufA;             // compose splitK partials (dead before bufA's first write)
  ushort* ovT = scr;             // after compose, scr dead -> ovT
  ushort* part = bufB;           // after transposes, bufB dead -> splitk partials

  const dim3 blk(256, 1, 1);
  const dim3 blk5(512, 1, 1);

  // 1. fused prep (incl. psum zeroing)
  prep<<<dim3(20496), blk, 0, stream>>>(lat, inp, Wl, bl, Wu, bu, WA, bA, WV, bV, Wo, bo,
                                        xBf, xBf2, w1, w2, wCat + NW, bc, bc2, psum);
  // 2. weight compose, split-K=4 + reduce
  gemm128<4, 4><<<dim3(8, 4, 8), blk5, 0, stream>>>(
      w1, w2, nullptr, Pc, D_, D_, NW, NW, 0, nullptr);
  reduce4<<<dim3(1024), blk, 0, stream>>>(Pc, wCat);
  // 3. S1 (bufB) + ov (bufA) + fused row exp-sums -> rsumP
  gemm256<<<dim3(8, 32, 1), blk5, 0, stream>>>(
      xBf, wCat, bc, bo, bufB, bufA, D_, D_, rsumP);
  // 4. fused softmax-transpose (l) + transpose (ov)
  transposeF<<<dim3(16, 32, 2 * B_), blk, 0, stream>>>(bufB, xBf, bufA, ovT, rsumP);
  // 5. merged MT partials + E (512 blocks)
  gemm_me<<<dim3(8, 4, 16), blk5, 0, stream>>>(
      ovT, xBf, part, xBf2, wCat + 2 * NW, bc2, bufA, psum);
  // 6. combine splitK + scale by 1/psum
  reduce2_scale<<<dim3(2048), blk, 0, stream>>>(part, psum, MT);
  // 7. final, 256 blocks
  gemm128<3><<<dim3(8, 8, 4), blk5, 0, stream>>>(
      bufA, MT, nullptr, d_out, D_, D_,
      (long)T_ * D_, NW, (long)T_ * D_, nullptr);
}

// Round 11
// 286.034 us; speedup vs baseline: 1.2560x; 1.0068x over previous
//
#include <hip/hip_runtime.h>
#include <hip/hip_bf16.h>
#include <stdint.h>

typedef __attribute__((ext_vector_type(8))) short bf16x8;
typedef __attribute__((ext_vector_type(4))) float f32x4;
typedef __attribute__((ext_vector_type(4))) unsigned short u16x4;

#define B_  4
#define T_  2048
#define D_  1024

__device__ __forceinline__ float bf2f(ushort u) {
  union { unsigned int i; float f; } v; v.i = ((unsigned int)u) << 16; return v.f;
}
__device__ __forceinline__ ushort f2bf(float f) {
  return (ushort)(__bfloat16_as_ushort(__float2bfloat16(f)));
}
__device__ __forceinline__ void async16(const void* g, void* l) {
  __builtin_amdgcn_global_load_lds(
      (const __attribute__((address_space(1))) void*)g,
      (__attribute__((address_space(3))) void*)l, 16, 0, 0);
}

// ---------------- fused prep (+ psum zeroing, blocks 20480..20495) ----------------
__global__ __launch_bounds__(256)
void prep(const float* __restrict__ lat, const float* __restrict__ inp,
          const float* __restrict__ Wl, const float* __restrict__ bl,
          const float* __restrict__ Wu, const float* __restrict__ bu,
          const float* __restrict__ WA, const float* __restrict__ bA,
          const float* __restrict__ WV, const float* __restrict__ bV,
          const float* __restrict__ Wo, const float* __restrict__ bo,
          ushort* __restrict__ xBf, ushort* __restrict__ xBf2,
          ushort* __restrict__ w1, ushort* __restrict__ w2,
          ushort* __restrict__ wCatWo, float* __restrict__ bc, float* __restrict__ bc2,
          float* __restrict__ psum)
{
  __shared__ alignas(16) ushort t[64 * 65];
  const long NW = (long)D_ * D_;
  const int bx = blockIdx.x;
  const int tid = threadIdx.x;
  if (bx < 16384) {
    const float* in = bx < 8192 ? lat : inp;
    ushort* out = bx < 8192 ? xBf : xBf2;
    const long i = (long)(bx & 8191) * 256 + tid;
    const float4 v = *(const float4*)(in + i * 4);
    u16x4 o;
    o[0] = f2bf(v.x); o[1] = f2bf(v.y); o[2] = f2bf(v.z); o[3] = f2bf(v.w);
    *(u16x4*)(out + i * 4) = o;
  } else if (bx < 19456) {
    const int seg = (bx - 16384) >> 10;
    const float* in  = seg == 0 ? Wu : (seg == 1 ? WV : Wo);
    ushort* out = seg == 0 ? w1 : (seg == 1 ? w1 + NW : wCatWo);
    const long i = (long)((bx - 16384) & 1023) * 256 + tid;
    const float4 v = *(const float4*)(in + i * 4);
    u16x4 o;
    o[0] = f2bf(v.x); o[1] = f2bf(v.y); o[2] = f2bf(v.z); o[3] = f2bf(v.w);
    *(u16x4*)(out + i * 4) = o;
  } else if (bx < 19968) {
    const int z = (bx - 19456) >> 8;
    const int w = (bx - 19456) & 255;
    const float* in = z ? WA : Wl;
    ushort* out = z ? w2 + NW : w2;
    const int c0 = (w & 15) * 64, r0 = (w >> 4) * 64;
    const int tx = tid & 15, ty = tid >> 4;
#pragma unroll
    for (int i = 0; i < 4; ++i) {
      const int r = ty + i * 16;
      const float4 v = *(const float4*)(in + (long)(r0 + r) * D_ + c0 + tx * 4);
      t[(tx * 4 + 0) * 65 + r] = f2bf(v.x);
      t[(tx * 4 + 1) * 65 + r] = f2bf(v.y);
      t[(tx * 4 + 2) * 65 + r] = f2bf(v.z);
      t[(tx * 4 + 3) * 65 + r] = f2bf(v.w);
    }
    __syncthreads();
#pragma unroll
    for (int i = 0; i < 4; ++i) {
      const int c = ty + i * 16;
      u16x4 v;
#pragma unroll
      for (int j = 0; j < 4; ++j) v[j] = t[c * 65 + tx * 4 + j];
      *(u16x4*)(out + (long)(c0 + c) * D_ + r0 + tx * 4) = v;
    }
  } else if (bx < 20480) {
    const int z = (bx - 19968) >> 8;
    const int w = (bx - 19968) & 255;
    const float* W    = z ? WV : Wu;
    const float* bin  = z ? bA : bl;
    const float* badd = z ? bV : bu;
    float* out        = z ? bc2 : bc;
    const int wv = tid >> 6, lane = tid & 63;
    const int e = w * 4 + wv;
    const float* row = W + (long)e * D_;
    float s = 0.f;
#pragma unroll
    for (int i = 0; i < 16; ++i) s += row[lane + i * 64] * bin[lane + i * 64];
#pragma unroll
    for (int off = 32; off; off >>= 1) s += __shfl_xor(s, off);
    if (lane == 0) out[e] = s + badd[e];
  } else {
    psum[(bx - 20480) * 256 + tid] = 0.f;
  }
}

// Phase skeleton (m201 template)
#define PH_SYNC_IN()                                               \
  __builtin_amdgcn_s_barrier();                                    \
  asm volatile("s_waitcnt lgkmcnt(0)" ::: "memory");               \
  __builtin_amdgcn_sched_barrier(0);                               \
  __builtin_amdgcn_s_setprio(1)
#define PH_SYNC_OUT()                                              \
  __builtin_amdgcn_s_setprio(0);                                   \
  __builtin_amdgcn_s_barrier()

// 256x256 4-phase K-loop body (shared by gemm256 / gemm_me2). Expects:
// AbS/BbS, gAs/gBs, ldA/ldB, sdst, aoffr/boffr, ck0/ck1, acc declared.
#define CORE256_LOOP(ldA_, ldB_)                                             \
  _Pragma("unroll")                                                          \
  for (int i = 0; i < 4; ++i) STA(0, i, 0);                                  \
  _Pragma("unroll")                                                          \
  for (int i = 0; i < 4; ++i) STB(0, i, 0);                                  \
  _Pragma("unroll")                                                          \
  for (int i = 0; i < 4; ++i) STA(1, i, 1);                                  \
  _Pragma("unroll")                                                          \
  for (int i = 0; i < 4; ++i) STB(1, i, 1);                                  \
  asm volatile("s_waitcnt vmcnt(8)" ::: "memory");                           \
  __builtin_amdgcn_s_barrier();                                              \
  _Pragma("unroll 1")                                                        \
  for (int t = 0; t < 16; ++t) {                                             \
    const int buf = t & 1;                                                   \
    const int bB  = t - (t / 3) * 3;                                         \
    const int nA  = (t + 1) & 1;                                             \
    const int nB  = (t + 2) - ((t + 2) / 3) * 3;                             \
    const ushort* Ac = AbS + buf * 16384;                                    \
    const ushort* Bc = BbS + bB * 16384;                                     \
    bf16x8 fa[4], fb[4], ga[4];                                              \
    _Pragma("unroll")                                                        \
    for (int n = 0; n < 4; ++n) fb[n] = *(const bf16x8*)(Bc + boffr[n] + ck0); \
    _Pragma("unroll")                                                        \
    for (int m = 0; m < 4; ++m) fa[m] = *(const bf16x8*)(Ac + aoffr[m] + ck0); \
    if (t >= 1 && t <= 14) { STA(nA, 0, t + 1); STA(nA, 1, t + 1); }         \
    PH_SYNC_IN();                                                            \
    _Pragma("unroll")                                                        \
    for (int m = 0; m < 4; ++m)                                              \
      _Pragma("unroll")                                                      \
      for (int n = 0; n < 4; ++n)                                            \
        acc[m][n] = __builtin_amdgcn_mfma_f32_16x16x32_bf16(fa[m], fb[n], acc[m][n], 0, 0, 0); \
    PH_SYNC_OUT();                                                           \
    _Pragma("unroll")                                                        \
    for (int m = 0; m < 4; ++m) ga[m] = *(const bf16x8*)(Ac + aoffr[4 + m] + ck0); \
    if (t >= 1 && t <= 14) { STA(nA, 2, t + 1); STA(nA, 3, t + 1); }         \
    if (t <= 13)           { STB(nB, 0, t + 2); STB(nB, 1, t + 2); }         \
    PH_SYNC_IN();                                                            \
    _Pragma("unroll")                                                        \
    for (int m = 0; m < 4; ++m)                                              \
      _Pragma("unroll")                                                      \
      for (int n = 0; n < 4; ++n)                                            \
        acc[4 + m][n] = __builtin_amdgcn_mfma_f32_16x16x32_bf16(ga[m], fb[n], acc[4 + m][n], 0, 0, 0); \
    PH_SYNC_OUT();                                                           \
    _Pragma("unroll")                                                        \
    for (int n = 0; n < 4; ++n) fb[n] = *(const bf16x8*)(Bc + boffr[n] + ck1); \
    _Pragma("unroll")                                                        \
    for (int m = 0; m < 4; ++m) fa[m] = *(const bf16x8*)(Ac + aoffr[m] + ck1); \
    if (t <= 13) { STB(nB, 2, t + 2); STB(nB, 3, t + 2); }                   \
    PH_SYNC_IN();                                                            \
    _Pragma("unroll")                                                        \
    for (int m = 0; m < 4; ++m)                                              \
      _Pragma("unroll")                                                      \
      for (int n = 0; n < 4; ++n)                                            \
        acc[m][n] = __builtin_amdgcn_mfma_f32_16x16x32_bf16(fa[m], fb[n], acc[m][n], 0, 0, 0); \
    PH_SYNC_OUT();                                                           \
    _Pragma("unroll")                                                        \
    for (int m = 0; m < 4; ++m) ga[m] = *(const bf16x8*)(Ac + aoffr[4 + m] + ck1); \
    if (t <= 13)      { asm volatile("s_waitcnt vmcnt(4)" ::: "memory"); }   \
    else if (t == 14) { asm volatile("s_waitcnt vmcnt(0)" ::: "memory"); }   \
    PH_SYNC_IN();                                                            \
    _Pragma("unroll")                                                        \
    for (int m = 0; m < 4; ++m)                                              \
      _Pragma("unroll")                                                      \
      for (int n = 0; n < 4; ++n)                                            \
        acc[4 + m][n] = __builtin_amdgcn_mfma_f32_16x16x32_bf16(ga[m], fb[n], acc[4 + m][n], 0, 0, 0); \
    PH_SYNC_OUT();                                                           \
  }

// =============== 256x256 dual GEMM + fused row exp-sum partials ===========
__global__ __launch_bounds__(512, 2)
void gemm256(const ushort* __restrict__ A, const ushort* __restrict__ Bm,
             const float* __restrict__ bias1, const float* __restrict__ bias2,
             ushort* __restrict__ C1, ushort* __restrict__ C2,
             int ldA, int ldB, float* __restrict__ rsumP)
{
  __shared__ alignas(16) ushort AbS[2 * 16384];
  __shared__ alignas(16) ushort BbS[3 * 16384];

  const int gx = gridDim.x;
  const int nwg = gx * gridDim.y;
  int fid = blockIdx.y * gx + blockIdx.x;
  fid = (fid & 7) * (nwg >> 3) + (fid >> 3);
  const int bx = fid % gx;
  const int by = fid / gx;
  const int tileM = by * 256, tileN = bx * 256;

  const int tid  = threadIdx.x;
  const int wid  = tid >> 6;
  const int lane = tid & 63;
  const int wm   = wid >> 2;
  const int wn   = wid & 3;

  const int srow8 = tid >> 3;
  const int scol8 = ((tid & 7) ^ (srow8 & 7)) << 3;
  const ushort* gAs = A  + (long)(tileM + srow8) * ldA + scol8;
  const ushort* gBs = Bm + (long)(tileN + srow8) * ldB + scol8;
  const int sdst = tid << 3;

#define STA(b, i, t) async16(gAs + (long)((i) * 64) * ldA + (t) * 64, \
                             AbS + (b) * 16384 + (i) * 4096 + sdst)
#define STB(b, i, t) async16(gBs + (long)((i) * 64) * ldB + (t) * 64, \
                             BbS + (b) * 16384 + (i) * 4096 + sdst)

  const int frow = lane & 15;
  const int kg   = lane >> 4;
  const int ck0 = ((kg       ^ (frow & 7)) << 3);
  const int ck1 = (((4 + kg) ^ (frow & 7)) << 3);
  int aoffr[8], boffr[4];
#pragma unroll
  for (int mi = 0; mi < 8; ++mi) aoffr[mi] = (wm * 128 + mi * 16 + frow) * 64;
#pragma unroll
  for (int n = 0; n < 4; ++n)    boffr[n]  = (wn * 64 + n * 16 + frow) * 64;

  f32x4 acc[8][4];
#pragma unroll
  for (int i = 0; i < 8; ++i)
#pragma unroll
    for (int j = 0; j < 4; ++j) acc[i][j] = (f32x4){0.f, 0.f, 0.f, 0.f};

  CORE256_LOOP(ldA, ldB)
#undef STA
#undef STB

  const bool second = tileN >= 1024;
  ushort* Cp = second ? C2 : C1;
  const float* bb = second ? bias2 : bias1;
  const int cb = tileN - (second ? 1024 : 0) + wn * 64 + (lane & 15);
  const int rb = tileM + wm * 128 + ((lane >> 4) << 2);

  if (!second) {
    float bvv[4];
#pragma unroll
    for (int ni = 0; ni < 4; ++ni) bvv[ni] = bb[cb + ni * 16];
    float* rsh = (float*)AbS;
#pragma unroll
    for (int mi = 0; mi < 8; ++mi) {
      const int mrow = rb + mi * 16;
#pragma unroll
      for (int r = 0; r < 4; ++r) {
        float s = 0.f;
#pragma unroll
        for (int ni = 0; ni < 4; ++ni) {
          const ushort ev = f2bf(acc[mi][ni][r] + bvv[ni]);
          Cp[(long)(mrow + r) * 1024 + cb + ni * 16] = ev;
          s += __expf(bf2f(ev));
        }
        s += __shfl_xor(s, 1); s += __shfl_xor(s, 2);
        s += __shfl_xor(s, 4); s += __shfl_xor(s, 8);
        if ((lane & 15) == 0)
          rsh[wn * 256 + (mrow + r - tileM)] = s;
      }
    }
    __syncthreads();
    if (tid < 256)
      rsumP[(long)(tileN >> 8) * 8192 + tileM + tid] =
          rsh[tid] + rsh[256 + tid] + rsh[512 + tid] + rsh[768 + tid];
  } else {
#pragma unroll
    for (int mi = 0; mi < 8; ++mi) {
      const int mrow = rb + mi * 16;
#pragma unroll
      for (int ni = 0; ni < 4; ++ni) {
        const int col = cb + ni * 16;
        const float bv = bb[col];
#pragma unroll
        for (int r = 0; r < 4; ++r)
          Cp[(long)(mrow + r) * 1024 + col] = f2bf(acc[mi][ni][r] + bv);
      }
    }
  }
}

// =============== merged MT + E on the 256x256 core (256 blocks, 1 round) =====
// fid<128: MT splitK2 partial: z=fid&7 (b=z>>1, sp=z&1), tile=(fid>>3) 4x4;
//          A=ovT+off, B=lT+off, ld=2048; part[sp][b] bf16.
// fid>=128: E = exp(xBf2@wc2^T + bc2): id2=fid-128, tileM=(id2>>2)*256 (32),
//          tileN=(id2&3)*256 (4); ld=1024; + colsum atomics into psum.
__global__ __launch_bounds__(512, 2)
void gemm_me2(const ushort* __restrict__ ovT, const ushort* __restrict__ lT,
              ushort* __restrict__ part,
              const ushort* __restrict__ xBf2, const ushort* __restrict__ wc2,
              const float* __restrict__ bias2, ushort* __restrict__ Eout,
              float* __restrict__ psumG)
{
  __shared__ alignas(16) ushort AbS[2 * 16384];
  __shared__ alignas(16) ushort BbS[3 * 16384];

  int fid = blockIdx.x;
  fid = (fid & 7) * 32 + (fid >> 3);
  const bool isE = fid >= 128;
  int tileM, tileN, b = 0, sp = 0;
  const ushort* Ap; const ushort* Bp; long ld;
  if (isE) {
    const int id2 = fid - 128;
    tileM = (id2 >> 2) * 256;
    tileN = (id2 & 3) * 256;
    Ap = xBf2; Bp = wc2; ld = 1024;
  } else {
    const int z = fid & 7;
    b = z >> 1; sp = z & 1;
    const int tidx = fid >> 3;
    tileM = (tidx >> 2) * 256;
    tileN = (tidx & 3) * 256;
    const long off = (long)b * ((long)D_ * T_) + (long)sp * 1024;
    Ap = ovT + off; Bp = lT + off; ld = 2048;
  }

  const int tid  = threadIdx.x;
  const int wid  = tid >> 6;
  const int lane = tid & 63;
  const int wm   = wid >> 2;
  const int wn   = wid & 3;

  const int srow8 = tid >> 3;
  const int scol8 = ((tid & 7) ^ (srow8 & 7)) << 3;
  const ushort* gAs = Ap + (long)(tileM + srow8) * ld + scol8;
  const ushort* gBs = Bp + (long)(tileN + srow8) * ld + scol8;
  const int sdst = tid << 3;

#define STA(b_, i, t) async16(gAs + (long)((i) * 64) * ld + (t) * 64, \
                              AbS + (b_) * 16384 + (i) * 4096 + sdst)
#define STB(b_, i, t) async16(gBs + (long)((i) * 64) * ld + (t) * 64, \
                              BbS + (b_) * 16384 + (i) * 4096 + sdst)

  const int frow = lane & 15;
  const int kg   = lane >> 4;
  const int ck0 = ((kg       ^ (frow & 7)) << 3);
  const int ck1 = (((4 + kg) ^ (frow & 7)) << 3);
  int aoffr[8], boffr[4];
#pragma unroll
  for (int mi = 0; mi < 8; ++mi) aoffr[mi] = (wm * 128 + mi * 16 + frow) * 64;
#pragma unroll
  for (int n = 0; n < 4; ++n)    boffr[n]  = (wn * 64 + n * 16 + frow) * 64;

  f32x4 acc[8][4];
#pragma unroll
  for (int i = 0; i < 8; ++i)
#pragma unroll
    for (int j = 0; j < 4; ++j) acc[i][j] = (f32x4){0.f, 0.f, 0.f, 0.f};

  CORE256_LOOP(ld, ld)
#undef STA
#undef STB

  const int cb = tileN + wn * 64 + (lane & 15);
  const int rb = tileM + wm * 128 + ((lane >> 4) << 2);

  if (isE) {
    const int bE = tileM >> 11;
#pragma unroll
    for (int ni = 0; ni < 4; ++ni) {
      const int col = cb + ni * 16;
      const float bv = bias2[col];
      float cs = 0.f;
#pragma unroll
      for (int mi = 0; mi < 8; ++mi)
#pragma unroll
        for (int r = 0; r < 4; ++r) {
          const ushort ev = f2bf(__expf(acc[mi][ni][r] + bv));
          Eout[(long)(rb + mi * 16 + r) * 1024 + col] = ev;
          cs += bf2f(ev);
        }
      cs += __shfl_xor(cs, 16);
      cs += __shfl_xor(cs, 32);
      if ((lane >> 4) == 0) atomicAdd(psumG + (long)bE * D_ + col, cs);
    }
  } else {
    ushort* Cp = part + ((long)sp * B_ + b) * ((long)D_ * D_);
#pragma unroll
    for (int mi = 0; mi < 8; ++mi) {
      const int mrow = rb + mi * 16;
#pragma unroll
      for (int ni = 0; ni < 4; ++ni) {
        const int col = cb + ni * 16;
#pragma unroll
        for (int r = 0; r < 4; ++r)
          Cp[(long)(mrow + r) * 1024 + col] = f2bf(acc[mi][ni][r]);
      }
    }
  }
}

// =============== 256x128 BK=64, 3-deep full-tile ring (compose + final) ======
template<int MODE, int NKT = 16>
__global__ __launch_bounds__(512, 2)
void gemm128(const ushort* __restrict__ A, const ushort* __restrict__ Bm,
             const float* __restrict__ bias1, void* __restrict__ C1,
             int ldA, int ldB, long sAz, long sBz, long sCz,
             float* __restrict__ psumG)
{
  __shared__ alignas(16) ushort AbS[3 * 16384];
  __shared__ alignas(16) ushort BbS[3 * 8192];

  const int gx = gridDim.x, gy = gridDim.y;
  const int nwg = gx * gy * gridDim.z;
  int fid = (blockIdx.z * gy + blockIdx.y) * gx + blockIdx.x;
  fid = (fid & 7) * (nwg >> 3) + (fid >> 3);
  const int bx = fid % gx;
  const int by = (fid / gx) % gy;
  const int bz = fid / (gx * gy);
  const int tileM = by * 256, tileN = bx * 128;

  const ushort* Ap = A;
  const ushort* Bp = Bm;
  if constexpr (MODE == 4) {
    Ap += (long)(bz >> 2) * sAz + (long)(bz & 3) * 256;
    Bp += (long)(bz >> 2) * sBz + (long)(bz & 3) * 256;
  } else {
    Ap += (long)bz * sAz;
    Bp += (long)bz * sBz;
  }

  const int tid  = threadIdx.x;
  const int wid  = tid >> 6;
  const int lane = tid & 63;
  const int wm   = wid >> 1;
  const int wn   = wid & 1;

  const int srow8 = tid >> 3;
  const int scol8 = ((tid & 7) ^ (srow8 & 7)) << 3;
  const ushort* gAs = Ap + (long)(tileM + srow8) * ldA + scol8;
  const ushort* gBs = Bp + (long)(tileN + srow8) * ldB + scol8;
  const int sdst = tid << 3;

#define STA(b, i, t) async16(gAs + (long)((i) * 64) * ldA + (t) * 64, \
                             AbS + (b) * 16384 + (i) * 4096 + sdst)
#define STB(b, i, t) async16(gBs + (long)((i) * 64) * ldB + (t) * 64, \
                             BbS + (b) * 8192 + (i) * 4096 + sdst)

  const int frow = lane & 15;
  const int kg   = lane >> 4;
  const int ck0 = ((kg       ^ (frow & 7)) << 3);
  const int ck1 = (((4 + kg) ^ (frow & 7)) << 3);
  int aoffr[4], boffr[4];
#pragma unroll
  for (int mi = 0; mi < 4; ++mi) aoffr[mi] = (wm * 64 + mi * 16 + frow) * 64;
#pragma unroll
  for (int n = 0; n < 4; ++n)    boffr[n]  = (wn * 64 + n * 16 + frow) * 64;

  f32x4 acc[4][4];
#pragma unroll
  for (int i = 0; i < 4; ++i)
#pragma unroll
    for (int j = 0; j < 4; ++j) acc[i][j] = (f32x4){0.f, 0.f, 0.f, 0.f};

#pragma unroll
  for (int i = 0; i < 4; ++i) STA(0, i, 0);
  STB(0, 0, 0); STB(0, 1, 0);
#pragma unroll
  for (int i = 0; i < 4; ++i) STA(1, i, 1);
  STB(1, 0, 1); STB(1, 1, 1);
  asm volatile("s_waitcnt vmcnt(6)" ::: "memory");
  __builtin_amdgcn_s_barrier();

#pragma unroll 1
  for (int t = 0; t < NKT; ++t) {
    const int bufT = t - (t / 3) * 3;
    const int nb   = (t + 2) - ((t + 2) / 3) * 3;
    const ushort* Ac = AbS + bufT * 16384;
    const ushort* Bc = BbS + bufT * 8192;
    bf16x8 fa[4], fb[4];

#pragma unroll
    for (int n = 0; n < 4; ++n) fb[n] = *(const bf16x8*)(Bc + boffr[n] + ck0);
#pragma unroll
    for (int m = 0; m < 4; ++m) fa[m] = *(const bf16x8*)(Ac + aoffr[m] + ck0);
    if (t <= NKT - 3) { STA(nb, 0, t + 2); STA(nb, 1, t + 2); STA(nb, 2, t + 2); STA(nb, 3, t + 2); }
    PH_SYNC_IN();
#pragma unroll
    for (int m = 0; m < 4; ++m)
#pragma unroll
      for (int n = 0; n < 4; ++n)
        acc[m][n] = __builtin_amdgcn_mfma_f32_16x16x32_bf16(fa[m], fb[n], acc[m][n], 0, 0, 0);
    PH_SYNC_OUT();

#pragma unroll
    for (int n = 0; n < 4; ++n) fb[n] = *(const bf16x8*)(Bc + boffr[n] + ck1);
#pragma unroll
    for (int m = 0; m < 4; ++m) fa[m] = *(const bf16x8*)(Ac + aoffr[m] + ck1);
    if (t <= NKT - 3) { STB(nb, 0, t + 2); STB(nb, 1, t + 2); }
    if (t <= NKT - 3)      { asm volatile("s_waitcnt vmcnt(6)" ::: "memory"); }
    else if (t == NKT - 2) { asm volatile("s_waitcnt vmcnt(0)" ::: "memory"); }
    PH_SYNC_IN();
#pragma unroll
    for (int m = 0; m < 4; ++m)
#pragma unroll
      for (int n = 0; n < 4; ++n)
        acc[m][n] = __builtin_amdgcn_mfma_f32_16x16x32_bf16(fa[m], fb[n], acc[m][n], 0, 0, 0);
    PH_SYNC_OUT();
  }
#undef STA
#undef STB

  const int cb = tileN + wn * 64 + (lane & 15);
  const int rb = tileM + wm * 64 + ((lane >> 4) << 2);

  if constexpr (MODE == 4) {
    const int comp = bz >> 2, sp = bz & 3;
    ushort* Cp = (ushort*)C1 + ((long)sp * 2 + comp) * ((long)D_ * D_);
#pragma unroll
    for (int ni = 0; ni < 4; ++ni) {
      const int col = cb + ni * 16;
#pragma unroll
      for (int mi = 0; mi < 4; ++mi)
#pragma unroll
        for (int r = 0; r < 4; ++r)
          Cp[(long)(rb + mi * 16 + r) * 1024 + col] = f2bf(acc[mi][ni][r]);
    }
  } else {
    float* Cp = (float*)C1 + (long)bz * sCz;
#pragma unroll
    for (int ni = 0; ni < 4; ++ni) {
      const int col = cb + ni * 16;
#pragma unroll
      for (int mi = 0; mi < 4; ++mi)
#pragma unroll
        for (int r = 0; r < 4; ++r)
          Cp[(long)(rb + mi * 16 + r) * 1024 + col] = acc[mi][ni][r];
    }
  }
}

// reduce compose split-K partials
__global__ __launch_bounds__(256)
void reduce4(const ushort* __restrict__ P, ushort* __restrict__ wCat)
{
  const long NW = (long)D_ * D_;
  const long i = ((long)blockIdx.x * 256 + threadIdx.x) * 8;
  float s[8] = {0.f, 0.f, 0.f, 0.f, 0.f, 0.f, 0.f, 0.f};
#pragma unroll
  for (int sp = 0; sp < 4; ++sp) {
    bf16x8 p = *(const bf16x8*)(P + (long)sp * 2 * NW + i);
#pragma unroll
    for (int j = 0; j < 8; ++j) s[j] += bf2f((ushort)p[j]);
  }
  const long comp = (i >= NW) ? 1 : 0;
  ushort* out = wCat + comp * 2 * NW + (i - comp * NW);
  bf16x8 o;
#pragma unroll
  for (int j = 0; j < 8; ++j) o[j] = (short)f2bf(s[j]);
  *(bf16x8*)out = o;
}

// merged transpose: z<B_: lT = (exp(S1)/rowsum)^T ; z>=B_: ovT = ov^T
__global__ __launch_bounds__(256)
void transposeF(const ushort* __restrict__ l, ushort* __restrict__ lT,
                const ushort* __restrict__ ov, ushort* __restrict__ ovT,
                const float* __restrict__ rsumP)
{
  __shared__ alignas(16) ushort t[64 * 65];
  const int z = blockIdx.z;
  const int b = z & (B_ - 1);
  const bool isL = z < B_;
  const ushort* in = (isL ? l : ov) + (long)b * T_ * D_;
  ushort* out      = (isL ? lT : ovT) + (long)b * (long)D_ * T_;
  const int c0 = blockIdx.x * 64, r0 = blockIdx.y * 64;
  const int tx = threadIdx.x & 15, ty = threadIdx.x >> 4;
#pragma unroll
  for (int i = 0; i < 4; ++i) {
    const int r = ty + i * 16;
    u16x4 v = *(const u16x4*)(in + (long)(r0 + r) * D_ + c0 + tx * 4);
    if (isL) {
      const long gr = (long)b * T_ + r0 + r;
      const float ri = 1.f / (rsumP[gr] + rsumP[8192 + gr] +
                              rsumP[16384 + gr] + rsumP[24576 + gr]);
#pragma unroll
      for (int c = 0; c < 4; ++c) t[(tx * 4 + c) * 65 + r] = f2bf(__expf(bf2f(v[c])) * ri);
    } else {
#pragma unroll
      for (int c = 0; c < 4; ++c) t[(tx * 4 + c) * 65 + r] = v[c];
    }
  }
  __syncthreads();
#pragma unroll
  for (int i = 0; i < 4; ++i) {
    const int c = ty + i * 16;
    u16x4 v;
#pragma unroll
    for (int j = 0; j < 4; ++j) v[j] = t[c * 65 + tx * 4 + j];
    *(u16x4*)(out + (long)(c0 + c) * T_ + r0 + tx * 4) = v;
  }
}

// MT2[b][d][e] = (p0+p1) / psum[b][e]
__global__ __launch_bounds__(256)
void reduce2_scale(const ushort* __restrict__ P, const float* __restrict__ psum,
                   ushort* __restrict__ MT)
{
  const long stride = (long)B_ * D_ * D_;
  const long base = ((long)blockIdx.x * 256 + threadIdx.x) * 8;
  const int b = (int)(base >> 20);
  const int e0 = (int)(base & (D_ - 1));
  bf16x8 p0 = *(const bf16x8*)(P + base);
  bf16x8 p1 = *(const bf16x8*)(P + stride + base);
  const float4 c0 = *(const float4*)(psum + (long)b * D_ + e0);
  const float4 c1 = *(const float4*)(psum + (long)b * D_ + e0 + 4);
  const float cc[8] = {1.f / c0.x, 1.f / c0.y, 1.f / c0.z, 1.f / c0.w,
                       1.f / c1.x, 1.f / c1.y, 1.f / c1.z, 1.f / c1.w};
  bf16x8 o;
#pragma unroll
  for (int j = 0; j < 8; ++j)
    o[j] = (short)f2bf((bf2f((ushort)p0[j]) + bf2f((ushort)p1[j])) * cc[j]);
  *(bf16x8*)(MT + base) = o;
}

extern "C" void kernel_launch(void* const* d_in, const int* in_sizes, int n_in,
                              void* d_out, int out_size, void* d_ws, size_t ws_size,
                              hipStream_t stream)
{
  (void)in_sizes; (void)n_in; (void)out_size; (void)ws_size;
  const float* lat = (const float*)d_in[0];
  const float* inp = (const float*)d_in[1];
  const float* Wl  = (const float*)d_in[2];
  const float* bl  = (const float*)d_in[3];
  const float* Wu  = (const float*)d_in[4];
  const float* bu  = (const float*)d_in[5];
  const float* WA  = (const float*)d_in[6];
  const float* bA  = (const float*)d_in[7];
  const float* WV  = (const float*)d_in[8];
  const float* bV  = (const float*)d_in[9];
  const float* Wo  = (const float*)d_in[10];
  const float* bo  = (const float*)d_in[11];

  char* w = (char*)d_ws;
  auto carve = [&](size_t bytes) { char* p = w; w += (bytes + 255) & ~(size_t)255; return p; };
  const long NT = (long)B_ * T_ * D_;
  const long NW = (long)D_ * D_;
  ushort* xBf   = (ushort*)carve(NT * 2);
  ushort* xBf2  = (ushort*)carve(NT * 2);
  ushort* bufA  = (ushort*)carve(NT * 2);
  ushort* bufB  = (ushort*)carve(NT * 2);
  ushort* scr   = (ushort*)carve(NT * 2);
  ushort* MT    = (ushort*)carve((long)B_ * NW * 2);
  ushort* wCat  = (ushort*)carve(3 * NW * 2);
  float*  bc    = (float*)carve(D_ * 4);
  float*  bc2   = (float*)carve(D_ * 4);
  float*  psum  = (float*)carve((long)B_ * D_ * 4);
  float*  rsumP = (float*)carve(4L * B_ * T_ * 4);
  ushort* w1 = scr;              // [Wu_bf ; WV_bf]
  ushort* w2 = scr + 2 * NW;     // [WlT ; WAT]
  ushort* Pc = bufA;             // compose splitK partials (dead before bufA's first write)
  ushort* ovT = scr;             // after compose, scr dead -> ovT
  ushort* part = bufB;           // after transposes, bufB dead -> splitk partials

  const dim3 blk(256, 1, 1);
  const dim3 blk5(512, 1, 1);

  // 1. fused prep (incl. psum zeroing)
  prep<<<dim3(20496), blk, 0, stream>>>(lat, inp, Wl, bl, Wu, bu, WA, bA, WV, bV, Wo, bo,
                                        xBf, xBf2, w1, w2, wCat + NW, bc, bc2, psum);
  // 2. weight compose, split-K=4 + reduce
  gemm128<4, 4><<<dim3(8, 4, 8), blk5, 0, stream>>>(
      w1, w2, nullptr, Pc, D_, D_, NW, NW, 0, nullptr);
  reduce4<<<dim3(1024), blk, 0, stream>>>(Pc, wCat);
  // 3. S1 (bufB) + ov (bufA) + fused row exp-sums -> rsumP
  gemm256<<<dim3(8, 32, 1), blk5, 0, stream>>>(
      xBf, wCat, bc, bo, bufB, bufA, D_, D_, rsumP);
  // 4. fused softmax-transpose (l) + transpose (ov)
  transposeF<<<dim3(16, 32, 2 * B_), blk, 0, stream>>>(bufB, xBf, bufA, ovT, rsumP);
  // 5. merged MT partials + E on the 256-tile core (256 blocks, 1 round)
  gemm_me2<<<dim3(256), blk5, 0, stream>>>(
      ovT, xBf, part, xBf2, wCat + 2 * NW, bc2, bufA, psum);
  // 6. combine splitK + scale by 1/psum
  reduce2_scale<<<dim3(2048), blk, 0, stream>>>(part, psum, MT);
  // 7. final, 256 blocks
  gemm128<3><<<dim3(8, 8, 4), blk5, 0, stream>>>(
      bufA, MT, nullptr, d_out, D_, D_,
      (long)T_ * D_, NW, (long)T_ * D_, nullptr);
}